// Round 1
// baseline (1361.628 us; speedup 1.0000x reference)
//
#include <hip/hip_runtime.h>
#include <math.h>

// ---------------------------------------------------------------------------
// GraphAutoEncoder (GATv2 x3 + graph-norm + encoder/decoder), fp32, MI355X
// ---------------------------------------------------------------------------

// ---------------- CSR build ----------------
__global__ void hist_k(const int* __restrict__ tgt, int* __restrict__ deg, int E) {
  int stride = gridDim.x * blockDim.x;
  for (int e = blockIdx.x * blockDim.x + threadIdx.x; e < E; e += stride)
    atomicAdd(&deg[tgt[e]], 1);
}

__global__ void scan1_k(const int* __restrict__ deg, int* __restrict__ bsum, int n) {
  __shared__ int sh[256];
  int idx = blockIdx.x * 256 + threadIdx.x;
  sh[threadIdx.x] = (idx < n) ? deg[idx] : 0;
  __syncthreads();
  for (int off = 128; off > 0; off >>= 1) {
    if (threadIdx.x < off) sh[threadIdx.x] += sh[threadIdx.x + off];
    __syncthreads();
  }
  if (threadIdx.x == 0) bsum[blockIdx.x] = sh[0];
}

__global__ void scan2_k(int* __restrict__ bsum, int nb) {
  __shared__ int sh[256];
  int t = threadIdx.x;
  int v = (t < nb) ? bsum[t] : 0;
  sh[t] = v; __syncthreads();
  for (int off = 1; off < 256; off <<= 1) {
    int add = (t >= off) ? sh[t - off] : 0;
    __syncthreads();
    sh[t] += add;
    __syncthreads();
  }
  if (t < nb) bsum[t] = sh[t] - v;  // exclusive
}

__global__ void scan3_k(const int* __restrict__ deg, const int* __restrict__ bsum,
                        int* __restrict__ starts, int* __restrict__ cursor, int n) {
  __shared__ int sh[256];
  int t = threadIdx.x;
  int idx = blockIdx.x * 256 + t;
  int v = (idx < n) ? deg[idx] : 0;
  sh[t] = v; __syncthreads();
  for (int off = 1; off < 256; off <<= 1) {
    int add = (t >= off) ? sh[t - off] : 0;
    __syncthreads();
    sh[t] += add;
    __syncthreads();
  }
  if (idx < n) {
    int ex = bsum[blockIdx.x] + sh[t] - v;
    starts[idx] = ex;
    cursor[idx] = ex;
  }
}

__global__ void scatter_k(const int* __restrict__ src, const int* __restrict__ tgt,
                          int* __restrict__ cursor, int* __restrict__ esrc, int E) {
  int stride = gridDim.x * blockDim.x;
  for (int e = blockIdx.x * blockDim.x + threadIdx.x; e < E; e += stride) {
    int p = atomicAdd(&cursor[tgt[e]], 1);
    esrc[p] = src[e];
  }
}

// ---------------- tiled fp32 GEMM: Y[n,F] = act(X[n,K] @ W[K,F] + b) (+Y) ----
template <int K, int F, int BN, int ACT, int ACCUM>
__global__ __launch_bounds__(256) void gemm_k(const float* __restrict__ X,
                                              const float* __restrict__ W,
                                              const float* __restrict__ Bv,
                                              float* __restrict__ Y, int n) {
  constexpr int NTC = F / 4;        // thread-columns (4 cols each)
  constexpr int NTR = 256 / NTC;    // thread-rows
  constexpr int TM = BN / NTR;      // rows per thread
  constexpr int KP = K + 1;         // padded LDS row
  constexpr int KC = 64;            // W k-chunk
  __shared__ float Xs[BN][KP];
  __shared__ float Ws[KC][F];
  const int tid = threadIdx.x;
  const int tc = tid % NTC;
  const int tr = tid / NTC;
  const int n0 = blockIdx.x * BN;

  for (int i = tid; i < BN * K; i += 256) {
    int r = i / K, k = i - r * K;
    int gr = n0 + r;
    Xs[r][k] = (gr < n) ? X[(size_t)gr * K + k] : 0.f;
  }
  float acc[TM][4];
#pragma unroll
  for (int i = 0; i < TM; ++i) { acc[i][0] = acc[i][1] = acc[i][2] = acc[i][3] = 0.f; }

  for (int kc = 0; kc < K; kc += KC) {
    __syncthreads();
    for (int i = tid; i < KC * F; i += 256) {
      int kk = i / F, c = i - kk * F;
      Ws[kk][c] = W[(size_t)(kc + kk) * F + c];
    }
    __syncthreads();
#pragma unroll 4
    for (int kk = 0; kk < KC; ++kk) {
      const float4 wv = *reinterpret_cast<const float4*>(&Ws[kk][tc * 4]);
#pragma unroll
      for (int i = 0; i < TM; ++i) {
        float xv = Xs[tr * TM + i][kc + kk];
        acc[i][0] = fmaf(xv, wv.x, acc[i][0]);
        acc[i][1] = fmaf(xv, wv.y, acc[i][1]);
        acc[i][2] = fmaf(xv, wv.z, acc[i][2]);
        acc[i][3] = fmaf(xv, wv.w, acc[i][3]);
      }
    }
  }
  float4 bv = make_float4(0.f, 0.f, 0.f, 0.f);
  if (Bv) bv = *reinterpret_cast<const float4*>(&Bv[tc * 4]);
#pragma unroll
  for (int i = 0; i < TM; ++i) {
    int gr = n0 + tr * TM + i;
    if (gr >= n) continue;
    float4 o;
    o.x = acc[i][0] + bv.x; o.y = acc[i][1] + bv.y;
    o.z = acc[i][2] + bv.z; o.w = acc[i][3] + bv.w;
    if (ACT) {
      o.x = fmaxf(o.x, 0.f); o.y = fmaxf(o.y, 0.f);
      o.z = fmaxf(o.z, 0.f); o.w = fmaxf(o.w, 0.f);
    }
    float* yp = &Y[(size_t)gr * F + tc * 4];
    if (ACCUM) {
      float4 old = *reinterpret_cast<const float4*>(yp);
      o.x += old.x; o.y += old.y; o.z += old.z; o.w += old.w;
    }
    *reinterpret_cast<float4*>(yp) = o;
  }
}

// ---------------- GATv2 edge aggregation: one wave per target node ----------
// online softmax over in-edges (+ implicit self loop), per-head reduce via shfl
template <int H, int C, int HAS_RES>
__global__ __launch_bounds__(256) void agg_k(const float* __restrict__ xl,
                                             const float* __restrict__ xr,
                                             const float* __restrict__ att,
                                             const float* __restrict__ bo,
                                             const int* __restrict__ starts,
                                             const int* __restrict__ deg,
                                             const int* __restrict__ esrc,
                                             float* __restrict__ out, int n) {
  constexpr int F = H * C;
  constexpr int VPL = F / 64;  // values per lane
  const int lane = threadIdx.x & 63;
  const int node = blockIdx.x * 4 + (threadIdx.x >> 6);
  if (node >= n) return;
  float xri[VPL], av[VPL], m[VPL], s[VPL], acc[VPL];
#pragma unroll
  for (int v = 0; v < VPL; ++v) {
    int ch = lane + 64 * v;
    xri[v] = xr[(size_t)node * F + ch];
    av[v] = att[ch];
    m[v] = -1e30f; s[v] = 0.f; acc[v] = 0.f;
  }
  const int st = starts[node];
  const int cnt = deg[node];
  for (int it = 0; it <= cnt; ++it) {  // last iteration = self loop
    const int j = (it < cnt) ? esrc[st + it] : node;
    float xj[VPL], e[VPL];
#pragma unroll
    for (int v = 0; v < VPL; ++v) {
      xj[v] = xl[(size_t)j * F + lane + 64 * v];
      float t = xri[v] + xj[v];
      t = (t > 0.f) ? t : 0.2f * t;  // leaky_relu(0.2)
      e[v] = t * av[v];
    }
#pragma unroll
    for (int v = 0; v < VPL; ++v) {
#pragma unroll
      for (int mm = 1; mm < C; mm <<= 1) e[v] += __shfl_xor(e[v], mm, 64);
    }
#pragma unroll
    for (int v = 0; v < VPL; ++v) {
      float mn = fmaxf(m[v], e[v]);
      float sc = __expf(m[v] - mn);
      float p = __expf(e[v] - mn);
      s[v] = s[v] * sc + p;
      acc[v] = acc[v] * sc + p * xj[v];
      m[v] = mn;
    }
  }
#pragma unroll
  for (int v = 0; v < VPL; ++v) {
    int ch = lane + 64 * v;
    size_t idx = (size_t)node * F + ch;
    float o = acc[v] / s[v] + bo[ch];
    if (HAS_RES) o += out[idx];  // residual precomputed into out
    out[idx] = o;
  }
}

// ---------------- graph layernorm (global mean/var) + relu ------------------
__global__ void ln_stats_k(const float* __restrict__ x, float* __restrict__ stats,
                           size_t total) {
  size_t stride = (size_t)gridDim.x * blockDim.x;
  float s1 = 0.f, s2 = 0.f;
  for (size_t k = (size_t)blockIdx.x * blockDim.x + threadIdx.x; k < total; k += stride) {
    float v = x[k];
    s1 += v; s2 += v * v;
  }
#pragma unroll
  for (int mm = 1; mm < 64; mm <<= 1) {
    s1 += __shfl_xor(s1, mm, 64);
    s2 += __shfl_xor(s2, mm, 64);
  }
  if ((threadIdx.x & 63) == 0) { atomicAdd(&stats[0], s1); atomicAdd(&stats[1], s2); }
}

__global__ void ln_apply_k(float* __restrict__ x, const float* __restrict__ stats,
                           const float* __restrict__ g, const float* __restrict__ b,
                           size_t total, int fmask, float invNF) {
  float mu = stats[0] * invNF;
  float var = stats[1] * invNF - mu * mu;
  float rs = rsqrtf(var + 1e-5f);
  size_t stride = (size_t)gridDim.x * blockDim.x;
  for (size_t k = (size_t)blockIdx.x * blockDim.x + threadIdx.x; k < total; k += stride) {
    int c = (int)(k & (size_t)fmask);
    float v = (x[k] - mu) * rs * g[c] + b[c];
    x[k] = fmaxf(v, 0.f);
  }
}

// ---------------- column mean (z_graph) -------------------------------------
__global__ void colmean_k(const float* __restrict__ z, float* __restrict__ outv,
                          int n, float inv) {
  __shared__ float sh[256];
  int col = threadIdx.x & 63;
  int w = threadIdx.x >> 6;
  float s = 0.f;
  for (int r = blockIdx.x * 4 + w; r < n; r += gridDim.x * 4)
    s += z[(size_t)r * 64 + col];
  sh[threadIdx.x] = s;
  __syncthreads();
  if (threadIdx.x < 64) {
    float t = sh[threadIdx.x] + sh[threadIdx.x + 64] + sh[threadIdx.x + 128] +
              sh[threadIdx.x + 192];
    atomicAdd(&outv[col], t * inv);
  }
}

// ---------------------------------------------------------------------------
extern "C" void kernel_launch(void* const* d_in, const int* in_sizes, int n_in,
                              void* d_out, int out_size, void* d_ws, size_t ws_size,
                              hipStream_t stream) {
  const float* x = (const float*)d_in[0];
  const int* ei = (const int*)d_in[1];
  const float *Wl1 = (const float*)d_in[3], *bl1 = (const float*)d_in[4];
  const float *Wr1 = (const float*)d_in[5], *br1 = (const float*)d_in[6];
  const float *att1 = (const float*)d_in[7], *bo1 = (const float*)d_in[8];
  const float *Wl2 = (const float*)d_in[9], *bl2 = (const float*)d_in[10];
  const float *Wr2 = (const float*)d_in[11], *br2 = (const float*)d_in[12];
  const float *att2 = (const float*)d_in[13], *bo2 = (const float*)d_in[14];
  const float *Wres2 = (const float*)d_in[15];
  const float *Wl3 = (const float*)d_in[16], *bl3 = (const float*)d_in[17];
  const float *Wr3 = (const float*)d_in[18], *br3 = (const float*)d_in[19];
  const float *att3 = (const float*)d_in[20], *bo3 = (const float*)d_in[21];
  const float *Wres3 = (const float*)d_in[22];
  const float *ln1g = (const float*)d_in[23], *ln1b = (const float*)d_in[24];
  const float *ln2g = (const float*)d_in[25], *ln2b = (const float*)d_in[26];
  const float *ln3g = (const float*)d_in[27], *ln3b = (const float*)d_in[28];
  const float *encW = (const float*)d_in[29], *encb = (const float*)d_in[30];
  const float *rpW = (const float*)d_in[31], *rpb = (const float*)d_in[32];
  const float *d1W = (const float*)d_in[33], *d1b = (const float*)d_in[34];
  const float *d2W = (const float*)d_in[35], *d2b = (const float*)d_in[36];
  const float *d3W = (const float*)d_in[37], *d3b = (const float*)d_in[38];

  const int N = in_sizes[0] / 64;
  const int E = in_sizes[1] / 2;
  const int* esrc_in = ei;       // row 0: src
  const int* etgt_in = ei + E;   // row 1: tgt

  // workspace layout
  float* ws = (float*)d_ws;
  size_t NA = (size_t)N * 256;
  float* bufA = ws;                       // xl (N x 256 max)
  float* bufB = bufA + NA;                // xr
  float* bufC = bufB + NA;                // h1 / h3
  float* bufD = bufC + NA;                // h2 (N x 128)
  float* stats = bufD + (size_t)N * 128;  // 8 floats (2 per layer)
  int* deg = (int*)(stats + 8);
  int* starts = deg + N;
  int* cursor = starts + N;
  int* bsum = cursor + N;                 // 256
  int* esrc = bsum + 256;                 // E
  size_t need = ((size_t)N * 896 + 8) * sizeof(float) +
                ((size_t)3 * N + 256 + (size_t)E) * sizeof(int);
  if (ws_size < need) return;  // insufficient scratch -> fail loudly in check

  float* z = (float*)d_out;                  // z_nodes  (N x 64)
  float* xhat = z + (size_t)N * 64;          // x_hat    (N x 64)
  float* zg = xhat + (size_t)N * 64;         // z_graph  (64)

  // ---- init ----
  hipMemsetAsync(deg, 0, (size_t)N * sizeof(int), stream);
  hipMemsetAsync(stats, 0, 8 * sizeof(float), stream);
  hipMemsetAsync(zg, 0, 64 * sizeof(float), stream);

  // ---- CSR by target ----
  const int nb = (N + 255) / 256;  // <= 256 blocks (N <= 65536)
  hist_k<<<512, 256, 0, stream>>>(etgt_in, deg, E);
  scan1_k<<<nb, 256, 0, stream>>>(deg, bsum, N);
  scan2_k<<<1, 256, 0, stream>>>(bsum, nb);
  scan3_k<<<nb, 256, 0, stream>>>(deg, bsum, starts, cursor, N);
  scatter_k<<<512, 256, 0, stream>>>(esrc_in, etgt_in, cursor, esrc, E);

#define GEMM(Kk, Ff, BNn, act, accum, Xp, Wp, Bp, Yp) \
  gemm_k<Kk, Ff, BNn, act, accum><<<(N + BNn - 1) / BNn, 256, 0, stream>>>(Xp, Wp, Bp, Yp, N)

  // ---- conv1: heads=1, C=64, no residual ----
  GEMM(64, 64, 64, 0, 0, x, Wl1, bl1, bufA);   // xl1
  GEMM(64, 64, 64, 0, 0, x, Wr1, br1, bufB);   // xr1
  agg_k<1, 64, 0><<<(N + 3) / 4, 256, 0, stream>>>(bufA, bufB, att1, bo1, starts, deg,
                                                   esrc, bufC, N);
  {
    size_t tot = (size_t)N * 64;
    ln_stats_k<<<1024, 256, 0, stream>>>(bufC, stats + 0, tot);
    ln_apply_k<<<2048, 256, 0, stream>>>(bufC, stats + 0, ln1g, ln1b, tot, 63,
                                         1.f / (float)tot);
  }

  // ---- conv2: heads=4, C=32, residual ----
  GEMM(64, 128, 32, 0, 0, bufC, Wres2, (const float*)nullptr, bufD);  // res
  GEMM(64, 128, 32, 0, 0, bufC, Wl2, bl2, bufA);                      // xl2
  GEMM(64, 128, 32, 0, 0, bufC, Wr2, br2, bufB);                      // xr2
  agg_k<4, 32, 1><<<(N + 3) / 4, 256, 0, stream>>>(bufA, bufB, att2, bo2, starts, deg,
                                                   esrc, bufD, N);
  {
    size_t tot = (size_t)N * 128;
    ln_stats_k<<<1024, 256, 0, stream>>>(bufD, stats + 2, tot);
    ln_apply_k<<<2048, 256, 0, stream>>>(bufD, stats + 2, ln2g, ln2b, tot, 127,
                                         1.f / (float)tot);
  }

  // ---- conv3: heads=4, C=64, residual ----
  GEMM(128, 256, 16, 0, 0, bufD, Wres3, (const float*)nullptr, bufC);  // res
  GEMM(128, 256, 16, 0, 0, bufD, Wl3, bl3, bufA);                      // xl3
  GEMM(128, 256, 16, 0, 0, bufD, Wr3, br3, bufB);                      // xr3
  agg_k<4, 64, 1><<<(N + 3) / 4, 256, 0, stream>>>(bufA, bufB, att3, bo3, starts, deg,
                                                   esrc, bufC, N);
  {
    size_t tot = (size_t)N * 256;
    ln_stats_k<<<1024, 256, 0, stream>>>(bufC, stats + 4, tot);
    ln_apply_k<<<2048, 256, 0, stream>>>(bufC, stats + 4, ln3g, ln3b, tot, 255,
                                         1.f / (float)tot);
  }

  // ---- encoder: z = relu(h3 @ encW + encb) + (x @ rpW + rpb) ----
  GEMM(64, 64, 64, 0, 0, x, rpW, rpb, z);          // z = x@rpW + rpb
  GEMM(256, 64, 32, 1, 1, bufC, encW, encb, z);    // z += relu(h3@encW + encb)

  // ---- z_graph = column mean of z ----
  colmean_k<<<256, 256, 0, stream>>>(z, zg, N, 1.f / (float)N);

  // ---- decoder ----
  GEMM(64, 128, 32, 1, 0, z, d1W, d1b, bufA);      // dh1 = relu(z@d1W+b)
  GEMM(128, 64, 64, 1, 0, bufA, d2W, d2b, bufB);   // dh2 = relu(dh1@d2W+b)
  GEMM(64, 64, 64, 0, 0, bufB, d3W, d3b, xhat);    // x_hat

#undef GEMM
}

// Round 2
// 1094.780 us; speedup vs baseline: 1.2437x; 1.2437x over previous
//
#include <hip/hip_runtime.h>
#include <math.h>

typedef __attribute__((ext_vector_type(8))) short short8;
typedef __attribute__((ext_vector_type(4))) float f32x4;

__device__ __forceinline__ unsigned short f2bf(float f) {
  union { float f; unsigned u; } c; c.f = f;
  unsigned r = c.u + 0x7fffu + ((c.u >> 16) & 1u);
  return (unsigned short)(r >> 16);
}
__device__ __forceinline__ float bf2f(unsigned short u) {
  union { unsigned u; float f; } c; c.u = ((unsigned)u) << 16;
  return c.f;
}

// ---------------- CSR build ----------------
__global__ void hist_k(const int* __restrict__ tgt, int* __restrict__ deg, int E) {
  int stride = gridDim.x * blockDim.x;
  for (int e = blockIdx.x * blockDim.x + threadIdx.x; e < E; e += stride)
    atomicAdd(&deg[tgt[e]], 1);
}

__global__ void scan1_k(const int* __restrict__ deg, int* __restrict__ bsum, int n) {
  __shared__ int sh[256];
  int idx = blockIdx.x * 256 + threadIdx.x;
  sh[threadIdx.x] = (idx < n) ? deg[idx] : 0;
  __syncthreads();
  for (int off = 128; off > 0; off >>= 1) {
    if (threadIdx.x < off) sh[threadIdx.x] += sh[threadIdx.x + off];
    __syncthreads();
  }
  if (threadIdx.x == 0) bsum[blockIdx.x] = sh[0];
}

__global__ void scan2_k(int* __restrict__ bsum, int nb) {
  __shared__ int sh[256];
  int t = threadIdx.x;
  int v = (t < nb) ? bsum[t] : 0;
  sh[t] = v; __syncthreads();
  for (int off = 1; off < 256; off <<= 1) {
    int add = (t >= off) ? sh[t - off] : 0;
    __syncthreads();
    sh[t] += add;
    __syncthreads();
  }
  if (t < nb) bsum[t] = sh[t] - v;  // exclusive
}

__global__ void scan3_k(const int* __restrict__ deg, const int* __restrict__ bsum,
                        int* __restrict__ starts, int* __restrict__ cursor, int n) {
  __shared__ int sh[256];
  int t = threadIdx.x;
  int idx = blockIdx.x * 256 + t;
  int v = (idx < n) ? deg[idx] : 0;
  sh[t] = v; __syncthreads();
  for (int off = 1; off < 256; off <<= 1) {
    int add = (t >= off) ? sh[t - off] : 0;
    __syncthreads();
    sh[t] += add;
    __syncthreads();
  }
  if (idx < n) {
    int ex = bsum[blockIdx.x] + sh[t] - v;
    starts[idx] = ex;
    cursor[idx] = ex;
  }
}

__global__ void scatter_k(const int* __restrict__ src, const int* __restrict__ tgt,
                          int* __restrict__ cursor, int* __restrict__ esrc, int E) {
  int stride = gridDim.x * blockDim.x;
  for (int e = blockIdx.x * blockDim.x + threadIdx.x; e < E; e += stride) {
    int p = atomicAdd(&cursor[tgt[e]], 1);
    esrc[p] = src[e];
  }
}

// ---------------- conversions ----------------
__global__ void cvt_k(const float* __restrict__ src, unsigned short* __restrict__ dst,
                      size_t n4) {
  size_t stride = (size_t)gridDim.x * blockDim.x;
  for (size_t i = (size_t)blockIdx.x * blockDim.x + threadIdx.x; i < n4; i += stride) {
    float4 v = reinterpret_cast<const float4*>(src)[i];
    ushort4 o;
    o.x = f2bf(v.x); o.y = f2bf(v.y); o.z = f2bf(v.z); o.w = f2bf(v.w);
    reinterpret_cast<ushort4*>(dst)[i] = o;
  }
}

// W[K,F] fp32 -> WT[F,K] bf16
__global__ void wconv_k(const float* __restrict__ W, unsigned short* __restrict__ WT,
                        int K, int F) {
  int idx = blockIdx.x * 256 + threadIdx.x;
  if (idx >= K * F) return;
  int k = idx / F, f = idx - k * F;
  WT[(size_t)f * K + k] = f2bf(W[idx]);
}

// ---------------- MFMA GEMM: Y[n,F] = act(Xbf[n,K] @ W + b) ----------------
// X bf16 row-major (K contig); WT bf16 [F,K] (K contig). One wave = 16 rows x F.
template <int K, int F, int ACT, int ACCUM, int WF32, int WBF>
__global__ __launch_bounds__(256) void mgemm_k(const unsigned short* __restrict__ X,
                                               const unsigned short* __restrict__ WT,
                                               const float* __restrict__ Bv,
                                               float* __restrict__ Y,
                                               unsigned short* __restrict__ Yb, int n) {
  constexpr int NT = F / 16;  // 16-col tiles
  const int lane = threadIdx.x & 63;
  const int wave = threadIdx.x >> 6;
  const int r0 = (blockIdx.x * 4 + wave) * 16;
  const int rl = lane & 15;   // A row / B col / C col within tile
  const int ks = lane >> 4;   // k-slot
  const int row = r0 + rl;
  const bool rok = row < n;

  f32x4 acc[NT];
#pragma unroll
  for (int t = 0; t < NT; ++t) acc[t] = (f32x4){0.f, 0.f, 0.f, 0.f};

  for (int kc = 0; kc < K; kc += 32) {
    short8 a = {0, 0, 0, 0, 0, 0, 0, 0};
    if (rok)
      a = *reinterpret_cast<const short8*>(&X[(size_t)row * K + kc + ks * 8]);
#pragma unroll
    for (int t = 0; t < NT; ++t) {
      short8 b = *reinterpret_cast<const short8*>(
          &WT[(size_t)(t * 16 + rl) * K + kc + ks * 8]);
      acc[t] = __builtin_amdgcn_mfma_f32_16x16x32_bf16(a, b, acc[t], 0, 0, 0);
    }
  }
  // D: col = t*16 + (lane&15), row = r0 + (lane>>4)*4 + r
  const int rowd = r0 + ks * 4;
#pragma unroll
  for (int t = 0; t < NT; ++t) {
    const float bias = Bv ? Bv[t * 16 + rl] : 0.f;
#pragma unroll
    for (int r = 0; r < 4; ++r) {
      const int gr = rowd + r;
      if (gr >= n) continue;
      float o = acc[t][r] + bias;
      if (ACT) o = fmaxf(o, 0.f);
      const size_t idx = (size_t)gr * F + t * 16 + rl;
      if (ACCUM) o += Y[idx];
      if (WF32) Y[idx] = o;
      if (WBF) Yb[idx] = f2bf(o);
    }
  }
}

// ---------------- GATv2 edge aggregation ------------------------------------
// one wave per target node; lane holds VEC=F/64 consecutive channels;
// head group = 64/H lanes; online softmax with defer-max (T13).
template <int H, int C, int VEC, int HAS_RES>
__global__ __launch_bounds__(256) void agg_k(const unsigned short* __restrict__ xl,
                                             const unsigned short* __restrict__ xr,
                                             const float* __restrict__ att,
                                             const float* __restrict__ bo,
                                             const int* __restrict__ starts,
                                             const int* __restrict__ deg,
                                             const int* __restrict__ esrc,
                                             float* __restrict__ out, int n) {
  constexpr int F = H * C;
  constexpr int G = 64 / H;  // lanes per head group
  const int lane = threadIdx.x & 63;
  const int node = blockIdx.x * 4 + (threadIdx.x >> 6);
  if (node >= n) return;

  float xri[VEC], av[VEC], acc[VEC];
#pragma unroll
  for (int q = 0; q < VEC; ++q) {
    xri[q] = bf2f(xr[(size_t)node * F + lane * VEC + q]);
    av[q] = att[lane * VEC + q];
    acc[q] = 0.f;
  }
  float m = -1e30f, s = 0.f;
  const int st = starts[node];
  const int cnt = deg[node];
  for (int it = 0; it <= cnt; ++it) {  // last iteration = self loop
    const int j = (it < cnt) ? esrc[st + it] : node;
    float xj[VEC];
    {
      const unsigned short* p = &xl[(size_t)j * F + lane * VEC];
      if (VEC == 4) {
        ushort4 u = *reinterpret_cast<const ushort4*>(p);
        xj[0] = bf2f(u.x); xj[1] = bf2f(u.y); xj[2] = bf2f(u.z); xj[3] = bf2f(u.w);
      } else if (VEC == 2) {
        ushort2 u = *reinterpret_cast<const ushort2*>(p);
        xj[0] = bf2f(u.x); xj[1] = bf2f(u.y);
      } else {
        xj[0] = bf2f(*p);
      }
    }
    float e = 0.f;
#pragma unroll
    for (int q = 0; q < VEC; ++q) {
      float t = xri[q] + xj[q];
      t = (t > 0.f) ? t : 0.2f * t;  // leaky_relu(0.2)
      e = fmaf(t, av[q], e);
    }
#pragma unroll
    for (int mask = 1; mask < G; mask <<= 1) e += __shfl_xor(e, mask, 64);
    if (e - m > 8.f) {  // rescale rarely (uniform within head group)
      const float sc = __expf(m - e);
      s *= sc;
#pragma unroll
      for (int q = 0; q < VEC; ++q) acc[q] *= sc;
      m = e;
    }
    const float p = __expf(e - m);
    s += p;
#pragma unroll
    for (int q = 0; q < VEC; ++q) acc[q] = fmaf(p, xj[q], acc[q]);
  }
  const float inv = 1.f / s;
#pragma unroll
  for (int q = 0; q < VEC; ++q) {
    const size_t idx = (size_t)node * F + lane * VEC + q;
    float o = acc[q] * inv + bo[lane * VEC + q];
    if (HAS_RES) o += out[idx];  // residual precomputed into out
    out[idx] = o;
  }
}

// ---------------- graph layernorm (global mean/var) + relu ------------------
__global__ void ln_stats_k(const float* __restrict__ x, float* __restrict__ stats,
                           size_t n4) {
  size_t stride = (size_t)gridDim.x * blockDim.x;
  float s1 = 0.f, s2 = 0.f;
  for (size_t i = (size_t)blockIdx.x * blockDim.x + threadIdx.x; i < n4; i += stride) {
    float4 v = reinterpret_cast<const float4*>(x)[i];
    s1 += v.x + v.y + v.z + v.w;
    s2 += v.x * v.x + v.y * v.y + v.z * v.z + v.w * v.w;
  }
#pragma unroll
  for (int mm = 1; mm < 64; mm <<= 1) {
    s1 += __shfl_xor(s1, mm, 64);
    s2 += __shfl_xor(s2, mm, 64);
  }
  if ((threadIdx.x & 63) == 0) { atomicAdd(&stats[0], s1); atomicAdd(&stats[1], s2); }
}

__global__ void ln_apply_k(float* __restrict__ x, unsigned short* __restrict__ xb,
                           const float* __restrict__ stats, const float* __restrict__ g,
                           const float* __restrict__ b, size_t n4, int fmask,
                           float invNF) {
  const float mu = stats[0] * invNF;
  const float var = stats[1] * invNF - mu * mu;
  const float rs = rsqrtf(var + 1e-5f);
  size_t stride = (size_t)gridDim.x * blockDim.x;
  for (size_t i = (size_t)blockIdx.x * blockDim.x + threadIdx.x; i < n4; i += stride) {
    float4 v = reinterpret_cast<const float4*>(x)[i];
    const int c0 = (int)((i * 4) & (size_t)fmask);
    v.x = fmaxf((v.x - mu) * rs * g[c0 + 0] + b[c0 + 0], 0.f);
    v.y = fmaxf((v.y - mu) * rs * g[c0 + 1] + b[c0 + 1], 0.f);
    v.z = fmaxf((v.z - mu) * rs * g[c0 + 2] + b[c0 + 2], 0.f);
    v.w = fmaxf((v.w - mu) * rs * g[c0 + 3] + b[c0 + 3], 0.f);
    reinterpret_cast<float4*>(x)[i] = v;
    ushort4 o;
    o.x = f2bf(v.x); o.y = f2bf(v.y); o.z = f2bf(v.z); o.w = f2bf(v.w);
    reinterpret_cast<ushort4*>(xb)[i] = o;
  }
}

// ---------------- column mean (z_graph) -------------------------------------
__global__ void colmean_k(const float* __restrict__ z, float* __restrict__ outv,
                          int n, float inv) {
  __shared__ float sh[256];
  int col = threadIdx.x & 63;
  int w = threadIdx.x >> 6;
  float s = 0.f;
  for (int r = blockIdx.x * 4 + w; r < n; r += gridDim.x * 4)
    s += z[(size_t)r * 64 + col];
  sh[threadIdx.x] = s;
  __syncthreads();
  if (threadIdx.x < 64) {
    float t = sh[threadIdx.x] + sh[threadIdx.x + 64] + sh[threadIdx.x + 128] +
              sh[threadIdx.x + 192];
    atomicAdd(&outv[col], t * inv);
  }
}

// ---------------------------------------------------------------------------
extern "C" void kernel_launch(void* const* d_in, const int* in_sizes, int n_in,
                              void* d_out, int out_size, void* d_ws, size_t ws_size,
                              hipStream_t stream) {
  const float* x = (const float*)d_in[0];
  const int* ei = (const int*)d_in[1];
  const float *Wl1 = (const float*)d_in[3], *bl1 = (const float*)d_in[4];
  const float *Wr1 = (const float*)d_in[5], *br1 = (const float*)d_in[6];
  const float *att1 = (const float*)d_in[7], *bo1 = (const float*)d_in[8];
  const float *Wl2 = (const float*)d_in[9], *bl2 = (const float*)d_in[10];
  const float *Wr2 = (const float*)d_in[11], *br2 = (const float*)d_in[12];
  const float *att2 = (const float*)d_in[13], *bo2 = (const float*)d_in[14];
  const float *Wres2 = (const float*)d_in[15];
  const float *Wl3 = (const float*)d_in[16], *bl3 = (const float*)d_in[17];
  const float *Wr3 = (const float*)d_in[18], *br3 = (const float*)d_in[19];
  const float *att3 = (const float*)d_in[20], *bo3 = (const float*)d_in[21];
  const float *Wres3 = (const float*)d_in[22];
  const float *ln1g = (const float*)d_in[23], *ln1b = (const float*)d_in[24];
  const float *ln2g = (const float*)d_in[25], *ln2b = (const float*)d_in[26];
  const float *ln3g = (const float*)d_in[27], *ln3b = (const float*)d_in[28];
  const float *encW = (const float*)d_in[29], *encb = (const float*)d_in[30];
  const float *rpW = (const float*)d_in[31], *rpb = (const float*)d_in[32];
  const float *d1W = (const float*)d_in[33], *d1b = (const float*)d_in[34];
  const float *d2W = (const float*)d_in[35], *d2b = (const float*)d_in[36];
  const float *d3W = (const float*)d_in[37], *d3b = (const float*)d_in[38];

  const int N = in_sizes[0] / 64;
  const int E = in_sizes[1] / 2;
  const int* esrc_in = ei;      // row 0: src
  const int* etgt_in = ei + E;  // row 1: tgt

  // ---- workspace layout (byte cursor, all chunks 16B-aligned) ----
  char* cur = (char*)d_ws;
  auto take = [&](size_t bytes) {
    char* p = cur;
    cur += (bytes + 15) & ~(size_t)15;
    return p;
  };
  float* bufC = (float*)take((size_t)N * 256 * 4);          // h1 / h3 / agg3 out
  float* bufD = (float*)take((size_t)N * 128 * 4);          // h2
  unsigned short* Ab = (unsigned short*)take((size_t)N * 256 * 2);  // xl (bf16)
  unsigned short* Bb = (unsigned short*)take((size_t)N * 256 * 2);  // xr (bf16)
  unsigned short* Cb = (unsigned short*)take((size_t)N * 256 * 2);  // h1b/h3b/dh2b
  unsigned short* Db = (unsigned short*)take((size_t)N * 128 * 2);  // h2b/dh1b
  unsigned short* xb = (unsigned short*)take((size_t)N * 64 * 2);   // xbf / zb
  float* stats = (float*)take(32);
  int* deg = (int*)take((size_t)N * 4);
  int* starts = (int*)take((size_t)N * 4);
  int* cursor = (int*)take((size_t)N * 4);
  int* bsum = (int*)take(1024);
  int* esrc = (int*)take((size_t)E * 4);
  // transposed bf16 weights
  auto wt = [&](int K, int F) { return (unsigned short*)take((size_t)K * F * 2); };
  unsigned short *Tl1 = wt(64, 64), *Tr1 = wt(64, 64);
  unsigned short *Tl2 = wt(64, 128), *Tr2 = wt(64, 128), *Tres2 = wt(64, 128);
  unsigned short *Tl3 = wt(128, 256), *Tr3 = wt(128, 256), *Tres3 = wt(128, 256);
  unsigned short *Tenc = wt(256, 64), *Trp = wt(64, 64);
  unsigned short *Td1 = wt(64, 128), *Td2 = wt(128, 64), *Td3 = wt(64, 64);
  if ((size_t)(cur - (char*)d_ws) > ws_size) return;  // insufficient scratch

  float* z = (float*)d_out;           // z_nodes (N x 64)
  float* xhat = z + (size_t)N * 64;   // x_hat   (N x 64)
  float* zg = xhat + (size_t)N * 64;  // z_graph (64)

  hipMemsetAsync(deg, 0, (size_t)N * sizeof(int), stream);
  hipMemsetAsync(stats, 0, 32, stream);
  hipMemsetAsync(zg, 0, 64 * sizeof(float), stream);

  // ---- weight conversion (fp32 -> bf16 transposed) ----
#define WCONV(W, T, K, F) wconv_k<<<((K) * (F) + 255) / 256, 256, 0, stream>>>(W, T, K, F)
  WCONV(Wl1, Tl1, 64, 64);   WCONV(Wr1, Tr1, 64, 64);
  WCONV(Wl2, Tl2, 64, 128);  WCONV(Wr2, Tr2, 64, 128);  WCONV(Wres2, Tres2, 64, 128);
  WCONV(Wl3, Tl3, 128, 256); WCONV(Wr3, Tr3, 128, 256); WCONV(Wres3, Tres3, 128, 256);
  WCONV(encW, Tenc, 256, 64); WCONV(rpW, Trp, 64, 64);
  WCONV(d1W, Td1, 64, 128);  WCONV(d2W, Td2, 128, 64);  WCONV(d3W, Td3, 64, 64);
#undef WCONV
  cvt_k<<<2048, 256, 0, stream>>>(x, xb, (size_t)N * 16);

  // ---- CSR by target ----
  const int nb = (N + 255) / 256;
  hist_k<<<512, 256, 0, stream>>>(etgt_in, deg, E);
  scan1_k<<<nb, 256, 0, stream>>>(deg, bsum, N);
  scan2_k<<<1, 256, 0, stream>>>(bsum, nb);
  scan3_k<<<nb, 256, 0, stream>>>(deg, bsum, starts, cursor, N);
  scatter_k<<<512, 256, 0, stream>>>(esrc_in, etgt_in, cursor, esrc, E);

  const int gblk = (N + 63) / 64;
#define MG(K, F, ACT, ACCUM, WF32, WBF, X, WT, B, Y, YB) \
  mgemm_k<K, F, ACT, ACCUM, WF32, WBF><<<gblk, 256, 0, stream>>>(X, WT, B, Y, YB, N)
  const float* nullf = nullptr;
  float* nullY = nullptr;
  unsigned short* nullB = nullptr;

  // ---- conv1: heads=1, C=64 ----
  MG(64, 64, 0, 0, 0, 1, xb, Tl1, bl1, nullY, Ab);
  MG(64, 64, 0, 0, 0, 1, xb, Tr1, br1, nullY, Bb);
  agg_k<1, 64, 1, 0><<<(N + 3) / 4, 256, 0, stream>>>(Ab, Bb, att1, bo1, starts, deg,
                                                      esrc, bufC, N);
  ln_stats_k<<<1024, 256, 0, stream>>>(bufC, stats + 0, (size_t)N * 16);
  ln_apply_k<<<2048, 256, 0, stream>>>(bufC, Cb, stats + 0, ln1g, ln1b, (size_t)N * 16,
                                       63, 1.f / ((float)N * 64.f));

  // ---- conv2: heads=4, C=32, residual ----
  MG(64, 128, 0, 0, 1, 0, Cb, Tres2, nullf, bufD, nullB);
  MG(64, 128, 0, 0, 0, 1, Cb, Tl2, bl2, nullY, Ab);
  MG(64, 128, 0, 0, 0, 1, Cb, Tr2, br2, nullY, Bb);
  agg_k<4, 32, 2, 1><<<(N + 3) / 4, 256, 0, stream>>>(Ab, Bb, att2, bo2, starts, deg,
                                                      esrc, bufD, N);
  ln_stats_k<<<1024, 256, 0, stream>>>(bufD, stats + 2, (size_t)N * 32);
  ln_apply_k<<<2048, 256, 0, stream>>>(bufD, Db, stats + 2, ln2g, ln2b, (size_t)N * 32,
                                       127, 1.f / ((float)N * 128.f));

  // ---- conv3: heads=4, C=64, residual ----
  MG(128, 256, 0, 0, 1, 0, Db, Tres3, nullf, bufC, nullB);
  MG(128, 256, 0, 0, 0, 1, Db, Tl3, bl3, nullY, Ab);
  MG(128, 256, 0, 0, 0, 1, Db, Tr3, br3, nullY, Bb);
  agg_k<4, 64, 4, 1><<<(N + 3) / 4, 256, 0, stream>>>(Ab, Bb, att3, bo3, starts, deg,
                                                      esrc, bufC, N);
  ln_stats_k<<<1024, 256, 0, stream>>>(bufC, stats + 4, (size_t)N * 64);
  ln_apply_k<<<2048, 256, 0, stream>>>(bufC, Cb, stats + 4, ln3g, ln3b, (size_t)N * 64,
                                       255, 1.f / ((float)N * 256.f));

  // ---- encoder: z = relu(h3 @ encW + encb) + (x @ rpW + rpb) ----
  MG(64, 64, 0, 0, 1, 0, xb, Trp, rpb, z, nullB);       // z = x@rpW + rpb
  MG(256, 64, 1, 1, 1, 1, Cb, Tenc, encb, z, xb);       // z += relu(h3@encW+encb); zb=xb

  // ---- z_graph ----
  colmean_k<<<256, 256, 0, stream>>>(z, zg, N, 1.f / (float)N);

  // ---- decoder ----
  MG(64, 128, 1, 0, 0, 1, xb, Td1, d1b, nullY, Db);     // dh1b
  MG(128, 64, 1, 0, 0, 1, Db, Td2, d2b, nullY, Cb);     // dh2b
  MG(64, 64, 0, 0, 1, 0, Cb, Td3, d3b, xhat, nullB);    // x_hat
#undef MG
}

// Round 3
// 730.538 us; speedup vs baseline: 1.8639x; 1.4986x over previous
//
#include <hip/hip_runtime.h>
#include <math.h>

typedef __attribute__((ext_vector_type(8))) short short8;
typedef __attribute__((ext_vector_type(4))) float f32x4;

__device__ __forceinline__ unsigned short f2bf(float f) {
  union { float f; unsigned u; } c; c.f = f;
  unsigned r = c.u + 0x7fffu + ((c.u >> 16) & 1u);
  return (unsigned short)(r >> 16);
}
__device__ __forceinline__ float bf2f(unsigned short u) {
  union { unsigned u; float f; } c; c.u = ((unsigned)u) << 16;
  return c.f;
}

// ---------------- CSR build ----------------
__global__ void hist_k(const int* __restrict__ tgt, int* __restrict__ deg, int E) {
  int stride = gridDim.x * blockDim.x;
  for (int e = blockIdx.x * blockDim.x + threadIdx.x; e < E; e += stride)
    atomicAdd(&deg[tgt[e]], 1);
}

__global__ void scan1_k(const int* __restrict__ deg, int* __restrict__ bsum, int n) {
  __shared__ int sh[256];
  int idx = blockIdx.x * 256 + threadIdx.x;
  sh[threadIdx.x] = (idx < n) ? deg[idx] : 0;
  __syncthreads();
  for (int off = 128; off > 0; off >>= 1) {
    if (threadIdx.x < off) sh[threadIdx.x] += sh[threadIdx.x + off];
    __syncthreads();
  }
  if (threadIdx.x == 0) bsum[blockIdx.x] = sh[0];
}

__global__ void scan2_k(int* __restrict__ bsum, int nb) {
  __shared__ int sh[256];
  int t = threadIdx.x;
  int v = (t < nb) ? bsum[t] : 0;
  sh[t] = v; __syncthreads();
  for (int off = 1; off < 256; off <<= 1) {
    int add = (t >= off) ? sh[t - off] : 0;
    __syncthreads();
    sh[t] += add;
    __syncthreads();
  }
  if (t < nb) bsum[t] = sh[t] - v;  // exclusive
}

__global__ void scan3_k(const int* __restrict__ deg, const int* __restrict__ bsum,
                        int* __restrict__ starts, int* __restrict__ cursor, int n) {
  __shared__ int sh[256];
  int t = threadIdx.x;
  int idx = blockIdx.x * 256 + t;
  int v = (idx < n) ? deg[idx] : 0;
  sh[t] = v; __syncthreads();
  for (int off = 1; off < 256; off <<= 1) {
    int add = (t >= off) ? sh[t - off] : 0;
    __syncthreads();
    sh[t] += add;
    __syncthreads();
  }
  if (idx < n) {
    int ex = bsum[blockIdx.x] + sh[t] - v;
    starts[idx] = ex;
    cursor[idx] = ex;
  }
}

__global__ void scatter_k(const int* __restrict__ src, const int* __restrict__ tgt,
                          int* __restrict__ cursor, int* __restrict__ esrc, int E) {
  int stride = gridDim.x * blockDim.x;
  for (int e = blockIdx.x * blockDim.x + threadIdx.x; e < E; e += stride) {
    int p = atomicAdd(&cursor[tgt[e]], 1);
    esrc[p] = src[e];
  }
}

// ---------------- conversions ----------------
__global__ void cvt_k(const float* __restrict__ src, unsigned short* __restrict__ dst,
                      size_t n4) {
  size_t stride = (size_t)gridDim.x * blockDim.x;
  for (size_t i = (size_t)blockIdx.x * blockDim.x + threadIdx.x; i < n4; i += stride) {
    float4 v = reinterpret_cast<const float4*>(src)[i];
    ushort4 o;
    o.x = f2bf(v.x); o.y = f2bf(v.y); o.z = f2bf(v.z); o.w = f2bf(v.w);
    reinterpret_cast<ushort4*>(dst)[i] = o;
  }
}

// all weights fp32 [K,F] -> bf16 [F,K], one launch
struct WSeg { const float* W; unsigned short* T; int K; int F; int base; };
struct WPack { WSeg s[13]; int total; };
__global__ __launch_bounds__(256) void wconv_all_k(WPack p) {
  int idx = blockIdx.x * 256 + threadIdx.x;
  if (idx >= p.total) return;
  int si = 0;
#pragma unroll
  for (int i = 1; i < 13; ++i) si = (idx >= p.s[i].base) ? i : si;
  const WSeg sg = p.s[si];
  const int loc = idx - sg.base;
  const int k = loc / sg.F, f = loc - k * sg.F;
  sg.T[(size_t)f * sg.K + k] = f2bf(sg.W[loc]);
}

// ---------------- MFMA GEMM: Y[n,F] = act(Xbf[n,K] @ W + b) (+ X2@W2 + b2) ---
template <int K, int F, int ACT, int ACCUM, int WF32, int WBF, int K2>
__global__ __launch_bounds__(256) void mgemm_k(const unsigned short* __restrict__ X,
                                               const unsigned short* __restrict__ WT,
                                               const float* __restrict__ Bv,
                                               const unsigned short* __restrict__ X2,
                                               const unsigned short* __restrict__ WT2,
                                               const float* __restrict__ Bv2,
                                               float* __restrict__ Y,
                                               unsigned short* __restrict__ Yb, int n) {
  constexpr int NT = F / 16;  // 16-col tiles
  const int lane = threadIdx.x & 63;
  const int wave = threadIdx.x >> 6;
  const int r0 = (blockIdx.x * 4 + wave) * 16;
  const int rl = lane & 15;  // A row / B col within tile
  const int ks = lane >> 4;  // k-slot
  const int row = r0 + rl;
  const bool rok = row < n;

  f32x4 acc[NT];
#pragma unroll
  for (int t = 0; t < NT; ++t) acc[t] = (f32x4){0.f, 0.f, 0.f, 0.f};

  for (int kc = 0; kc < K; kc += 32) {
    short8 a = {0, 0, 0, 0, 0, 0, 0, 0};
    if (rok) a = *reinterpret_cast<const short8*>(&X[(size_t)row * K + kc + ks * 8]);
#pragma unroll
    for (int t = 0; t < NT; ++t) {
      short8 b = *reinterpret_cast<const short8*>(
          &WT[(size_t)(t * 16 + rl) * K + kc + ks * 8]);
      acc[t] = __builtin_amdgcn_mfma_f32_16x16x32_bf16(a, b, acc[t], 0, 0, 0);
    }
  }
  f32x4 acc2[K2 > 0 ? NT : 1];
  if constexpr (K2 > 0) {
#pragma unroll
    for (int t = 0; t < NT; ++t) acc2[t] = (f32x4){0.f, 0.f, 0.f, 0.f};
    for (int kc = 0; kc < K2; kc += 32) {
      short8 a = {0, 0, 0, 0, 0, 0, 0, 0};
      if (rok) a = *reinterpret_cast<const short8*>(&X2[(size_t)row * K2 + kc + ks * 8]);
#pragma unroll
      for (int t = 0; t < NT; ++t) {
        short8 b = *reinterpret_cast<const short8*>(
            &WT2[(size_t)(t * 16 + rl) * K2 + kc + ks * 8]);
        acc2[t] = __builtin_amdgcn_mfma_f32_16x16x32_bf16(a, b, acc2[t], 0, 0, 0);
      }
    }
  }
  // D: col = t*16 + (lane&15), row = r0 + (lane>>4)*4 + r
  const int rowd = r0 + ks * 4;
#pragma unroll
  for (int t = 0; t < NT; ++t) {
    const float bias = Bv ? Bv[t * 16 + rl] : 0.f;
#pragma unroll
    for (int r = 0; r < 4; ++r) {
      const int gr = rowd + r;
      if (gr >= n) continue;
      float o = acc[t][r] + bias;
      if (ACT) o = fmaxf(o, 0.f);
      if constexpr (K2 > 0) o += acc2[t][r] + Bv2[t * 16 + rl];
      const size_t idx = (size_t)gr * F + t * 16 + rl;
      if (ACCUM) o += Y[idx];
      if (WF32) Y[idx] = o;
      if (WBF) Yb[idx] = f2bf(o);
    }
  }
}

// ---------------- GATv2 edge aggregation ------------------------------------
template <int VEC> struct RawT;
template <> struct RawT<1> { using T = unsigned short; };
template <> struct RawT<2> { using T = unsigned; };
template <> struct RawT<4> { using T = unsigned long long; };

__device__ __forceinline__ void bdec(unsigned short u, float* o) { o[0] = bf2f(u); }
__device__ __forceinline__ void bdec(unsigned u, float* o) {
  o[0] = bf2f((unsigned short)(u & 0xffffu));
  o[1] = bf2f((unsigned short)(u >> 16));
}
__device__ __forceinline__ void bdec(unsigned long long u, float* o) {
  o[0] = bf2f((unsigned short)(u & 0xffffu));
  o[1] = bf2f((unsigned short)((u >> 16) & 0xffffu));
  o[2] = bf2f((unsigned short)((u >> 32) & 0xffffu));
  o[3] = bf2f((unsigned short)(u >> 48));
}

// one wave per target node; lane holds VEC=F/64 consecutive channels;
// head group = 64/H lanes; online softmax with defer-max; depth-1 prefetch.
template <int H, int C, int VEC, int HAS_RES>
__global__ __launch_bounds__(256) void agg_k(const unsigned short* __restrict__ xl,
                                             const unsigned short* __restrict__ xr,
                                             const float* __restrict__ att,
                                             const float* __restrict__ bo,
                                             const int* __restrict__ starts,
                                             const int* __restrict__ deg,
                                             const int* __restrict__ esrc,
                                             float* __restrict__ out, int n) {
  constexpr int F = H * C;
  constexpr int G = 64 / H;        // lanes per head group
  constexpr int CS = F / VEC;      // raw elements per row
  using RT = typename RawT<VEC>::T;
  const int lane = threadIdx.x & 63;
  const int node = blockIdx.x * 4 + (threadIdx.x >> 6);
  if (node >= n) return;
  const RT* xlr = reinterpret_cast<const RT*>(xl);

  float xri[VEC], av[VEC], acc[VEC];
  {
    RT rx = reinterpret_cast<const RT*>(xr)[(size_t)node * CS + lane];
    bdec(rx, xri);
  }
#pragma unroll
  for (int q = 0; q < VEC; ++q) {
    av[q] = att[lane * VEC + q];
    acc[q] = 0.f;
  }
  float m = -1e30f, s = 0.f;
  const int st = starts[node];
  const int cnt = deg[node];
  int j = (cnt > 0) ? esrc[st] : node;
  RT u = xlr[(size_t)j * CS + lane];
  for (int it = 0; it <= cnt; ++it) {
    RT un = u;
    if (it < cnt) {  // prefetch next row (last prefetch = self row)
      const int jn = (it + 1 < cnt) ? esrc[st + it + 1] : node;
      un = xlr[(size_t)jn * CS + lane];
    }
    float xj[VEC];
    bdec(u, xj);
    float e = 0.f;
#pragma unroll
    for (int q = 0; q < VEC; ++q) {
      float t = xri[q] + xj[q];
      t = (t > 0.f) ? t : 0.2f * t;  // leaky_relu(0.2)
      e = fmaf(t, av[q], e);
    }
#pragma unroll
    for (int mask = 1; mask < G; mask <<= 1) e += __shfl_xor(e, mask, 64);
    if (e - m > 8.f) {  // rare rescale (uniform within head group)
      const float sc = __expf(m - e);
      s *= sc;
#pragma unroll
      for (int q = 0; q < VEC; ++q) acc[q] *= sc;
      m = e;
    }
    const float p = __expf(e - m);
    s += p;
#pragma unroll
    for (int q = 0; q < VEC; ++q) acc[q] = fmaf(p, xj[q], acc[q]);
    u = un;
  }
  const float inv = 1.f / s;
#pragma unroll
  for (int q = 0; q < VEC; ++q) {
    const size_t idx = (size_t)node * F + lane * VEC + q;
    float o = acc[q] * inv + bo[lane * VEC + q];
    if (HAS_RES) o += out[idx];  // residual precomputed into out
    out[idx] = o;
  }
}

// ---------------- graph layernorm (global mean/var) + relu ------------------
// stage 1: per-block reduce -> atomicAdd into 16 spread bins (s1[16], s2[16])
__global__ __launch_bounds__(256) void ln_stats_k(const float* __restrict__ x,
                                                  float* __restrict__ bins, size_t n4) {
  size_t stride = (size_t)gridDim.x * blockDim.x;
  float s1 = 0.f, s2 = 0.f;
  for (size_t i = (size_t)blockIdx.x * blockDim.x + threadIdx.x; i < n4; i += stride) {
    float4 v = reinterpret_cast<const float4*>(x)[i];
    s1 += v.x + v.y + v.z + v.w;
    s2 += v.x * v.x + v.y * v.y + v.z * v.z + v.w * v.w;
  }
#pragma unroll
  for (int mm = 1; mm < 64; mm <<= 1) {
    s1 += __shfl_xor(s1, mm, 64);
    s2 += __shfl_xor(s2, mm, 64);
  }
  __shared__ float sh[8];
  const int w = threadIdx.x >> 6;
  if ((threadIdx.x & 63) == 0) { sh[w] = s1; sh[4 + w] = s2; }
  __syncthreads();
  if (threadIdx.x == 0) {
    const int bin = blockIdx.x & 15;
    atomicAdd(&bins[bin], sh[0] + sh[1] + sh[2] + sh[3]);
    atomicAdd(&bins[16 + bin], sh[4] + sh[5] + sh[6] + sh[7]);
  }
}

// stage 2: normalize + relu, write bf16 only (fp32 post-norm is never read)
__global__ __launch_bounds__(256) void ln_apply_k(const float* __restrict__ x,
                                                  unsigned short* __restrict__ xb,
                                                  const float* __restrict__ bins,
                                                  const float* __restrict__ g,
                                                  const float* __restrict__ b, size_t n4,
                                                  int fmask, float invNF) {
  float s1 = 0.f, s2 = 0.f;
#pragma unroll
  for (int i = 0; i < 16; ++i) { s1 += bins[i]; s2 += bins[16 + i]; }
  const float mu = s1 * invNF;
  const float var = s2 * invNF - mu * mu;
  const float rs = rsqrtf(var + 1e-5f);
  size_t stride = (size_t)gridDim.x * blockDim.x;
  for (size_t i = (size_t)blockIdx.x * blockDim.x + threadIdx.x; i < n4; i += stride) {
    float4 v = reinterpret_cast<const float4*>(x)[i];
    const int c0 = (int)((i * 4) & (size_t)fmask);
    ushort4 o;
    o.x = f2bf(fmaxf((v.x - mu) * rs * g[c0 + 0] + b[c0 + 0], 0.f));
    o.y = f2bf(fmaxf((v.y - mu) * rs * g[c0 + 1] + b[c0 + 1], 0.f));
    o.z = f2bf(fmaxf((v.z - mu) * rs * g[c0 + 2] + b[c0 + 2], 0.f));
    o.w = f2bf(fmaxf((v.w - mu) * rs * g[c0 + 3] + b[c0 + 3], 0.f));
    reinterpret_cast<ushort4*>(xb)[i] = o;
  }
}

// ---------------- column mean (z_graph) -------------------------------------
__global__ void colmean_k(const float* __restrict__ z, float* __restrict__ outv,
                          int n, float inv) {
  __shared__ float sh[256];
  int col = threadIdx.x & 63;
  int w = threadIdx.x >> 6;
  float s = 0.f;
  for (int r = blockIdx.x * 4 + w; r < n; r += gridDim.x * 4)
    s += z[(size_t)r * 64 + col];
  sh[threadIdx.x] = s;
  __syncthreads();
  if (threadIdx.x < 64) {
    float t = sh[threadIdx.x] + sh[threadIdx.x + 64] + sh[threadIdx.x + 128] +
              sh[threadIdx.x + 192];
    atomicAdd(&outv[col], t * inv);
  }
}

// ---------------------------------------------------------------------------
extern "C" void kernel_launch(void* const* d_in, const int* in_sizes, int n_in,
                              void* d_out, int out_size, void* d_ws, size_t ws_size,
                              hipStream_t stream) {
  const float* x = (const float*)d_in[0];
  const int* ei = (const int*)d_in[1];
  const float *Wl1 = (const float*)d_in[3], *bl1 = (const float*)d_in[4];
  const float *Wr1 = (const float*)d_in[5], *br1 = (const float*)d_in[6];
  const float *att1 = (const float*)d_in[7], *bo1 = (const float*)d_in[8];
  const float *Wl2 = (const float*)d_in[9], *bl2 = (const float*)d_in[10];
  const float *Wr2 = (const float*)d_in[11], *br2 = (const float*)d_in[12];
  const float *att2 = (const float*)d_in[13], *bo2 = (const float*)d_in[14];
  const float *Wres2 = (const float*)d_in[15];
  const float *Wl3 = (const float*)d_in[16], *bl3 = (const float*)d_in[17];
  const float *Wr3 = (const float*)d_in[18], *br3 = (const float*)d_in[19];
  const float *att3 = (const float*)d_in[20], *bo3 = (const float*)d_in[21];
  const float *Wres3 = (const float*)d_in[22];
  const float *ln1g = (const float*)d_in[23], *ln1b = (const float*)d_in[24];
  const float *ln2g = (const float*)d_in[25], *ln2b = (const float*)d_in[26];
  const float *ln3g = (const float*)d_in[27], *ln3b = (const float*)d_in[28];
  const float *encW = (const float*)d_in[29], *encb = (const float*)d_in[30];
  const float *rpW = (const float*)d_in[31], *rpb = (const float*)d_in[32];
  const float *d1W = (const float*)d_in[33], *d1b = (const float*)d_in[34];
  const float *d2W = (const float*)d_in[35], *d2b = (const float*)d_in[36];
  const float *d3W = (const float*)d_in[37], *d3b = (const float*)d_in[38];

  const int N = in_sizes[0] / 64;
  const int E = in_sizes[1] / 2;
  const int* esrc_in = ei;      // row 0: src
  const int* etgt_in = ei + E;  // row 1: tgt

  // ---- workspace layout ----
  char* cur = (char*)d_ws;
  auto take = [&](size_t bytes) {
    char* p = cur;
    cur += (bytes + 15) & ~(size_t)15;
    return p;
  };
  float* bufC = (float*)take((size_t)N * 256 * 4);                  // agg1/agg3 out
  float* bufD = (float*)take((size_t)N * 128 * 4);                  // agg2 out
  unsigned short* Ab = (unsigned short*)take((size_t)N * 256 * 2);  // xl (bf16)
  unsigned short* Bb = (unsigned short*)take((size_t)N * 256 * 2);  // xr (bf16)
  unsigned short* Cb = (unsigned short*)take((size_t)N * 256 * 2);  // h1b/h3b/dh2b
  unsigned short* Db = (unsigned short*)take((size_t)N * 128 * 2);  // h2b/dh1b
  unsigned short* xb = (unsigned short*)take((size_t)N * 64 * 2);   // xbf / zb
  float* stats = (float*)take(96 * 4);                              // 3 x 32 bins
  int* deg = (int*)take((size_t)N * 4);
  int* starts = (int*)take((size_t)N * 4);
  int* cursor = (int*)take((size_t)N * 4);
  int* bsum = (int*)take(1024);
  int* esrc = (int*)take((size_t)E * 4);
  auto wt = [&](int K, int F) { return (unsigned short*)take((size_t)K * F * 2); };
  unsigned short *Tl1 = wt(64, 64), *Tr1 = wt(64, 64);
  unsigned short *Tl2 = wt(64, 128), *Tr2 = wt(64, 128), *Tres2 = wt(64, 128);
  unsigned short *Tl3 = wt(128, 256), *Tr3 = wt(128, 256), *Tres3 = wt(128, 256);
  unsigned short *Tenc = wt(256, 64), *Trp = wt(64, 64);
  unsigned short *Td1 = wt(64, 128), *Td2 = wt(128, 64), *Td3 = wt(64, 64);
  if ((size_t)(cur - (char*)d_ws) > ws_size) return;

  float* z = (float*)d_out;           // z_nodes (N x 64)
  float* xhat = z + (size_t)N * 64;   // x_hat   (N x 64)
  float* zg = xhat + (size_t)N * 64;  // z_graph (64)

  hipMemsetAsync(deg, 0, (size_t)N * sizeof(int), stream);
  hipMemsetAsync(stats, 0, 96 * 4, stream);
  hipMemsetAsync(zg, 0, 64 * sizeof(float), stream);

  // ---- weight conversion: one fused launch ----
  {
    WPack p;
    const float* Ws[13] = {Wl1, Wr1, Wl2, Wr2, Wres2, Wl3, Wr3, Wres3,
                           encW, rpW, d1W, d2W, d3W};
    unsigned short* Ts[13] = {Tl1, Tr1, Tl2, Tr2, Tres2, Tl3, Tr3, Tres3,
                              Tenc, Trp, Td1, Td2, Td3};
    const int Ks[13] = {64, 64, 64, 64, 64, 128, 128, 128, 256, 64, 64, 128, 64};
    const int Fs[13] = {64, 64, 128, 128, 128, 256, 256, 256, 64, 64, 128, 64, 64};
    int base = 0;
    for (int i = 0; i < 13; ++i) {
      p.s[i] = {Ws[i], Ts[i], Ks[i], Fs[i], base};
      base += Ks[i] * Fs[i];
    }
    p.total = base;
    wconv_all_k<<<(base + 255) / 256, 256, 0, stream>>>(p);
  }
  cvt_k<<<1024, 256, 0, stream>>>(x, xb, (size_t)N * 16);

  // ---- CSR by target ----
  const int nb = (N + 255) / 256;
  hist_k<<<512, 256, 0, stream>>>(etgt_in, deg, E);
  scan1_k<<<nb, 256, 0, stream>>>(deg, bsum, N);
  scan2_k<<<1, 256, 0, stream>>>(bsum, nb);
  scan3_k<<<nb, 256, 0, stream>>>(deg, bsum, starts, cursor, N);
  scatter_k<<<512, 256, 0, stream>>>(esrc_in, etgt_in, cursor, esrc, E);

  const int gblk = (N + 63) / 64;
  const float* nullf = nullptr;
  float* nullY = nullptr;
  unsigned short* nullB = nullptr;
#define MG(K, F, ACT, ACCUM, WF32, WBF, X, WT, B, Y, YB) \
  mgemm_k<K, F, ACT, ACCUM, WF32, WBF, 0>                \
      <<<gblk, 256, 0, stream>>>(X, WT, B, nullB, nullB, nullf, Y, YB, N)

  // ---- conv1: heads=1, C=64 ----
  MG(64, 64, 0, 0, 0, 1, xb, Tl1, bl1, nullY, Ab);
  MG(64, 64, 0, 0, 0, 1, xb, Tr1, br1, nullY, Bb);
  agg_k<1, 64, 1, 0><<<(N + 3) / 4, 256, 0, stream>>>(Ab, Bb, att1, bo1, starts, deg,
                                                      esrc, bufC, N);
  ln_stats_k<<<512, 256, 0, stream>>>(bufC, stats + 0, (size_t)N * 16);
  ln_apply_k<<<1024, 256, 0, stream>>>(bufC, Cb, stats + 0, ln1g, ln1b, (size_t)N * 16,
                                       63, 1.f / ((float)N * 64.f));

  // ---- conv2: heads=4, C=32, residual ----
  MG(64, 128, 0, 0, 1, 0, Cb, Tres2, nullf, bufD, nullB);
  MG(64, 128, 0, 0, 0, 1, Cb, Tl2, bl2, nullY, Ab);
  MG(64, 128, 0, 0, 0, 1, Cb, Tr2, br2, nullY, Bb);
  agg_k<4, 32, 2, 1><<<(N + 3) / 4, 256, 0, stream>>>(Ab, Bb, att2, bo2, starts, deg,
                                                      esrc, bufD, N);
  ln_stats_k<<<512, 256, 0, stream>>>(bufD, stats + 32, (size_t)N * 32);
  ln_apply_k<<<1024, 256, 0, stream>>>(bufD, Db, stats + 32, ln2g, ln2b, (size_t)N * 32,
                                       127, 1.f / ((float)N * 128.f));

  // ---- conv3: heads=4, C=64, residual ----
  MG(128, 256, 0, 0, 1, 0, Db, Tres3, nullf, bufC, nullB);
  MG(128, 256, 0, 0, 0, 1, Db, Tl3, bl3, nullY, Ab);
  MG(128, 256, 0, 0, 0, 1, Db, Tr3, br3, nullY, Bb);
  agg_k<4, 64, 4, 1><<<(N + 3) / 4, 256, 0, stream>>>(Ab, Bb, att3, bo3, starts, deg,
                                                      esrc, bufC, N);
  ln_stats_k<<<512, 256, 0, stream>>>(bufC, stats + 64, (size_t)N * 64);
  ln_apply_k<<<1024, 256, 0, stream>>>(bufC, Cb, stats + 64, ln3g, ln3b, (size_t)N * 64,
                                       255, 1.f / ((float)N * 256.f));

  // ---- encoder (fused): z = relu(h3@encW + encb) + (x@rpW + rpb); zb -> xb ----
  mgemm_k<256, 64, 1, 0, 1, 1, 64><<<gblk, 256, 0, stream>>>(Cb, Tenc, encb, xb, Trp,
                                                             rpb, z, xb, N);

  // ---- z_graph ----
  colmean_k<<<256, 256, 0, stream>>>(z, zg, N, 1.f / (float)N);

  // ---- decoder ----
  MG(64, 128, 1, 0, 0, 1, xb, Td1, d1b, nullY, Db);   // dh1b
  MG(128, 64, 1, 0, 0, 1, Db, Td2, d2b, nullY, Cb);   // dh2b
  MG(64, 64, 0, 0, 1, 0, Cb, Td3, d3b, xhat, nullB);  // x_hat
#undef MG
}

// Round 4
// 670.563 us; speedup vs baseline: 2.0306x; 1.0894x over previous
//
#include <hip/hip_runtime.h>
#include <math.h>

typedef __attribute__((ext_vector_type(8))) short short8;
typedef __attribute__((ext_vector_type(4))) float f32x4;

__device__ __forceinline__ unsigned short f2bf(float f) {
  union { float f; unsigned u; } c; c.f = f;
  unsigned r = c.u + 0x7fffu + ((c.u >> 16) & 1u);
  return (unsigned short)(r >> 16);
}
__device__ __forceinline__ float bf2f(unsigned short u) {
  union { unsigned u; float f; } c; c.u = ((unsigned)u) << 16;
  return c.f;
}

// ---------------- init ----------------
__global__ void zero_k(int* __restrict__ deg, int n, float* __restrict__ stats,
                       float* __restrict__ zg) {
  int i = blockIdx.x * 256 + threadIdx.x;
  if (i < n) deg[i] = 0;
  if (i < 768) stats[i] = 0.f;
  if (i < 64) zg[i] = 0.f;
}

// ---------------- CSR build ----------------
__global__ void hist_k(const int* __restrict__ tgt, int* __restrict__ deg, int E) {
  int stride = gridDim.x * blockDim.x;
  for (int e = blockIdx.x * blockDim.x + threadIdx.x; e < E; e += stride)
    atomicAdd(&deg[tgt[e]], 1);
}

__global__ void scan1_k(const int* __restrict__ deg, int* __restrict__ bsum, int n) {
  __shared__ int sh[256];
  int idx = blockIdx.x * 256 + threadIdx.x;
  sh[threadIdx.x] = (idx < n) ? deg[idx] : 0;
  __syncthreads();
  for (int off = 128; off > 0; off >>= 1) {
    if (threadIdx.x < off) sh[threadIdx.x] += sh[threadIdx.x + off];
    __syncthreads();
  }
  if (threadIdx.x == 0) bsum[blockIdx.x] = sh[0];
}

__global__ void scan2_k(int* __restrict__ bsum, int nb) {
  __shared__ int sh[256];
  int t = threadIdx.x;
  int v = (t < nb) ? bsum[t] : 0;
  sh[t] = v; __syncthreads();
  for (int off = 1; off < 256; off <<= 1) {
    int add = (t >= off) ? sh[t - off] : 0;
    __syncthreads();
    sh[t] += add;
    __syncthreads();
  }
  if (t < nb) bsum[t] = sh[t] - v;  // exclusive
}

__global__ void scan3_k(const int* __restrict__ deg, const int* __restrict__ bsum,
                        int* __restrict__ starts, int* __restrict__ cursor, int n) {
  __shared__ int sh[256];
  int t = threadIdx.x;
  int idx = blockIdx.x * 256 + t;
  int v = (idx < n) ? deg[idx] : 0;
  sh[t] = v; __syncthreads();
  for (int off = 1; off < 256; off <<= 1) {
    int add = (t >= off) ? sh[t - off] : 0;
    __syncthreads();
    sh[t] += add;
    __syncthreads();
  }
  if (idx < n) {
    int ex = bsum[blockIdx.x] + sh[t] - v;
    starts[idx] = ex;
    cursor[idx] = ex;
  }
}

__global__ void scatter_k(const int* __restrict__ src, const int* __restrict__ tgt,
                          int* __restrict__ cursor, int* __restrict__ esrc, int E) {
  int stride = gridDim.x * blockDim.x;
  for (int e = blockIdx.x * blockDim.x + threadIdx.x; e < E; e += stride) {
    int p = atomicAdd(&cursor[tgt[e]], 1);
    esrc[p] = src[e];
  }
}

// ---------------- conversions ----------------
__global__ void cvt_k(const float* __restrict__ src, unsigned short* __restrict__ dst,
                      size_t n4) {
  size_t stride = (size_t)gridDim.x * blockDim.x;
  for (size_t i = (size_t)blockIdx.x * blockDim.x + threadIdx.x; i < n4; i += stride) {
    float4 v = reinterpret_cast<const float4*>(src)[i];
    ushort4 o;
    o.x = f2bf(v.x); o.y = f2bf(v.y); o.z = f2bf(v.z); o.w = f2bf(v.w);
    reinterpret_cast<ushort4*>(dst)[i] = o;
  }
}

struct WSeg { const float* W; unsigned short* T; int K; int F; int base; };
struct WPack { WSeg s[13]; int total; };
__global__ __launch_bounds__(256) void wconv_all_k(WPack p) {
  int idx = blockIdx.x * 256 + threadIdx.x;
  if (idx >= p.total) return;
  int si = 0;
#pragma unroll
  for (int i = 1; i < 13; ++i) si = (idx >= p.s[i].base) ? i : si;
  const WSeg sg = p.s[si];
  const int loc = idx - sg.base;
  const int k = loc / sg.F, f = loc - k * sg.F;
  sg.T[(size_t)f * sg.K + k] = f2bf(sg.W[loc]);
}

// ---------------- fused per-layer GEMM (xl, xr, [res]) with inline LN -------
// A (node feats) loaded+normalized once into bf16 fragments, then SETS B-sweeps.
template <int K, int F, int SETS, int LNF, int BF16IN>
__global__ __launch_bounds__(256) void mg3_k(
    const void* __restrict__ Xv, const float* __restrict__ bins,
    const float* __restrict__ lng, const float* __restrict__ lnb, float invNF,
    const unsigned short* __restrict__ WT0, const float* __restrict__ B0,
    const unsigned short* __restrict__ WT1, const float* __restrict__ B1,
    const unsigned short* __restrict__ WT2,  // residual, no bias, fp32 out
    unsigned short* __restrict__ Y0, unsigned short* __restrict__ Y1,
    float* __restrict__ Y2, int n) {
  constexpr int NT = F / 16;
  constexpr int NK = K / 32;
  const int lane = threadIdx.x & 63;
  const int wave = threadIdx.x >> 6;
  const int r0 = (blockIdx.x * 4 + wave) * 16;
  const int rl = lane & 15;
  const int ks = lane >> 4;
  const int row = r0 + rl;
  const bool rok = row < n;

  float mu = 0.f, rs = 0.f;
  if (LNF) {  // reduce 128+128 spread bins (uniform -> scalar loads)
    float s1 = 0.f, s2 = 0.f;
    const float4* b4 = (const float4*)bins;
#pragma unroll
    for (int i = 0; i < 32; ++i) { float4 v = b4[i]; s1 += v.x + v.y + v.z + v.w; }
#pragma unroll
    for (int i = 32; i < 64; ++i) { float4 v = b4[i]; s2 += v.x + v.y + v.z + v.w; }
    mu = s1 * invNF;
    rs = rsqrtf(s2 * invNF - mu * mu + 1e-5f);
  }

  short8 afrag[NK];
#pragma unroll
  for (int kk = 0; kk < NK; ++kk) {
    short8 a = {0, 0, 0, 0, 0, 0, 0, 0};
    const int kb = kk * 32 + ks * 8;
    if (rok) {
      if (BF16IN) {
        a = *reinterpret_cast<const short8*>((const unsigned short*)Xv +
                                             (size_t)row * K + kb);
      } else {
        const float* Xf = (const float*)Xv + (size_t)row * K + kb;
        float v[8];
        *(float4*)&v[0] = *(const float4*)&Xf[0];
        *(float4*)&v[4] = *(const float4*)&Xf[4];
        if (LNF) {
          float g[8], bb[8];
          *(float4*)&g[0] = *(const float4*)&lng[kb];
          *(float4*)&g[4] = *(const float4*)&lng[kb + 4];
          *(float4*)&bb[0] = *(const float4*)&lnb[kb];
          *(float4*)&bb[4] = *(const float4*)&lnb[kb + 4];
#pragma unroll
          for (int q = 0; q < 8; ++q)
            v[q] = fmaxf(fmaf(v[q] - mu, rs * g[q], bb[q]), 0.f);  // LN + relu
        }
#pragma unroll
        for (int q = 0; q < 8; ++q) a[q] = (short)f2bf(v[q]);
      }
    }
    afrag[kk] = a;
  }

  const int rowd = r0 + ks * 4;
  for (int set = 0; set < SETS; ++set) {
    const unsigned short* WT = (set == 0) ? WT0 : (set == 1) ? WT1 : WT2;
    f32x4 acc[NT];
#pragma unroll
    for (int t = 0; t < NT; ++t) acc[t] = (f32x4){0.f, 0.f, 0.f, 0.f};
#pragma unroll
    for (int kk = 0; kk < NK; ++kk) {
#pragma unroll
      for (int t = 0; t < NT; ++t) {
        short8 b = *reinterpret_cast<const short8*>(
            &WT[(size_t)(t * 16 + rl) * K + kk * 32 + ks * 8]);
        acc[t] = __builtin_amdgcn_mfma_f32_16x16x32_bf16(afrag[kk], b, acc[t], 0, 0, 0);
      }
    }
    if (set < 2) {
      const float* Bv = (set == 0) ? B0 : B1;
      unsigned short* Y = (set == 0) ? Y0 : Y1;
#pragma unroll
      for (int t = 0; t < NT; ++t) {
        const float bias = Bv[t * 16 + rl];
#pragma unroll
        for (int r = 0; r < 4; ++r) {
          const int gr = rowd + r;
          if (gr < n) Y[(size_t)gr * F + t * 16 + rl] = f2bf(acc[t][r] + bias);
        }
      }
    } else {
#pragma unroll
      for (int t = 0; t < NT; ++t) {
#pragma unroll
        for (int r = 0; r < 4; ++r) {
          const int gr = rowd + r;
          if (gr < n) Y2[(size_t)gr * F + t * 16 + rl] = acc[t][r];
        }
      }
    }
  }
}

// ---------------- encoder: z = relu(LN3(h3)@We+be) + xb@Wrp+brp -------------
template <int K1, int K2, int F>
__global__ __launch_bounds__(256) void enc_k(
    const float* __restrict__ h3, const float* __restrict__ bins,
    const float* __restrict__ lng, const float* __restrict__ lnb, float invNF,
    const unsigned short* __restrict__ WTe, const float* __restrict__ Be,
    const unsigned short* __restrict__ xb, const unsigned short* __restrict__ WTrp,
    const float* __restrict__ Brp, float* __restrict__ z,
    unsigned short* __restrict__ zb, int n) {
  constexpr int NT = F / 16;
  constexpr int NK1 = K1 / 32;
  constexpr int NK2 = K2 / 32;
  const int lane = threadIdx.x & 63;
  const int wave = threadIdx.x >> 6;
  const int r0 = (blockIdx.x * 4 + wave) * 16;
  const int rl = lane & 15;
  const int ks = lane >> 4;
  const int row = r0 + rl;
  const bool rok = row < n;

  float s1 = 0.f, s2 = 0.f;
  const float4* b4 = (const float4*)bins;
#pragma unroll
  for (int i = 0; i < 32; ++i) { float4 v = b4[i]; s1 += v.x + v.y + v.z + v.w; }
#pragma unroll
  for (int i = 32; i < 64; ++i) { float4 v = b4[i]; s2 += v.x + v.y + v.z + v.w; }
  const float mu = s1 * invNF;
  const float rs = rsqrtf(s2 * invNF - mu * mu + 1e-5f);

  f32x4 acc1[NT], acc2[NT];
#pragma unroll
  for (int t = 0; t < NT; ++t) {
    acc1[t] = (f32x4){0.f, 0.f, 0.f, 0.f};
    acc2[t] = (f32x4){0.f, 0.f, 0.f, 0.f};
  }
#pragma unroll
  for (int kk = 0; kk < NK1; ++kk) {
    short8 a = {0, 0, 0, 0, 0, 0, 0, 0};
    const int kb = kk * 32 + ks * 8;
    if (rok) {
      const float* Xf = h3 + (size_t)row * K1 + kb;
      float v[8], g[8], bb[8];
      *(float4*)&v[0] = *(const float4*)&Xf[0];
      *(float4*)&v[4] = *(const float4*)&Xf[4];
      *(float4*)&g[0] = *(const float4*)&lng[kb];
      *(float4*)&g[4] = *(const float4*)&lng[kb + 4];
      *(float4*)&bb[0] = *(const float4*)&lnb[kb];
      *(float4*)&bb[4] = *(const float4*)&lnb[kb + 4];
#pragma unroll
      for (int q = 0; q < 8; ++q) {
        float t = fmaxf(fmaf(v[q] - mu, rs * g[q], bb[q]), 0.f);
        a[q] = (short)f2bf(t);
      }
    }
#pragma unroll
    for (int t = 0; t < NT; ++t) {
      short8 b = *reinterpret_cast<const short8*>(
          &WTe[(size_t)(t * 16 + rl) * K1 + kk * 32 + ks * 8]);
      acc1[t] = __builtin_amdgcn_mfma_f32_16x16x32_bf16(a, b, acc1[t], 0, 0, 0);
    }
  }
#pragma unroll
  for (int kk = 0; kk < NK2; ++kk) {
    short8 a = {0, 0, 0, 0, 0, 0, 0, 0};
    if (rok)
      a = *reinterpret_cast<const short8*>(&xb[(size_t)row * K2 + kk * 32 + ks * 8]);
#pragma unroll
    for (int t = 0; t < NT; ++t) {
      short8 b = *reinterpret_cast<const short8*>(
          &WTrp[(size_t)(t * 16 + rl) * K2 + kk * 32 + ks * 8]);
      acc2[t] = __builtin_amdgcn_mfma_f32_16x16x32_bf16(a, b, acc2[t], 0, 0, 0);
    }
  }
  const int rowd = r0 + ks * 4;
#pragma unroll
  for (int t = 0; t < NT; ++t) {
    const float be = Be[t * 16 + rl];
    const float brp = Brp[t * 16 + rl];
#pragma unroll
    for (int r = 0; r < 4; ++r) {
      const int gr = rowd + r;
      if (gr >= n) continue;
      const float o = fmaxf(acc1[t][r] + be, 0.f) + acc2[t][r] + brp;
      const size_t idx = (size_t)gr * F + t * 16 + rl;
      z[idx] = o;
      zb[idx] = f2bf(o);
    }
  }
}

// ---------------- decoder GEMM ----------------------------------------------
template <int K, int F, int ACT, int WF32, int WBF>
__global__ __launch_bounds__(256) void mgemm_k(const unsigned short* __restrict__ X,
                                               const unsigned short* __restrict__ WT,
                                               const float* __restrict__ Bv,
                                               float* __restrict__ Y,
                                               unsigned short* __restrict__ Yb, int n) {
  constexpr int NT = F / 16;
  const int lane = threadIdx.x & 63;
  const int wave = threadIdx.x >> 6;
  const int r0 = (blockIdx.x * 4 + wave) * 16;
  const int rl = lane & 15;
  const int ks = lane >> 4;
  const int row = r0 + rl;
  const bool rok = row < n;

  f32x4 acc[NT];
#pragma unroll
  for (int t = 0; t < NT; ++t) acc[t] = (f32x4){0.f, 0.f, 0.f, 0.f};
  for (int kc = 0; kc < K; kc += 32) {
    short8 a = {0, 0, 0, 0, 0, 0, 0, 0};
    if (rok) a = *reinterpret_cast<const short8*>(&X[(size_t)row * K + kc + ks * 8]);
#pragma unroll
    for (int t = 0; t < NT; ++t) {
      short8 b = *reinterpret_cast<const short8*>(
          &WT[(size_t)(t * 16 + rl) * K + kc + ks * 8]);
      acc[t] = __builtin_amdgcn_mfma_f32_16x16x32_bf16(a, b, acc[t], 0, 0, 0);
    }
  }
  const int rowd = r0 + ks * 4;
#pragma unroll
  for (int t = 0; t < NT; ++t) {
    const float bias = Bv[t * 16 + rl];
#pragma unroll
    for (int r = 0; r < 4; ++r) {
      const int gr = rowd + r;
      if (gr >= n) continue;
      float o = acc[t][r] + bias;
      if (ACT) o = fmaxf(o, 0.f);
      const size_t idx = (size_t)gr * F + t * 16 + rl;
      if (WF32) Y[idx] = o;
      if (WBF) Yb[idx] = f2bf(o);
    }
  }
}

// ---------------- GATv2 edge aggregation ------------------------------------
template <int VEC> struct RawT;
template <> struct RawT<1> { using T = unsigned short; };
template <> struct RawT<2> { using T = unsigned; };
template <> struct RawT<4> { using T = unsigned long long; };

__device__ __forceinline__ void bdec(unsigned short u, float* o) { o[0] = bf2f(u); }
__device__ __forceinline__ void bdec(unsigned u, float* o) {
  o[0] = bf2f((unsigned short)(u & 0xffffu));
  o[1] = bf2f((unsigned short)(u >> 16));
}
__device__ __forceinline__ void bdec(unsigned long long u, float* o) {
  o[0] = bf2f((unsigned short)(u & 0xffffu));
  o[1] = bf2f((unsigned short)((u >> 16) & 0xffffu));
  o[2] = bf2f((unsigned short)((u >> 32) & 0xffffu));
  o[3] = bf2f((unsigned short)(u >> 48));
}

// one wave per target node; 2-edge unrolled online softmax; epilogue
// accumulates graph-LN stats into 128 spread bins.
template <int H, int C, int VEC, int HAS_RES>
__global__ __launch_bounds__(256) void agg_k(
    const unsigned short* __restrict__ xl, const unsigned short* __restrict__ xr,
    const float* __restrict__ att, const float* __restrict__ bo,
    const int* __restrict__ starts, const int* __restrict__ deg,
    const int* __restrict__ esrc, float* __restrict__ out,
    float* __restrict__ bins, int n) {
  constexpr int F = H * C;
  constexpr int G = 64 / H;    // lanes per head group
  constexpr int CS = F / VEC;  // raw elements per row
  using RT = typename RawT<VEC>::T;
  const int lane = threadIdx.x & 63;
  const int wv = threadIdx.x >> 6;
  const int node = blockIdx.x * 4 + wv;
  const bool active = node < n;
  float s1w = 0.f, s2w = 0.f;

  if (active) {
    const RT* xlr = reinterpret_cast<const RT*>(xl);
    float xri[VEC], av[VEC], acc[VEC];
    {
      RT rx = reinterpret_cast<const RT*>(xr)[(size_t)node * CS + lane];
      bdec(rx, xri);
    }
#pragma unroll
    for (int q = 0; q < VEC; ++q) {
      av[q] = att[lane * VEC + q];
      acc[q] = 0.f;
    }
    float m = -1e30f, s = 0.f;
    const int st = starts[node];
    const int cnt = deg[node];
    const int total = cnt + 1;  // + self loop
    RT u0, u1 = 0;
    {
      int j0 = (cnt > 0) ? esrc[st] : node;
      u0 = xlr[(size_t)j0 * CS + lane];
    }
    if (total > 1) {
      int j1 = (1 < cnt) ? esrc[st + 1] : node;
      u1 = xlr[(size_t)j1 * CS + lane];
    }
    int it = 0;
    for (; it + 2 <= total; it += 2) {
      RT n0 = u0, n1 = u1;
      if (it + 2 < total) {
        int jn = (it + 2 < cnt) ? esrc[st + it + 2] : node;
        n0 = xlr[(size_t)jn * CS + lane];
      }
      if (it + 3 < total) {
        int jn = (it + 3 < cnt) ? esrc[st + it + 3] : node;
        n1 = xlr[(size_t)jn * CS + lane];
      }
      float x0[VEC], x1[VEC];
      bdec(u0, x0);
      bdec(u1, x1);
      float e0 = 0.f, e1 = 0.f;
#pragma unroll
      for (int q = 0; q < VEC; ++q) {
        float t0 = xri[q] + x0[q];
        float t1 = xri[q] + x1[q];
        t0 = (t0 > 0.f) ? t0 : 0.2f * t0;
        t1 = (t1 > 0.f) ? t1 : 0.2f * t1;
        e0 = fmaf(t0, av[q], e0);
        e1 = fmaf(t1, av[q], e1);
      }
#pragma unroll
      for (int mask = 1; mask < G; mask <<= 1) {
        e0 += __shfl_xor(e0, mask, 64);
        e1 += __shfl_xor(e1, mask, 64);
      }
      const float eM = fmaxf(e0, e1);
      if (eM - m > 8.f) {
        const float sc = __expf(m - eM);
        s *= sc;
#pragma unroll
        for (int q = 0; q < VEC; ++q) acc[q] *= sc;
        m = eM;
      }
      const float p0 = __expf(e0 - m);
      const float p1 = __expf(e1 - m);
      s += p0 + p1;
#pragma unroll
      for (int q = 0; q < VEC; ++q)
        acc[q] = fmaf(p0, x0[q], fmaf(p1, x1[q], acc[q]));
      u0 = n0;
      u1 = n1;
    }
    if (it < total) {  // odd tail
      float x0[VEC];
      bdec(u0, x0);
      float e0 = 0.f;
#pragma unroll
      for (int q = 0; q < VEC; ++q) {
        float t0 = xri[q] + x0[q];
        t0 = (t0 > 0.f) ? t0 : 0.2f * t0;
        e0 = fmaf(t0, av[q], e0);
      }
#pragma unroll
      for (int mask = 1; mask < G; mask <<= 1) e0 += __shfl_xor(e0, mask, 64);
      if (e0 - m > 8.f) {
        const float sc = __expf(m - e0);
        s *= sc;
#pragma unroll
        for (int q = 0; q < VEC; ++q) acc[q] *= sc;
        m = e0;
      }
      const float p0 = __expf(e0 - m);
      s += p0;
#pragma unroll
      for (int q = 0; q < VEC; ++q) acc[q] = fmaf(p0, x0[q], acc[q]);
    }
    const float inv = 1.f / s;
#pragma unroll
    for (int q = 0; q < VEC; ++q) {
      const size_t idx = (size_t)node * F + lane * VEC + q;
      float o = acc[q] * inv + bo[lane * VEC + q];
      if (HAS_RES) o += out[idx];  // residual precomputed into out
      out[idx] = o;
      s1w += o;
      s2w += o * o;
    }
  }
  // graph-LN stats: wave reduce -> block combine -> 2 atomics into spread bins
#pragma unroll
  for (int mask = 1; mask < 64; mask <<= 1) {
    s1w += __shfl_xor(s1w, mask, 64);
    s2w += __shfl_xor(s2w, mask, 64);
  }
  __shared__ float sh[8];
  if (lane == 0) { sh[wv] = s1w; sh[4 + wv] = s2w; }
  __syncthreads();
  if (threadIdx.x == 0) {
    const int bin = blockIdx.x & 127;
    atomicAdd(&bins[bin], sh[0] + sh[1] + sh[2] + sh[3]);
    atomicAdd(&bins[128 + bin], sh[4] + sh[5] + sh[6] + sh[7]);
  }
}

// ---------------- column mean (z_graph) -------------------------------------
__global__ void colmean_k(const float* __restrict__ z, float* __restrict__ outv,
                          int n, float inv) {
  __shared__ float sh[256];
  int col = threadIdx.x & 63;
  int w = threadIdx.x >> 6;
  float s = 0.f;
  for (int r = blockIdx.x * 4 + w; r < n; r += gridDim.x * 4)
    s += z[(size_t)r * 64 + col];
  sh[threadIdx.x] = s;
  __syncthreads();
  if (threadIdx.x < 64) {
    float t = sh[threadIdx.x] + sh[threadIdx.x + 64] + sh[threadIdx.x + 128] +
              sh[threadIdx.x + 192];
    atomicAdd(&outv[col], t * inv);
  }
}

// ---------------------------------------------------------------------------
extern "C" void kernel_launch(void* const* d_in, const int* in_sizes, int n_in,
                              void* d_out, int out_size, void* d_ws, size_t ws_size,
                              hipStream_t stream) {
  const float* x = (const float*)d_in[0];
  const int* ei = (const int*)d_in[1];
  const float *Wl1 = (const float*)d_in[3], *bl1 = (const float*)d_in[4];
  const float *Wr1 = (const float*)d_in[5], *br1 = (const float*)d_in[6];
  const float *att1 = (const float*)d_in[7], *bo1 = (const float*)d_in[8];
  const float *Wl2 = (const float*)d_in[9], *bl2 = (const float*)d_in[10];
  const float *Wr2 = (const float*)d_in[11], *br2 = (const float*)d_in[12];
  const float *att2 = (const float*)d_in[13], *bo2 = (const float*)d_in[14];
  const float *Wres2 = (const float*)d_in[15];
  const float *Wl3 = (const float*)d_in[16], *bl3 = (const float*)d_in[17];
  const float *Wr3 = (const float*)d_in[18], *br3 = (const float*)d_in[19];
  const float *att3 = (const float*)d_in[20], *bo3 = (const float*)d_in[21];
  const float *Wres3 = (const float*)d_in[22];
  const float *ln1g = (const float*)d_in[23], *ln1b = (const float*)d_in[24];
  const float *ln2g = (const float*)d_in[25], *ln2b = (const float*)d_in[26];
  const float *ln3g = (const float*)d_in[27], *ln3b = (const float*)d_in[28];
  const float *encW = (const float*)d_in[29], *encb = (const float*)d_in[30];
  const float *rpW = (const float*)d_in[31], *rpb = (const float*)d_in[32];
  const float *d1W = (const float*)d_in[33], *d1b = (const float*)d_in[34];
  const float *d2W = (const float*)d_in[35], *d2b = (const float*)d_in[36];
  const float *d3W = (const float*)d_in[37], *d3b = (const float*)d_in[38];

  const int N = in_sizes[0] / 64;
  const int E = in_sizes[1] / 2;
  const int* esrc_in = ei;      // row 0: src
  const int* etgt_in = ei + E;  // row 1: tgt

  // ---- workspace layout ----
  char* cur = (char*)d_ws;
  auto take = [&](size_t bytes) {
    char* p = cur;
    cur += (bytes + 15) & ~(size_t)15;
    return p;
  };
  float* bufC = (float*)take((size_t)N * 256 * 4);                  // h1 / h3 (fp32)
  float* bufD = (float*)take((size_t)N * 128 * 4);                  // h2 (fp32)
  unsigned short* Ab = (unsigned short*)take((size_t)N * 256 * 2);  // xl (bf16)
  unsigned short* Bb = (unsigned short*)take((size_t)N * 256 * 2);  // xr (bf16)
  unsigned short* Cb = (unsigned short*)take((size_t)N * 256 * 2);  // dh2b
  unsigned short* Db = (unsigned short*)take((size_t)N * 128 * 2);  // dh1b
  unsigned short* xb = (unsigned short*)take((size_t)N * 64 * 2);   // xbf -> zb
  float* stats = (float*)take(768 * 4);                             // 3 x (128+128)
  int* deg = (int*)take((size_t)N * 4);
  int* starts = (int*)take((size_t)N * 4);
  int* cursor = (int*)take((size_t)N * 4);
  int* bsum = (int*)take(1024);
  int* esrc = (int*)take((size_t)E * 4);
  auto wt = [&](int K, int F) { return (unsigned short*)take((size_t)K * F * 2); };
  unsigned short *Tl1 = wt(64, 64), *Tr1 = wt(64, 64);
  unsigned short *Tl2 = wt(64, 128), *Tr2 = wt(64, 128), *Tres2 = wt(64, 128);
  unsigned short *Tl3 = wt(128, 256), *Tr3 = wt(128, 256), *Tres3 = wt(128, 256);
  unsigned short *Tenc = wt(256, 64), *Trp = wt(64, 64);
  unsigned short *Td1 = wt(64, 128), *Td2 = wt(128, 64), *Td3 = wt(64, 64);
  if ((size_t)(cur - (char*)d_ws) > ws_size) return;

  float* z = (float*)d_out;           // z_nodes (N x 64)
  float* xhat = z + (size_t)N * 64;   // x_hat   (N x 64)
  float* zg = xhat + (size_t)N * 64;  // z_graph (64)

  zero_k<<<(N + 255) / 256, 256, 0, stream>>>(deg, N, stats, zg);

  // ---- weight conversion: one fused launch ----
  {
    WPack p;
    const float* Ws[13] = {Wl1, Wr1, Wl2, Wr2, Wres2, Wl3, Wr3, Wres3,
                           encW, rpW, d1W, d2W, d3W};
    unsigned short* Ts[13] = {Tl1, Tr1, Tl2, Tr2, Tres2, Tl3, Tr3, Tres3,
                              Tenc, Trp, Td1, Td2, Td3};
    const int Ks[13] = {64, 64, 64, 64, 64, 128, 128, 128, 256, 64, 64, 128, 64};
    const int Fs[13] = {64, 64, 128, 128, 128, 256, 256, 256, 64, 64, 128, 64, 64};
    int base = 0;
    for (int i = 0; i < 13; ++i) {
      p.s[i] = {Ws[i], Ts[i], Ks[i], Fs[i], base};
      base += Ks[i] * Fs[i];
    }
    p.total = base;
    wconv_all_k<<<(base + 255) / 256, 256, 0, stream>>>(p);
  }
  cvt_k<<<1024, 256, 0, stream>>>(x, xb, (size_t)N * 16);

  // ---- CSR by target ----
  const int nb = (N + 255) / 256;
  hist_k<<<512, 256, 0, stream>>>(etgt_in, deg, E);
  scan1_k<<<nb, 256, 0, stream>>>(deg, bsum, N);
  scan2_k<<<1, 256, 0, stream>>>(bsum, nb);
  scan3_k<<<nb, 256, 0, stream>>>(deg, bsum, starts, cursor, N);
  scatter_k<<<512, 256, 0, stream>>>(esrc_in, etgt_in, cursor, esrc, E);

  const int gblk = (N + 63) / 64;
  const int ablk = (N + 3) / 4;
  const float* nullf = nullptr;

  // ---- conv1 ----
  mg3_k<64, 64, 2, 0, 1><<<gblk, 256, 0, stream>>>(
      xb, nullf, nullf, nullf, 0.f, Tl1, bl1, Tr1, br1, nullptr, Ab, Bb, nullptr, N);
  agg_k<1, 64, 1, 0><<<ablk, 256, 0, stream>>>(Ab, Bb, att1, bo1, starts, deg, esrc,
                                               bufC, stats + 0, N);
  // ---- conv2 (LN1 inline) ----
  mg3_k<64, 128, 3, 1, 0><<<gblk, 256, 0, stream>>>(
      bufC, stats + 0, ln1g, ln1b, 1.f / ((float)N * 64.f), Tl2, bl2, Tr2, br2, Tres2,
      Ab, Bb, bufD, N);
  agg_k<4, 32, 2, 1><<<ablk, 256, 0, stream>>>(Ab, Bb, att2, bo2, starts, deg, esrc,
                                               bufD, stats + 256, N);
  // ---- conv3 (LN2 inline) ----
  mg3_k<128, 256, 3, 1, 0><<<gblk, 256, 0, stream>>>(
      bufD, stats + 256, ln2g, ln2b, 1.f / ((float)N * 128.f), Tl3, bl3, Tr3, br3,
      Tres3, Ab, Bb, bufC, N);
  agg_k<4, 64, 4, 1><<<ablk, 256, 0, stream>>>(Ab, Bb, att3, bo3, starts, deg, esrc,
                                               bufC, stats + 512, N);
  // ---- encoder (LN3 inline) ----
  enc_k<256, 64, 64><<<gblk, 256, 0, stream>>>(bufC, stats + 512, ln3g, ln3b,
                                               1.f / ((float)N * 256.f), Tenc, encb, xb,
                                               Trp, rpb, z, xb, N);
  // ---- z_graph ----
  colmean_k<<<256, 256, 0, stream>>>(z, zg, N, 1.f / (float)N);

  // ---- decoder ----
  mgemm_k<64, 128, 1, 0, 1><<<gblk, 256, 0, stream>>>(xb, Td1, d1b, nullptr, Db, N);
  mgemm_k<128, 64, 1, 0, 1><<<gblk, 256, 0, stream>>>(Db, Td2, d2b, nullptr, Cb, N);
  mgemm_k<64, 64, 0, 1, 0><<<gblk, 256, 0, stream>>>(Cb, Td3, d3b, xhat, nullptr, N);
}

// Round 5
// 557.120 us; speedup vs baseline: 2.4440x; 1.2036x over previous
//
#include <hip/hip_runtime.h>
#include <math.h>

typedef __attribute__((ext_vector_type(8))) short short8;
typedef __attribute__((ext_vector_type(4))) float f32x4;

__device__ __forceinline__ unsigned short f2bf(float f) {
  union { float f; unsigned u; } c; c.f = f;
  unsigned r = c.u + 0x7fffu + ((c.u >> 16) & 1u);
  return (unsigned short)(r >> 16);
}
__device__ __forceinline__ float bf2f(unsigned short u) {
  union { unsigned u; float f; } c; c.u = ((unsigned)u) << 16;
  return c.f;
}

// ---------------- init ----------------
__global__ void zero_k(int* __restrict__ deg, int n, float* __restrict__ stats,
                       float* __restrict__ zg) {
  int i = blockIdx.x * 256 + threadIdx.x;
  if (i < n) deg[i] = 0;
  if (i < 768) stats[i] = 0.f;
  if (i < 64) zg[i] = 0.f;
}

// ---------------- CSR build ----------------
__global__ void hist_k(const int* __restrict__ tgt, int* __restrict__ deg, int E) {
  int stride = gridDim.x * blockDim.x;
  for (int e = blockIdx.x * blockDim.x + threadIdx.x; e < E; e += stride)
    atomicAdd(&deg[tgt[e]], 1);
}

__global__ void scan1_k(const int* __restrict__ deg, int* __restrict__ bsum, int n) {
  __shared__ int sh[256];
  int idx = blockIdx.x * 256 + threadIdx.x;
  sh[threadIdx.x] = (idx < n) ? deg[idx] : 0;
  __syncthreads();
  for (int off = 128; off > 0; off >>= 1) {
    if (threadIdx.x < off) sh[threadIdx.x] += sh[threadIdx.x + off];
    __syncthreads();
  }
  if (threadIdx.x == 0) bsum[blockIdx.x] = sh[0];
}

__global__ void scan2_k(int* __restrict__ bsum, int nb) {
  __shared__ int sh[256];
  int t = threadIdx.x;
  int v = (t < nb) ? bsum[t] : 0;
  sh[t] = v; __syncthreads();
  for (int off = 1; off < 256; off <<= 1) {
    int add = (t >= off) ? sh[t - off] : 0;
    __syncthreads();
    sh[t] += add;
    __syncthreads();
  }
  if (t < nb) bsum[t] = sh[t] - v;  // exclusive
}

__global__ void scan3_k(const int* __restrict__ deg, const int* __restrict__ bsum,
                        int* __restrict__ starts, int* __restrict__ cursor, int n) {
  __shared__ int sh[256];
  int t = threadIdx.x;
  int idx = blockIdx.x * 256 + t;
  int v = (idx < n) ? deg[idx] : 0;
  sh[t] = v; __syncthreads();
  for (int off = 1; off < 256; off <<= 1) {
    int add = (t >= off) ? sh[t - off] : 0;
    __syncthreads();
    sh[t] += add;
    __syncthreads();
  }
  if (idx < n) {
    int ex = bsum[blockIdx.x] + sh[t] - v;
    starts[idx] = ex;
    cursor[idx] = ex;
  }
}

__global__ void scatter_k(const int* __restrict__ src, const int* __restrict__ tgt,
                          int* __restrict__ cursor, int* __restrict__ esrc, int E) {
  int stride = gridDim.x * blockDim.x;
  for (int e = blockIdx.x * blockDim.x + threadIdx.x; e < E; e += stride) {
    int p = atomicAdd(&cursor[tgt[e]], 1);
    esrc[p] = src[e];
  }
}

// ---------------- conversions ----------------
__global__ void cvt_k(const float* __restrict__ src, unsigned short* __restrict__ dst,
                      size_t n4) {
  size_t stride = (size_t)gridDim.x * blockDim.x;
  for (size_t i = (size_t)blockIdx.x * blockDim.x + threadIdx.x; i < n4; i += stride) {
    float4 v = reinterpret_cast<const float4*>(src)[i];
    ushort4 o;
    o.x = f2bf(v.x); o.y = f2bf(v.y); o.z = f2bf(v.z); o.w = f2bf(v.w);
    reinterpret_cast<ushort4*>(dst)[i] = o;
  }
}

struct WSeg { const float* W; unsigned short* T; int K; int F; int base; };
struct WPack { WSeg s[13]; int total; };
__global__ __launch_bounds__(256) void wconv_all_k(WPack p) {
  int idx = blockIdx.x * 256 + threadIdx.x;
  if (idx >= p.total) return;
  int si = 0;
#pragma unroll
  for (int i = 1; i < 13; ++i) si = (idx >= p.s[i].base) ? i : si;
  const WSeg sg = p.s[si];
  const int loc = idx - sg.base;
  const int k = loc / sg.F, f = loc - k * sg.F;
  sg.T[(size_t)f * sg.K + k] = f2bf(sg.W[loc]);
}

// ---------------- universal MFMA GEMM, 64-row block tile ---------------------
// A staged in LDS (bf16, XOR-swizzled, optional inline graph-LN+relu).
// Wave w owns cols [w*F/4, (w+1)*F/4), 4 row-tiles; B-frags reused 4x.
// set0 -> Y0 bf16 (bias B0, opt relu) or Y2 fp32 if W32_1; set1 -> Y1 bf16 (B1);
// set2 -> Y2 fp32 (residual, no bias).
template <int K, int F, int SETS, int LNF, int BF16IN, int ACT1, int W32_1>
__global__ __launch_bounds__(256) void mg_k(
    const void* __restrict__ Xv, const float* __restrict__ bins,
    const float* __restrict__ lng, const float* __restrict__ lnb, float invNF,
    const unsigned short* __restrict__ WT0, const float* __restrict__ B0,
    const unsigned short* __restrict__ WT1, const float* __restrict__ B1,
    const unsigned short* __restrict__ WT2,
    unsigned short* __restrict__ Y0, unsigned short* __restrict__ Y1,
    float* __restrict__ Y2, int n) {
  constexpr int NK = K / 32;   // 32-wide k chunks
  constexpr int TL = F / 64;   // col tiles per wave
  constexpr int CPR = K / 8;   // 8-elem chunks per row
  __shared__ unsigned short As[64 * K];
  __shared__ float lnp[2];
  char* asb = (char*)As;
  const int tid = threadIdx.x;
  const int lane = tid & 63;
  const int wv = tid >> 6;
  const int r0 = blockIdx.x * 64;

  if (LNF) {
    if (tid < 64) {
      float s1 = bins[tid] + bins[tid + 64];
      float s2 = bins[tid + 128] + bins[tid + 192];
#pragma unroll
      for (int mm = 1; mm < 64; mm <<= 1) {
        s1 += __shfl_xor(s1, mm, 64);
        s2 += __shfl_xor(s2, mm, 64);
      }
      if (tid == 0) {
        const float mu = s1 * invNF;
        lnp[0] = mu;
        lnp[1] = rsqrtf(s2 * invNF - mu * mu + 1e-5f);
      }
    }
    __syncthreads();
  }
  const float mu = LNF ? lnp[0] : 0.f;
  const float rs = LNF ? lnp[1] : 0.f;

  // ---- stage A: 64 rows x K into LDS (swizzled) ----
  for (int c = tid; c < 64 * CPR; c += 256) {
    const int row = c / CPR;
    const int k0 = (c - row * CPR) * 8;
    const int gr = r0 + row;
    short8 a = {0, 0, 0, 0, 0, 0, 0, 0};
    if (gr < n) {
      if (BF16IN) {
        a = *reinterpret_cast<const short8*>((const unsigned short*)Xv +
                                             (size_t)gr * K + k0);
      } else {
        const float* Xf = (const float*)Xv + (size_t)gr * K + k0;
        float v[8];
        *(float4*)&v[0] = *(const float4*)&Xf[0];
        *(float4*)&v[4] = *(const float4*)&Xf[4];
        if (LNF) {
          float g[8], bb[8];
          *(float4*)&g[0] = *(const float4*)&lng[k0];
          *(float4*)&g[4] = *(const float4*)&lng[k0 + 4];
          *(float4*)&bb[0] = *(const float4*)&lnb[k0];
          *(float4*)&bb[4] = *(const float4*)&lnb[k0 + 4];
#pragma unroll
          for (int q = 0; q < 8; ++q)
            v[q] = fmaxf(fmaf(v[q] - mu, rs * g[q], bb[q]), 0.f);  // LN + relu
        }
#pragma unroll
        for (int q = 0; q < 8; ++q) a[q] = (short)f2bf(v[q]);
      }
    }
    const int boff = ((row * K + k0) * 2) ^ ((row & 7) << 4);
    *(short8*)(asb + boff) = a;
  }
  __syncthreads();

  const int rl = lane & 15;
  const int ks = lane >> 4;
#pragma unroll
  for (int set = 0; set < SETS; ++set) {
    const unsigned short* WT = (set == 0) ? WT0 : (set == 1) ? WT1 : WT2;
    f32x4 acc[4][TL];
#pragma unroll
    for (int rt = 0; rt < 4; ++rt)
#pragma unroll
      for (int t = 0; t < TL; ++t) acc[rt][t] = (f32x4){0.f, 0.f, 0.f, 0.f};
#pragma unroll
    for (int kk = 0; kk < NK; ++kk) {
      short8 bf[TL];
#pragma unroll
      for (int t = 0; t < TL; ++t)
        bf[t] = *reinterpret_cast<const short8*>(
            &WT[(size_t)((wv * TL + t) * 16 + rl) * K + kk * 32 + ks * 8]);
      short8 af[4];
#pragma unroll
      for (int rt = 0; rt < 4; ++rt) {
        const int row = rt * 16 + rl;
        const int boff = ((row * K + kk * 32 + ks * 8) * 2) ^ ((row & 7) << 4);
        af[rt] = *(const short8*)(asb + boff);
      }
#pragma unroll
      for (int rt = 0; rt < 4; ++rt)
#pragma unroll
        for (int t = 0; t < TL; ++t)
          acc[rt][t] =
              __builtin_amdgcn_mfma_f32_16x16x32_bf16(af[rt], bf[t], acc[rt][t], 0, 0, 0);
    }
    // ---- epilogue ----
#pragma unroll
    for (int rt = 0; rt < 4; ++rt) {
      const int rowd = r0 + rt * 16 + ks * 4;
#pragma unroll
      for (int t = 0; t < TL; ++t) {
        const int col = (wv * TL + t) * 16 + rl;
        const float bias = (set == 0) ? B0[col] : (set == 1) ? B1[col] : 0.f;
#pragma unroll
        for (int r = 0; r < 4; ++r) {
          const int gr = rowd + r;
          if (gr >= n) continue;
          float o = acc[rt][t][r] + bias;
          const size_t idx = (size_t)gr * F + col;
          if (set == 0) {
            if (ACT1) o = fmaxf(o, 0.f);
            if (W32_1) Y2[idx] = o; else Y0[idx] = f2bf(o);
          } else if (set == 1) {
            Y1[idx] = f2bf(o);
          } else {
            Y2[idx] = o;
          }
        }
      }
    }
  }
}

// ---------------- encoder: z = relu(LN3(h3)@We+be) + xb@Wrp+brp --------------
__global__ __launch_bounds__(256) void enc_k(
    const float* __restrict__ h3, const float* __restrict__ bins,
    const float* __restrict__ lng, const float* __restrict__ lnb, float invNF,
    const unsigned short* __restrict__ WTe, const float* __restrict__ Be,
    const unsigned short* __restrict__ xb, const unsigned short* __restrict__ WTrp,
    const float* __restrict__ Brp, float* __restrict__ z,
    unsigned short* __restrict__ zb, int n) {
  constexpr int K1 = 256, K2 = 64, F = 64;
  __shared__ unsigned short As1[64 * K1];  // 32 KB
  __shared__ unsigned short As2[64 * K2];  // 8 KB
  __shared__ float lnp[2];
  char* a1b = (char*)As1;
  char* a2b = (char*)As2;
  const int tid = threadIdx.x;
  const int lane = tid & 63;
  const int wv = tid >> 6;
  const int r0 = blockIdx.x * 64;

  if (tid < 64) {
    float s1 = bins[tid] + bins[tid + 64];
    float s2 = bins[tid + 128] + bins[tid + 192];
#pragma unroll
    for (int mm = 1; mm < 64; mm <<= 1) {
      s1 += __shfl_xor(s1, mm, 64);
      s2 += __shfl_xor(s2, mm, 64);
    }
    if (tid == 0) {
      const float mu = s1 * invNF;
      lnp[0] = mu;
      lnp[1] = rsqrtf(s2 * invNF - mu * mu + 1e-5f);
    }
  }
  __syncthreads();
  const float mu = lnp[0], rs = lnp[1];

  for (int c = tid; c < 64 * (K1 / 8); c += 256) {  // stage h3 with LN+relu
    const int row = c / (K1 / 8);
    const int k0 = (c - row * (K1 / 8)) * 8;
    const int gr = r0 + row;
    short8 a = {0, 0, 0, 0, 0, 0, 0, 0};
    if (gr < n) {
      const float* Xf = h3 + (size_t)gr * K1 + k0;
      float v[8], g[8], bb[8];
      *(float4*)&v[0] = *(const float4*)&Xf[0];
      *(float4*)&v[4] = *(const float4*)&Xf[4];
      *(float4*)&g[0] = *(const float4*)&lng[k0];
      *(float4*)&g[4] = *(const float4*)&lng[k0 + 4];
      *(float4*)&bb[0] = *(const float4*)&lnb[k0];
      *(float4*)&bb[4] = *(const float4*)&lnb[k0 + 4];
#pragma unroll
      for (int q = 0; q < 8; ++q) {
        float t = fmaxf(fmaf(v[q] - mu, rs * g[q], bb[q]), 0.f);
        a[q] = (short)f2bf(t);
      }
    }
    const int boff = ((row * K1 + k0) * 2) ^ ((row & 7) << 4);
    *(short8*)(a1b + boff) = a;
  }
  for (int c = tid; c < 64 * (K2 / 8); c += 256) {  // stage xb
    const int row = c / (K2 / 8);
    const int k0 = (c - row * (K2 / 8)) * 8;
    const int gr = r0 + row;
    short8 a = {0, 0, 0, 0, 0, 0, 0, 0};
    if (gr < n)
      a = *reinterpret_cast<const short8*>(&xb[(size_t)gr * K2 + k0]);
    const int boff = ((row * K2 + k0) * 2) ^ ((row & 7) << 4);
    *(short8*)(a2b + boff) = a;
  }
  __syncthreads();

  const int rl = lane & 15;
  const int ks = lane >> 4;
  f32x4 a1[4], a2[4];
#pragma unroll
  for (int rt = 0; rt < 4; ++rt) {
    a1[rt] = (f32x4){0.f, 0.f, 0.f, 0.f};
    a2[rt] = (f32x4){0.f, 0.f, 0.f, 0.f};
  }
#pragma unroll
  for (int kk = 0; kk < K1 / 32; ++kk) {
    short8 bf = *reinterpret_cast<const short8*>(
        &WTe[(size_t)(wv * 16 + rl) * K1 + kk * 32 + ks * 8]);
#pragma unroll
    for (int rt = 0; rt < 4; ++rt) {
      const int row = rt * 16 + rl;
      const int boff = ((row * K1 + kk * 32 + ks * 8) * 2) ^ ((row & 7) << 4);
      short8 af = *(const short8*)(a1b + boff);
      a1[rt] = __builtin_amdgcn_mfma_f32_16x16x32_bf16(af, bf, a1[rt], 0, 0, 0);
    }
  }
#pragma unroll
  for (int kk = 0; kk < K2 / 32; ++kk) {
    short8 bf = *reinterpret_cast<const short8*>(
        &WTrp[(size_t)(wv * 16 + rl) * K2 + kk * 32 + ks * 8]);
#pragma unroll
    for (int rt = 0; rt < 4; ++rt) {
      const int row = rt * 16 + rl;
      const int boff = ((row * K2 + kk * 32 + ks * 8) * 2) ^ ((row & 7) << 4);
      short8 af = *(const short8*)(a2b + boff);
      a2[rt] = __builtin_amdgcn_mfma_f32_16x16x32_bf16(af, bf, a2[rt], 0, 0, 0);
    }
  }
  const int col = wv * 16 + rl;
  const float be = Be[col];
  const float brp = Brp[col];
#pragma unroll
  for (int rt = 0; rt < 4; ++rt) {
    const int rowd = r0 + rt * 16 + ks * 4;
#pragma unroll
    for (int r = 0; r < 4; ++r) {
      const int gr = rowd + r;
      if (gr >= n) continue;
      const float o = fmaxf(a1[rt][r] + be, 0.f) + a2[rt][r] + brp;
      const size_t idx = (size_t)gr * F + col;
      z[idx] = o;
      zb[idx] = f2bf(o);
    }
  }
}

// ---------------- GATv2 edge aggregation ------------------------------------
template <int VEC> struct RawT;
template <> struct RawT<1> { using T = unsigned short; };
template <> struct RawT<2> { using T = unsigned; };
template <> struct RawT<4> { using T = unsigned long long; };

__device__ __forceinline__ void bdec(unsigned short u, float* o) { o[0] = bf2f(u); }
__device__ __forceinline__ void bdec(unsigned u, float* o) {
  o[0] = bf2f((unsigned short)(u & 0xffffu));
  o[1] = bf2f((unsigned short)(u >> 16));
}
__device__ __forceinline__ void bdec(unsigned long long u, float* o) {
  o[0] = bf2f((unsigned short)(u & 0xffffu));
  o[1] = bf2f((unsigned short)((u >> 16) & 0xffffu));
  o[2] = bf2f((unsigned short)((u >> 32) & 0xffffu));
  o[3] = bf2f((unsigned short)(u >> 48));
}

// one wave per target node; 2-edge unrolled online softmax; epilogue
// accumulates graph-LN stats into 128 spread bins.
template <int H, int C, int VEC, int HAS_RES>
__global__ __launch_bounds__(256) void agg_k(
    const unsigned short* __restrict__ xl, const unsigned short* __restrict__ xr,
    const float* __restrict__ att, const float* __restrict__ bo,
    const int* __restrict__ starts, const int* __restrict__ deg,
    const int* __restrict__ esrc, float* __restrict__ out,
    float* __restrict__ bins, int n) {
  constexpr int F = H * C;
  constexpr int G = 64 / H;    // lanes per head group
  constexpr int CS = F / VEC;  // raw elements per row
  using RT = typename RawT<VEC>::T;
  const int lane = threadIdx.x & 63;
  const int wv = threadIdx.x >> 6;
  const int node = blockIdx.x * 4 + wv;
  const bool active = node < n;
  float s1w = 0.f, s2w = 0.f;

  if (active) {
    const RT* xlr = reinterpret_cast<const RT*>(xl);
    float xri[VEC], av[VEC], acc[VEC];
    {
      RT rx = reinterpret_cast<const RT*>(xr)[(size_t)node * CS + lane];
      bdec(rx, xri);
    }
#pragma unroll
    for (int q = 0; q < VEC; ++q) {
      av[q] = att[lane * VEC + q];
      acc[q] = 0.f;
    }
    float m = -1e30f, s = 0.f;
    const int st = starts[node];
    const int cnt = deg[node];
    const int total = cnt + 1;  // + self loop
    RT u0, u1 = 0;
    {
      int j0 = (cnt > 0) ? esrc[st] : node;
      u0 = xlr[(size_t)j0 * CS + lane];
    }
    if (total > 1) {
      int j1 = (1 < cnt) ? esrc[st + 1] : node;
      u1 = xlr[(size_t)j1 * CS + lane];
    }
    int it = 0;
    for (; it + 2 <= total; it += 2) {
      RT n0 = u0, n1 = u1;
      if (it + 2 < total) {
        int jn = (it + 2 < cnt) ? esrc[st + it + 2] : node;
        n0 = xlr[(size_t)jn * CS + lane];
      }
      if (it + 3 < total) {
        int jn = (it + 3 < cnt) ? esrc[st + it + 3] : node;
        n1 = xlr[(size_t)jn * CS + lane];
      }
      float x0[VEC], x1[VEC];
      bdec(u0, x0);
      bdec(u1, x1);
      float e0 = 0.f, e1 = 0.f;
#pragma unroll
      for (int q = 0; q < VEC; ++q) {
        float t0 = xri[q] + x0[q];
        float t1 = xri[q] + x1[q];
        t0 = (t0 > 0.f) ? t0 : 0.2f * t0;
        t1 = (t1 > 0.f) ? t1 : 0.2f * t1;
        e0 = fmaf(t0, av[q], e0);
        e1 = fmaf(t1, av[q], e1);
      }
#pragma unroll
      for (int mask = 1; mask < G; mask <<= 1) {
        e0 += __shfl_xor(e0, mask, 64);
        e1 += __shfl_xor(e1, mask, 64);
      }
      const float eM = fmaxf(e0, e1);
      if (eM - m > 8.f) {
        const float sc = __expf(m - eM);
        s *= sc;
#pragma unroll
        for (int q = 0; q < VEC; ++q) acc[q] *= sc;
        m = eM;
      }
      const float p0 = __expf(e0 - m);
      const float p1 = __expf(e1 - m);
      s += p0 + p1;
#pragma unroll
      for (int q = 0; q < VEC; ++q)
        acc[q] = fmaf(p0, x0[q], fmaf(p1, x1[q], acc[q]));
      u0 = n0;
      u1 = n1;
    }
    if (it < total) {  // odd tail
      float x0[VEC];
      bdec(u0, x0);
      float e0 = 0.f;
#pragma unroll
      for (int q = 0; q < VEC; ++q) {
        float t0 = xri[q] + x0[q];
        t0 = (t0 > 0.f) ? t0 : 0.2f * t0;
        e0 = fmaf(t0, av[q], e0);
      }
#pragma unroll
      for (int mask = 1; mask < G; mask <<= 1) e0 += __shfl_xor(e0, mask, 64);
      if (e0 - m > 8.f) {
        const float sc = __expf(m - e0);
        s *= sc;
#pragma unroll
        for (int q = 0; q < VEC; ++q) acc[q] *= sc;
        m = e0;
      }
      const float p0 = __expf(e0 - m);
      s += p0;
#pragma unroll
      for (int q = 0; q < VEC; ++q) acc[q] = fmaf(p0, x0[q], acc[q]);
    }
    const float inv = 1.f / s;
#pragma unroll
    for (int q = 0; q < VEC; ++q) {
      const size_t idx = (size_t)node * F + lane * VEC + q;
      float o = acc[q] * inv + bo[lane * VEC + q];
      if (HAS_RES) o += out[idx];  // residual precomputed into out
      out[idx] = o;
      s1w += o;
      s2w += o * o;
    }
  }
  // graph-LN stats: wave reduce -> block combine -> 2 atomics into spread bins
#pragma unroll
  for (int mask = 1; mask < 64; mask <<= 1) {
    s1w += __shfl_xor(s1w, mask, 64);
    s2w += __shfl_xor(s2w, mask, 64);
  }
  __shared__ float sh[8];
  if (lane == 0) { sh[wv] = s1w; sh[4 + wv] = s2w; }
  __syncthreads();
  if (threadIdx.x == 0) {
    const int bin = blockIdx.x & 127;
    atomicAdd(&bins[bin], sh[0] + sh[1] + sh[2] + sh[3]);
    atomicAdd(&bins[128 + bin], sh[4] + sh[5] + sh[6] + sh[7]);
  }
}

// ---------------- column mean (z_graph) -------------------------------------
__global__ void colmean_k(const float* __restrict__ z, float* __restrict__ outv,
                          int n, float inv) {
  __shared__ float sh[256];
  int col = threadIdx.x & 63;
  int w = threadIdx.x >> 6;
  float s = 0.f;
  for (int r = blockIdx.x * 4 + w; r < n; r += gridDim.x * 4)
    s += z[(size_t)r * 64 + col];
  sh[threadIdx.x] = s;
  __syncthreads();
  if (threadIdx.x < 64) {
    float t = sh[threadIdx.x] + sh[threadIdx.x + 64] + sh[threadIdx.x + 128] +
              sh[threadIdx.x + 192];
    atomicAdd(&outv[col], t * inv);
  }
}

// ---------------------------------------------------------------------------
extern "C" void kernel_launch(void* const* d_in, const int* in_sizes, int n_in,
                              void* d_out, int out_size, void* d_ws, size_t ws_size,
                              hipStream_t stream) {
  const float* x = (const float*)d_in[0];
  const int* ei = (const int*)d_in[1];
  const float *Wl1 = (const float*)d_in[3], *bl1 = (const float*)d_in[4];
  const float *Wr1 = (const float*)d_in[5], *br1 = (const float*)d_in[6];
  const float *att1 = (const float*)d_in[7], *bo1 = (const float*)d_in[8];
  const float *Wl2 = (const float*)d_in[9], *bl2 = (const float*)d_in[10];
  const float *Wr2 = (const float*)d_in[11], *br2 = (const float*)d_in[12];
  const float *att2 = (const float*)d_in[13], *bo2 = (const float*)d_in[14];
  const float *Wres2 = (const float*)d_in[15];
  const float *Wl3 = (const float*)d_in[16], *bl3 = (const float*)d_in[17];
  const float *Wr3 = (const float*)d_in[18], *br3 = (const float*)d_in[19];
  const float *att3 = (const float*)d_in[20], *bo3 = (const float*)d_in[21];
  const float *Wres3 = (const float*)d_in[22];
  const float *ln1g = (const float*)d_in[23], *ln1b = (const float*)d_in[24];
  const float *ln2g = (const float*)d_in[25], *ln2b = (const float*)d_in[26];
  const float *ln3g = (const float*)d_in[27], *ln3b = (const float*)d_in[28];
  const float *encW = (const float*)d_in[29], *encb = (const float*)d_in[30];
  const float *rpW = (const float*)d_in[31], *rpb = (const float*)d_in[32];
  const float *d1W = (const float*)d_in[33], *d1b = (const float*)d_in[34];
  const float *d2W = (const float*)d_in[35], *d2b = (const float*)d_in[36];
  const float *d3W = (const float*)d_in[37], *d3b = (const float*)d_in[38];

  const int N = in_sizes[0] / 64;
  const int E = in_sizes[1] / 2;
  const int* esrc_in = ei;      // row 0: src
  const int* etgt_in = ei + E;  // row 1: tgt

  // ---- workspace layout ----
  char* cur = (char*)d_ws;
  auto take = [&](size_t bytes) {
    char* p = cur;
    cur += (bytes + 15) & ~(size_t)15;
    return p;
  };
  float* bufC = (float*)take((size_t)N * 256 * 4);                  // h1 / h3 (fp32)
  float* bufD = (float*)take((size_t)N * 128 * 4);                  // h2 (fp32)
  unsigned short* Ab = (unsigned short*)take((size_t)N * 256 * 2);  // xl (bf16)
  unsigned short* Bb = (unsigned short*)take((size_t)N * 256 * 2);  // xr (bf16)
  unsigned short* Cb = (unsigned short*)take((size_t)N * 256 * 2);  // dh2b
  unsigned short* Db = (unsigned short*)take((size_t)N * 128 * 2);  // dh1b
  unsigned short* xb = (unsigned short*)take((size_t)N * 64 * 2);   // xbf -> zb
  float* stats = (float*)take(768 * 4);                             // 3 x (128+128)
  int* deg = (int*)take((size_t)N * 4);
  int* starts = (int*)take((size_t)N * 4);
  int* cursor = (int*)take((size_t)N * 4);
  int* bsum = (int*)take(1024);
  int* esrc = (int*)take((size_t)E * 4);
  auto wt = [&](int K, int F) { return (unsigned short*)take((size_t)K * F * 2); };
  unsigned short *Tl1 = wt(64, 64), *Tr1 = wt(64, 64);
  unsigned short *Tl2 = wt(64, 128), *Tr2 = wt(64, 128), *Tres2 = wt(64, 128);
  unsigned short *Tl3 = wt(128, 256), *Tr3 = wt(128, 256), *Tres3 = wt(128, 256);
  unsigned short *Tenc = wt(256, 64), *Trp = wt(64, 64);
  unsigned short *Td1 = wt(64, 128), *Td2 = wt(128, 64), *Td3 = wt(64, 64);
  if ((size_t)(cur - (char*)d_ws) > ws_size) return;

  float* z = (float*)d_out;           // z_nodes (N x 64)
  float* xhat = z + (size_t)N * 64;   // x_hat   (N x 64)
  float* zg = xhat + (size_t)N * 64;  // z_graph (64)

  zero_k<<<(N + 255) / 256, 256, 0, stream>>>(deg, N, stats, zg);

  // ---- weight conversion: one fused launch ----
  {
    WPack p;
    const float* Ws[13] = {Wl1, Wr1, Wl2, Wr2, Wres2, Wl3, Wr3, Wres3,
                           encW, rpW, d1W, d2W, d3W};
    unsigned short* Ts[13] = {Tl1, Tr1, Tl2, Tr2, Tres2, Tl3, Tr3, Tres3,
                              Tenc, Trp, Td1, Td2, Td3};
    const int Ks[13] = {64, 64, 64, 64, 64, 128, 128, 128, 256, 64, 64, 128, 64};
    const int Fs[13] = {64, 64, 128, 128, 128, 256, 256, 256, 64, 64, 128, 64, 64};
    int base = 0;
    for (int i = 0; i < 13; ++i) {
      p.s[i] = {Ws[i], Ts[i], Ks[i], Fs[i], base};
      base += Ks[i] * Fs[i];
    }
    p.total = base;
    wconv_all_k<<<(base + 255) / 256, 256, 0, stream>>>(p);
  }
  cvt_k<<<1024, 256, 0, stream>>>(x, xb, (size_t)N * 16);

  // ---- CSR by target ----
  const int nb = (N + 255) / 256;
  hist_k<<<512, 256, 0, stream>>>(etgt_in, deg, E);
  scan1_k<<<nb, 256, 0, stream>>>(deg, bsum, N);
  scan2_k<<<1, 256, 0, stream>>>(bsum, nb);
  scan3_k<<<nb, 256, 0, stream>>>(deg, bsum, starts, cursor, N);
  scatter_k<<<512, 256, 0, stream>>>(esrc_in, etgt_in, cursor, esrc, E);

  const int gblk = (N + 63) / 64;
  const int ablk = (N + 3) / 4;
  const float* nullf = nullptr;
  unsigned short* nullb = nullptr;
  float* nully = nullptr;

  // ---- conv1 ----
  mg_k<64, 64, 2, 0, 1, 0, 0><<<gblk, 256, 0, stream>>>(
      xb, nullf, nullf, nullf, 0.f, Tl1, bl1, Tr1, br1, nullb, Ab, Bb, nully, N);
  agg_k<1, 64, 1, 0><<<ablk, 256, 0, stream>>>(Ab, Bb, att1, bo1, starts, deg, esrc,
                                               bufC, stats + 0, N);
  // ---- conv2 (LN1 inline) ----
  mg_k<64, 128, 3, 1, 0, 0, 0><<<gblk, 256, 0, stream>>>(
      bufC, stats + 0, ln1g, ln1b, 1.f / ((float)N * 64.f), Tl2, bl2, Tr2, br2, Tres2,
      Ab, Bb, bufD, N);
  agg_k<4, 32, 2, 1><<<ablk, 256, 0, stream>>>(Ab, Bb, att2, bo2, starts, deg, esrc,
                                               bufD, stats + 256, N);
  // ---- conv3 (LN2 inline) ----
  mg_k<128, 256, 3, 1, 0, 0, 0><<<gblk, 256, 0, stream>>>(
      bufD, stats + 256, ln2g, ln2b, 1.f / ((float)N * 128.f), Tl3, bl3, Tr3, br3,
      Tres3, Ab, Bb, bufC, N);
  agg_k<4, 64, 4, 1><<<ablk, 256, 0, stream>>>(Ab, Bb, att3, bo3, starts, deg, esrc,
                                               bufC, stats + 512, N);
  // ---- encoder (LN3 inline) ----
  enc_k<<<gblk, 256, 0, stream>>>(bufC, stats + 512, ln3g, ln3b,
                                  1.f / ((float)N * 256.f), Tenc, encb, xb, Trp, rpb, z,
                                  xb, N);
  // ---- z_graph ----
  colmean_k<<<256, 256, 0, stream>>>(z, zg, N, 1.f / (float)N);

  // ---- decoder ----
  mg_k<64, 128, 1, 0, 1, 1, 0><<<gblk, 256, 0, stream>>>(
      xb, nullf, nullf, nullf, 0.f, Td1, d1b, nullb, nullf, nullb, Db, nullb, nully, N);
  mg_k<128, 64, 1, 0, 1, 1, 0><<<gblk, 256, 0, stream>>>(
      Db, nullf, nullf, nullf, 0.f, Td2, d2b, nullb, nullf, nullb, Cb, nullb, nully, N);
  mg_k<64, 64, 1, 0, 1, 0, 1><<<gblk, 256, 0, stream>>>(
      Cb, nullf, nullf, nullf, 0.f, Td3, d3b, nullb, nullf, nullb, nullb, nullb, xhat, N);
}

// Round 6
// 506.885 us; speedup vs baseline: 2.6863x; 1.0991x over previous
//
#include <hip/hip_runtime.h>
#include <math.h>

typedef __attribute__((ext_vector_type(8))) short short8;
typedef __attribute__((ext_vector_type(4))) float f32x4;
typedef _Float16 h2 __attribute__((ext_vector_type(2)));

__device__ __forceinline__ unsigned short f2bf(float f) {
  union { float f; unsigned u; } c; c.f = f;
  unsigned r = c.u + 0x7fffu + ((c.u >> 16) & 1u);
  return (unsigned short)(r >> 16);
}
__device__ __forceinline__ float bf2f(unsigned short u) {
  union { unsigned u; float f; } c; c.u = ((unsigned)u) << 16;
  return c.f;
}
__device__ __forceinline__ void dot2(float& e, h2 a, h2 b) {
  asm("v_dot2_f32_f16 %0, %1, %2, %0" : "+v"(e) : "v"(a), "v"(b));
}

// ---------------- init ----------------
__global__ void zero_k(int* __restrict__ deg, int n, float* __restrict__ stats,
                       float* __restrict__ zg) {
  int i = blockIdx.x * 256 + threadIdx.x;
  if (i < n) deg[i] = 0;
  if (i < 768) stats[i] = 0.f;
  if (i < 64) zg[i] = 0.f;
}

// ---------------- CSR build ----------------
__global__ void hist_k(const int* __restrict__ tgt, int* __restrict__ deg, int E) {
  int stride = gridDim.x * blockDim.x;
  for (int e = blockIdx.x * blockDim.x + threadIdx.x; e < E; e += stride)
    atomicAdd(&deg[tgt[e]], 1);
}

__global__ void scan1_k(const int* __restrict__ deg, int* __restrict__ bsum, int n) {
  __shared__ int sh[256];
  int idx = blockIdx.x * 256 + threadIdx.x;
  sh[threadIdx.x] = (idx < n) ? deg[idx] : 0;
  __syncthreads();
  for (int off = 128; off > 0; off >>= 1) {
    if (threadIdx.x < off) sh[threadIdx.x] += sh[threadIdx.x + off];
    __syncthreads();
  }
  if (threadIdx.x == 0) bsum[blockIdx.x] = sh[0];
}

__global__ void scan2_k(int* __restrict__ bsum, int nb) {
  __shared__ int sh[256];
  int t = threadIdx.x;
  int v = (t < nb) ? bsum[t] : 0;
  sh[t] = v; __syncthreads();
  for (int off = 1; off < 256; off <<= 1) {
    int add = (t >= off) ? sh[t - off] : 0;
    __syncthreads();
    sh[t] += add;
    __syncthreads();
  }
  if (t < nb) bsum[t] = sh[t] - v;  // exclusive
}

__global__ void scan3_k(const int* __restrict__ deg, const int* __restrict__ bsum,
                        int* __restrict__ starts, int* __restrict__ cursor, int n) {
  __shared__ int sh[256];
  int t = threadIdx.x;
  int idx = blockIdx.x * 256 + t;
  int v = (idx < n) ? deg[idx] : 0;
  sh[t] = v; __syncthreads();
  for (int off = 1; off < 256; off <<= 1) {
    int add = (t >= off) ? sh[t - off] : 0;
    __syncthreads();
    sh[t] += add;
    __syncthreads();
  }
  if (idx < n) {
    int ex = bsum[blockIdx.x] + sh[t] - v;
    starts[idx] = ex;
    cursor[idx] = ex;
  }
}

__global__ void scatter_k(const int* __restrict__ src, const int* __restrict__ tgt,
                          int* __restrict__ cursor, int* __restrict__ esrc, int E) {
  int stride = gridDim.x * blockDim.x;
  for (int e = blockIdx.x * blockDim.x + threadIdx.x; e < E; e += stride) {
    int p = atomicAdd(&cursor[tgt[e]], 1);
    esrc[p] = src[e];
  }
}

// ---------------- conversions ----------------
__global__ void cvt_k(const float* __restrict__ src, unsigned short* __restrict__ dst,
                      size_t n4) {
  size_t stride = (size_t)gridDim.x * blockDim.x;
  for (size_t i = (size_t)blockIdx.x * blockDim.x + threadIdx.x; i < n4; i += stride) {
    float4 v = reinterpret_cast<const float4*>(src)[i];
    ushort4 o;
    o.x = f2bf(v.x); o.y = f2bf(v.y); o.z = f2bf(v.z); o.w = f2bf(v.w);
    reinterpret_cast<ushort4*>(dst)[i] = o;
  }
}

struct WSeg { const float* W; unsigned short* T; int K; int F; int base; };
struct WPack { WSeg s[13]; int total; };
__global__ __launch_bounds__(256) void wconv_all_k(WPack p) {
  int idx = blockIdx.x * 256 + threadIdx.x;
  if (idx >= p.total) return;
  int si = 0;
#pragma unroll
  for (int i = 1; i < 13; ++i) si = (idx >= p.s[i].base) ? i : si;
  const WSeg sg = p.s[si];
  const int loc = idx - sg.base;
  const int k = loc / sg.F, f = loc - k * sg.F;
  sg.T[(size_t)f * sg.K + k] = f2bf(sg.W[loc]);
}

// ---------------- universal MFMA GEMM, 64-row block tile ---------------------
// X bf16 (optional inline graph-LN+relu), staged in LDS (XOR-swizzled).
// OM0: set0 output 0=fp16->Y0, 1=bf16->Y2b, 2=fp32->Y2f. set1 fp16->Y1 (B1).
// set2 bf16->Y2b (residual, no bias).
template <int K, int F, int SETS, int LNF, int OM0, int ACT1>
__global__ __launch_bounds__(256) void mg_k(
    const unsigned short* __restrict__ X, const float* __restrict__ bins,
    const float* __restrict__ lng, const float* __restrict__ lnb, float invNF,
    const unsigned short* __restrict__ WT0, const float* __restrict__ B0,
    const unsigned short* __restrict__ WT1, const float* __restrict__ B1,
    const unsigned short* __restrict__ WT2,
    _Float16* __restrict__ Y0, _Float16* __restrict__ Y1,
    unsigned short* __restrict__ Y2b, float* __restrict__ Y2f, int n) {
  constexpr int NK = K / 32;
  constexpr int TL = F / 64;
  constexpr int CPR = K / 8;
  __shared__ unsigned short As[64 * K];
  __shared__ float lnp[2];
  char* asb = (char*)As;
  const int tid = threadIdx.x;
  const int lane = tid & 63;
  const int wv = tid >> 6;
  const int r0 = blockIdx.x * 64;

  if (LNF) {
    if (tid < 64) {
      float s1 = bins[tid] + bins[tid + 64];
      float s2 = bins[tid + 128] + bins[tid + 192];
#pragma unroll
      for (int mm = 1; mm < 64; mm <<= 1) {
        s1 += __shfl_xor(s1, mm, 64);
        s2 += __shfl_xor(s2, mm, 64);
      }
      if (tid == 0) {
        const float mu = s1 * invNF;
        lnp[0] = mu;
        lnp[1] = rsqrtf(s2 * invNF - mu * mu + 1e-5f);
      }
    }
    __syncthreads();
  }
  const float mu = LNF ? lnp[0] : 0.f;
  const float rs = LNF ? lnp[1] : 0.f;

  // ---- stage A: 64 rows x K into LDS (swizzled) ----
  for (int c = tid; c < 64 * CPR; c += 256) {
    const int row = c / CPR;
    const int k0 = (c - row * CPR) * 8;
    const int gr = r0 + row;
    short8 a = {0, 0, 0, 0, 0, 0, 0, 0};
    if (gr < n) {
      a = *reinterpret_cast<const short8*>(&X[(size_t)gr * K + k0]);
      if (LNF) {
        float g[8], bb[8];
        *(float4*)&g[0] = *(const float4*)&lng[k0];
        *(float4*)&g[4] = *(const float4*)&lng[k0 + 4];
        *(float4*)&bb[0] = *(const float4*)&lnb[k0];
        *(float4*)&bb[4] = *(const float4*)&lnb[k0 + 4];
#pragma unroll
        for (int q = 0; q < 8; ++q) {
          float f = bf2f((unsigned short)a[q]);
          f = fmaxf(fmaf(f - mu, rs * g[q], bb[q]), 0.f);  // LN + relu
          a[q] = (short)f2bf(f);
        }
      }
    }
    const int boff = ((row * K + k0) * 2) ^ ((row & 7) << 4);
    *(short8*)(asb + boff) = a;
  }
  __syncthreads();

  const int rl = lane & 15;
  const int ks = lane >> 4;
#pragma unroll
  for (int set = 0; set < SETS; ++set) {
    const unsigned short* WT = (set == 0) ? WT0 : (set == 1) ? WT1 : WT2;
    f32x4 acc[4][TL];
#pragma unroll
    for (int rt = 0; rt < 4; ++rt)
#pragma unroll
      for (int t = 0; t < TL; ++t) acc[rt][t] = (f32x4){0.f, 0.f, 0.f, 0.f};
#pragma unroll
    for (int kk = 0; kk < NK; ++kk) {
      short8 bf[TL];
#pragma unroll
      for (int t = 0; t < TL; ++t)
        bf[t] = *reinterpret_cast<const short8*>(
            &WT[(size_t)((wv * TL + t) * 16 + rl) * K + kk * 32 + ks * 8]);
      short8 af[4];
#pragma unroll
      for (int rt = 0; rt < 4; ++rt) {
        const int row = rt * 16 + rl;
        const int boff = ((row * K + kk * 32 + ks * 8) * 2) ^ ((row & 7) << 4);
        af[rt] = *(const short8*)(asb + boff);
      }
#pragma unroll
      for (int rt = 0; rt < 4; ++rt)
#pragma unroll
        for (int t = 0; t < TL; ++t)
          acc[rt][t] =
              __builtin_amdgcn_mfma_f32_16x16x32_bf16(af[rt], bf[t], acc[rt][t], 0, 0, 0);
    }
#pragma unroll
    for (int rt = 0; rt < 4; ++rt) {
      const int rowd = r0 + rt * 16 + ks * 4;
#pragma unroll
      for (int t = 0; t < TL; ++t) {
        const int col = (wv * TL + t) * 16 + rl;
        const float bias = (set == 0) ? B0[col] : (set == 1) ? B1[col] : 0.f;
#pragma unroll
        for (int r = 0; r < 4; ++r) {
          const int gr = rowd + r;
          if (gr >= n) continue;
          float o = acc[rt][t][r] + bias;
          const size_t idx = (size_t)gr * F + col;
          if (set == 0) {
            if (ACT1) o = fmaxf(o, 0.f);
            if (OM0 == 0) Y0[idx] = (_Float16)o;
            else if (OM0 == 1) Y2b[idx] = f2bf(o);
            else Y2f[idx] = o;
          } else if (set == 1) {
            Y1[idx] = (_Float16)o;
          } else {
            Y2b[idx] = f2bf(o);
          }
        }
      }
    }
  }
}

// ---------------- encoder: z = relu(LN3(h3)@We+be) + xb@Wrp+brp --------------
__global__ __launch_bounds__(256) void enc_k(
    const unsigned short* __restrict__ h3, const float* __restrict__ bins,
    const float* __restrict__ lng, const float* __restrict__ lnb, float invNF,
    const unsigned short* __restrict__ WTe, const float* __restrict__ Be,
    const unsigned short* __restrict__ xb, const unsigned short* __restrict__ WTrp,
    const float* __restrict__ Brp, float* __restrict__ z,
    unsigned short* __restrict__ zb, int n) {
  constexpr int K1 = 256, K2 = 64, F = 64;
  __shared__ unsigned short As1[64 * K1];
  __shared__ unsigned short As2[64 * K2];
  __shared__ float lnp[2];
  char* a1b = (char*)As1;
  char* a2b = (char*)As2;
  const int tid = threadIdx.x;
  const int lane = tid & 63;
  const int wv = tid >> 6;
  const int r0 = blockIdx.x * 64;

  if (tid < 64) {
    float s1 = bins[tid] + bins[tid + 64];
    float s2 = bins[tid + 128] + bins[tid + 192];
#pragma unroll
    for (int mm = 1; mm < 64; mm <<= 1) {
      s1 += __shfl_xor(s1, mm, 64);
      s2 += __shfl_xor(s2, mm, 64);
    }
    if (tid == 0) {
      const float mu = s1 * invNF;
      lnp[0] = mu;
      lnp[1] = rsqrtf(s2 * invNF - mu * mu + 1e-5f);
    }
  }
  __syncthreads();
  const float mu = lnp[0], rs = lnp[1];

  for (int c = tid; c < 64 * (K1 / 8); c += 256) {  // stage h3 (bf16) with LN+relu
    const int row = c / (K1 / 8);
    const int k0 = (c - row * (K1 / 8)) * 8;
    const int gr = r0 + row;
    short8 a = {0, 0, 0, 0, 0, 0, 0, 0};
    if (gr < n) {
      a = *reinterpret_cast<const short8*>(&h3[(size_t)gr * K1 + k0]);
      float g[8], bb[8];
      *(float4*)&g[0] = *(const float4*)&lng[k0];
      *(float4*)&g[4] = *(const float4*)&lng[k0 + 4];
      *(float4*)&bb[0] = *(const float4*)&lnb[k0];
      *(float4*)&bb[4] = *(const float4*)&lnb[k0 + 4];
#pragma unroll
      for (int q = 0; q < 8; ++q) {
        float f = bf2f((unsigned short)a[q]);
        f = fmaxf(fmaf(f - mu, rs * g[q], bb[q]), 0.f);
        a[q] = (short)f2bf(f);
      }
    }
    const int boff = ((row * K1 + k0) * 2) ^ ((row & 7) << 4);
    *(short8*)(a1b + boff) = a;
  }
  for (int c = tid; c < 64 * (K2 / 8); c += 256) {  // stage xb
    const int row = c / (K2 / 8);
    const int k0 = (c - row * (K2 / 8)) * 8;
    const int gr = r0 + row;
    short8 a = {0, 0, 0, 0, 0, 0, 0, 0};
    if (gr < n) a = *reinterpret_cast<const short8*>(&xb[(size_t)gr * K2 + k0]);
    const int boff = ((row * K2 + k0) * 2) ^ ((row & 7) << 4);
    *(short8*)(a2b + boff) = a;
  }
  __syncthreads();

  const int rl = lane & 15;
  const int ks = lane >> 4;
  f32x4 a1[4], a2[4];
#pragma unroll
  for (int rt = 0; rt < 4; ++rt) {
    a1[rt] = (f32x4){0.f, 0.f, 0.f, 0.f};
    a2[rt] = (f32x4){0.f, 0.f, 0.f, 0.f};
  }
#pragma unroll
  for (int kk = 0; kk < K1 / 32; ++kk) {
    short8 bf = *reinterpret_cast<const short8*>(
        &WTe[(size_t)(wv * 16 + rl) * K1 + kk * 32 + ks * 8]);
#pragma unroll
    for (int rt = 0; rt < 4; ++rt) {
      const int row = rt * 16 + rl;
      const int boff = ((row * K1 + kk * 32 + ks * 8) * 2) ^ ((row & 7) << 4);
      short8 af = *(const short8*)(a1b + boff);
      a1[rt] = __builtin_amdgcn_mfma_f32_16x16x32_bf16(af, bf, a1[rt], 0, 0, 0);
    }
  }
#pragma unroll
  for (int kk = 0; kk < K2 / 32; ++kk) {
    short8 bf = *reinterpret_cast<const short8*>(
        &WTrp[(size_t)(wv * 16 + rl) * K2 + kk * 32 + ks * 8]);
#pragma unroll
    for (int rt = 0; rt < 4; ++rt) {
      const int row = rt * 16 + rl;
      const int boff = ((row * K2 + kk * 32 + ks * 8) * 2) ^ ((row & 7) << 4);
      short8 af = *(const short8*)(a2b + boff);
      a2[rt] = __builtin_amdgcn_mfma_f32_16x16x32_bf16(af, bf, a2[rt], 0, 0, 0);
    }
  }
  const int col = wv * 16 + rl;
  const float be = Be[col];
  const float brp = Brp[col];
#pragma unroll
  for (int rt = 0; rt < 4; ++rt) {
    const int rowd = r0 + rt * 16 + ks * 4;
#pragma unroll
    for (int r = 0; r < 4; ++r) {
      const int gr = rowd + r;
      if (gr >= n) continue;
      const float o = fmaxf(a1[rt][r] + be, 0.f) + a2[rt][r] + brp;
      const size_t idx = (size_t)gr * F + col;
      z[idx] = o;
      zb[idx] = f2bf(o);
    }
  }
}

// ---------------- GATv2 edge aggregation (fp16 packed) -----------------------
template <int VEC> struct RawT;
template <> struct RawT<2> { using T = unsigned; };
template <> struct RawT<4> { using T = unsigned long long; };

// one node per wave (64 lanes, CS=64 raw elems/row); depth-2 gather pipeline;
// 2 edges per iter; online softmax w/ defer-max; bf16 out + LN-stat epilogue.
template <int F, int H, int VEC, int HAS_RES>
__global__ __launch_bounds__(256) void agg_k(
    const _Float16* __restrict__ xl, const _Float16* __restrict__ xr,
    const float* __restrict__ att, const float* __restrict__ bo,
    const int* __restrict__ starts, const int* __restrict__ deg,
    const int* __restrict__ esrc, unsigned short* __restrict__ out,
    float* __restrict__ bins, int n) {
  constexpr int G = 64 / H;   // lanes per head group
  constexpr int NP = VEC / 2;
  using RT = typename RawT<VEC>::T;
  union PU { RT r; h2 h[NP]; _Float16 e[VEC]; };
  const h2 HC = {(_Float16)0.2f, (_Float16)0.2f};
  const h2 HZ = {(_Float16)0.f, (_Float16)0.f};
  const int lane = threadIdx.x & 63;
  const int wv = threadIdx.x >> 6;
  const int node = blockIdx.x * 4 + wv;
  const bool active = node < n;
  const int nl = active ? node : 0;
  float s1w = 0.f, s2w = 0.f;

  const RT* xlr = (const RT*)xl;
  PU xru; xru.r = ((const RT*)xr)[(size_t)nl * 64 + lane];
  h2 attp[NP];
  float bov[VEC];
  PU resu; resu.r = 0;
#pragma unroll
  for (int pp = 0; pp < NP; ++pp) {
    attp[pp][0] = (_Float16)att[lane * VEC + pp * 2];
    attp[pp][1] = (_Float16)att[lane * VEC + pp * 2 + 1];
  }
#pragma unroll
  for (int q = 0; q < VEC; ++q) bov[q] = bo[lane * VEC + q];
  unsigned short resb[VEC];
  if (HAS_RES) {
#pragma unroll
    for (int q = 0; q < VEC; ++q) resb[q] = out[(size_t)nl * F + lane * VEC + q];
  }
  int st = 0, cnt = 0;
  if (active) { st = starts[node]; cnt = deg[node]; }
  const int total = active ? cnt + 1 : 0;
  auto LD = [&](int i) -> RT {
    const int j = (i < cnt) ? esrc[st + i] : nl;
    return xlr[(size_t)j * 64 + lane];
  };
  float m = -1e30f, s = 0.f, acc[VEC];
#pragma unroll
  for (int q = 0; q < VEC; ++q) acc[q] = 0.f;

  RT q0 = LD(0), q1 = LD(1), q2 = LD(2), q3 = LD(3);
  for (int it = 0; it < total; it += 2) {
    const RT f0 = LD(it + 4), f1 = LD(it + 5);
    PU x0, x1; x0.r = q0; x1.r = q1;
    float e0 = 0.f, e1 = 0.f;
#pragma unroll
    for (int pp = 0; pp < NP; ++pp) {
      h2 t0 = xru.h[pp] + x0.h[pp];
      h2 t1 = xru.h[pp] + x1.h[pp];
      h2 lk0 = __builtin_elementwise_fma(__builtin_elementwise_min(t0, HZ), HC,
                                         __builtin_elementwise_max(t0, HZ));
      h2 lk1 = __builtin_elementwise_fma(__builtin_elementwise_min(t1, HZ), HC,
                                         __builtin_elementwise_max(t1, HZ));
      dot2(e0, lk0, attp[pp]);
      dot2(e1, lk1, attp[pp]);
    }
#pragma unroll
    for (int mask = 1; mask < G; mask <<= 1) {
      e0 += __shfl_xor(e0, mask, 64);
      e1 += __shfl_xor(e1, mask, 64);
    }
    if (it + 1 >= total) e1 = -1e30f;
    const float eM = fmaxf(e0, e1);
    if (eM - m > 8.f) {
      const float sc = __expf(m - eM);
      s *= sc;
#pragma unroll
      for (int q = 0; q < VEC; ++q) acc[q] *= sc;
      m = eM;
    }
    const float p0 = __expf(e0 - m);
    const float p1 = __expf(e1 - m);
    s += p0 + p1;
#pragma unroll
    for (int q = 0; q < VEC; ++q)
      acc[q] = fmaf(p0, (float)x0.e[q], fmaf(p1, (float)x1.e[q], acc[q]));
    q0 = q2; q1 = q3; q2 = f0; q3 = f1;
  }
  if (active) {
    const float inv = 1.f / s;
#pragma unroll
    for (int q = 0; q < VEC; ++q) {
      float o = acc[q] * inv + bov[q];
      if (HAS_RES) o += bf2f(resb[q]);
      out[(size_t)node * F + lane * VEC + q] = f2bf(o);
      s1w += o;
      s2w += o * o;
    }
  }
#pragma unroll
  for (int mask = 1; mask < 64; mask <<= 1) {
    s1w += __shfl_xor(s1w, mask, 64);
    s2w += __shfl_xor(s2w, mask, 64);
  }
  __shared__ float sh[8];
  if (lane == 0) { sh[wv] = s1w; sh[4 + wv] = s2w; }
  __syncthreads();
  if (threadIdx.x == 0) {
    const int bin = blockIdx.x & 127;
    atomicAdd(&bins[bin], sh[0] + sh[1] + sh[2] + sh[3]);
    atomicAdd(&bins[128 + bin], sh[4] + sh[5] + sh[6] + sh[7]);
  }
}

// conv1 (F=64, H=1): two nodes per wave, 32 lanes x VEC=2 each.
__global__ __launch_bounds__(256) void agg1_k(
    const _Float16* __restrict__ xl, const _Float16* __restrict__ xr,
    const float* __restrict__ att, const float* __restrict__ bo,
    const int* __restrict__ starts, const int* __restrict__ deg,
    const int* __restrict__ esrc, unsigned short* __restrict__ out,
    float* __restrict__ bins, int n) {
  union PU { unsigned r; h2 h; _Float16 e[2]; };
  const h2 HC = {(_Float16)0.2f, (_Float16)0.2f};
  const h2 HZ = {(_Float16)0.f, (_Float16)0.f};
  const int lane = threadIdx.x & 63;
  const int wv = threadIdx.x >> 6;
  const int l32 = lane & 31;
  const int node = blockIdx.x * 8 + wv * 2 + (lane >> 5);
  const bool active = node < n;
  const int nl = active ? node : 0;
  float s1w = 0.f, s2w = 0.f;

  const unsigned* xlr = (const unsigned*)xl;
  PU xru; xru.r = ((const unsigned*)xr)[(size_t)nl * 32 + l32];
  h2 attp = {(_Float16)att[l32 * 2], (_Float16)att[l32 * 2 + 1]};
  const float bo0 = bo[l32 * 2], bo1 = bo[l32 * 2 + 1];
  int st = 0, cnt = 0;
  if (active) { st = starts[node]; cnt = deg[node]; }
  const int total = active ? cnt + 1 : 0;
  const int mt = max(total, __shfl_xor(total, 32, 64));
  auto LD = [&](int i) -> unsigned {
    const int j = (i < cnt) ? esrc[st + i] : nl;
    return xlr[(size_t)j * 32 + l32];
  };
  float m = -1e30f, s = 0.f, a0 = 0.f, a1 = 0.f;
  unsigned q0 = LD(0), q1 = LD(1), q2 = LD(2), q3 = LD(3);
  for (int it = 0; it < mt; it += 2) {
    const unsigned f0 = LD(it + 4), f1 = LD(it + 5);
    PU x0, x1; x0.r = q0; x1.r = q1;
    float e0 = 0.f, e1 = 0.f;
    {
      h2 t0 = xru.h + x0.h;
      h2 t1 = xru.h + x1.h;
      h2 lk0 = __builtin_elementwise_fma(__builtin_elementwise_min(t0, HZ), HC,
                                         __builtin_elementwise_max(t0, HZ));
      h2 lk1 = __builtin_elementwise_fma(__builtin_elementwise_min(t1, HZ), HC,
                                         __builtin_elementwise_max(t1, HZ));
      dot2(e0, lk0, attp);
      dot2(e1, lk1, attp);
    }
#pragma unroll
    for (int mask = 1; mask < 32; mask <<= 1) {
      e0 += __shfl_xor(e0, mask, 64);
      e1 += __shfl_xor(e1, mask, 64);
    }
    if (it >= total) e0 = -1e30f;
    if (it + 1 >= total) e1 = -1e30f;
    const float eM = fmaxf(e0, e1);
    if (eM - m > 8.f && eM > -1e29f) {
      const float sc = __expf(m - eM);
      s *= sc; a0 *= sc; a1 *= sc;
      m = eM;
    }
    const float p0 = __expf(e0 - m);
    const float p1 = __expf(e1 - m);
    s += p0 + p1;
    a0 = fmaf(p0, (float)x0.e[0], fmaf(p1, (float)x1.e[0], a0));
    a1 = fmaf(p0, (float)x0.e[1], fmaf(p1, (float)x1.e[1], a1));
    q0 = q2; q1 = q3; q2 = f0; q3 = f1;
  }
  if (active) {
    const float inv = 1.f / s;
    const float o0 = a0 * inv + bo0;
    const float o1 = a1 * inv + bo1;
    out[(size_t)node * 64 + l32 * 2] = f2bf(o0);
    out[(size_t)node * 64 + l32 * 2 + 1] = f2bf(o1);
    s1w = o0 + o1;
    s2w = o0 * o0 + o1 * o1;
  }
#pragma unroll
  for (int mask = 1; mask < 64; mask <<= 1) {
    s1w += __shfl_xor(s1w, mask, 64);
    s2w += __shfl_xor(s2w, mask, 64);
  }
  __shared__ float sh[8];
  if (lane == 0) { sh[wv] = s1w; sh[4 + wv] = s2w; }
  __syncthreads();
  if (threadIdx.x == 0) {
    const int bin = blockIdx.x & 127;
    atomicAdd(&bins[bin], sh[0] + sh[1] + sh[2] + sh[3]);
    atomicAdd(&bins[128 + bin], sh[4] + sh[5] + sh[6] + sh[7]);
  }
}

// ---------------- column mean (z_graph) -------------------------------------
__global__ void colmean_k(const float* __restrict__ z, float* __restrict__ outv,
                          int n, float inv) {
  __shared__ float sh[256];
  int col = threadIdx.x & 63;
  int w = threadIdx.x >> 6;
  float s = 0.f;
  for (int r = blockIdx.x * 4 + w; r < n; r += gridDim.x * 4)
    s += z[(size_t)r * 64 + col];
  sh[threadIdx.x] = s;
  __syncthreads();
  if (threadIdx.x < 64) {
    float t = sh[threadIdx.x] + sh[threadIdx.x + 64] + sh[threadIdx.x + 128] +
              sh[threadIdx.x + 192];
    atomicAdd(&outv[col], t * inv);
  }
}

// ---------------------------------------------------------------------------
extern "C" void kernel_launch(void* const* d_in, const int* in_sizes, int n_in,
                              void* d_out, int out_size, void* d_ws, size_t ws_size,
                              hipStream_t stream) {
  const float* x = (const float*)d_in[0];
  const int* ei = (const int*)d_in[1];
  const float *Wl1 = (const float*)d_in[3], *bl1 = (const float*)d_in[4];
  const float *Wr1 = (const float*)d_in[5], *br1 = (const float*)d_in[6];
  const float *att1 = (const float*)d_in[7], *bo1 = (const float*)d_in[8];
  const float *Wl2 = (const float*)d_in[9], *bl2 = (const float*)d_in[10];
  const float *Wr2 = (const float*)d_in[11], *br2 = (const float*)d_in[12];
  const float *att2 = (const float*)d_in[13], *bo2 = (const float*)d_in[14];
  const float *Wres2 = (const float*)d_in[15];
  const float *Wl3 = (const float*)d_in[16], *bl3 = (const float*)d_in[17];
  const float *Wr3 = (const float*)d_in[18], *br3 = (const float*)d_in[19];
  const float *att3 = (const float*)d_in[20], *bo3 = (const float*)d_in[21];
  const float *Wres3 = (const float*)d_in[22];
  const float *ln1g = (const float*)d_in[23], *ln1b = (const float*)d_in[24];
  const float *ln2g = (const float*)d_in[25], *ln2b = (const float*)d_in[26];
  const float *ln3g = (const float*)d_in[27], *ln3b = (const float*)d_in[28];
  const float *encW = (const float*)d_in[29], *encb = (const float*)d_in[30];
  const float *rpW = (const float*)d_in[31], *rpb = (const float*)d_in[32];
  const float *d1W = (const float*)d_in[33], *d1b = (const float*)d_in[34];
  const float *d2W = (const float*)d_in[35], *d2b = (const float*)d_in[36];
  const float *d3W = (const float*)d_in[37], *d3b = (const float*)d_in[38];

  const int N = in_sizes[0] / 64;
  const int E = in_sizes[1] / 2;
  const int* esrc_in = ei;      // row 0: src
  const int* etgt_in = ei + E;  // row 1: tgt

  // ---- workspace layout ----
  char* cur = (char*)d_ws;
  auto take = [&](size_t bytes) {
    char* p = cur;
    cur += (bytes + 15) & ~(size_t)15;
    return p;
  };
  unsigned short* bufCb = (unsigned short*)take((size_t)N * 256 * 2);  // h1/h3 bf16
  unsigned short* bufDb = (unsigned short*)take((size_t)N * 128 * 2);  // h2 bf16
  _Float16* Ab = (_Float16*)take((size_t)N * 256 * 2);                 // xl fp16
  _Float16* Bb = (_Float16*)take((size_t)N * 256 * 2);                 // xr fp16
  unsigned short* Cb = (unsigned short*)take((size_t)N * 256 * 2);     // dh2 bf16
  unsigned short* Db = (unsigned short*)take((size_t)N * 128 * 2);     // dh1 bf16
  unsigned short* xb = (unsigned short*)take((size_t)N * 64 * 2);      // xbf -> zb
  float* stats = (float*)take(768 * 4);                                // 3 x (128+128)
  int* deg = (int*)take((size_t)N * 4);
  int* starts = (int*)take((size_t)N * 4);
  int* cursor = (int*)take((size_t)N * 4);
  int* bsum = (int*)take(1024);
  int* esrc = (int*)take((size_t)E * 4);
  auto wt = [&](int K, int F) { return (unsigned short*)take((size_t)K * F * 2); };
  unsigned short *Tl1 = wt(64, 64), *Tr1 = wt(64, 64);
  unsigned short *Tl2 = wt(64, 128), *Tr2 = wt(64, 128), *Tres2 = wt(64, 128);
  unsigned short *Tl3 = wt(128, 256), *Tr3 = wt(128, 256), *Tres3 = wt(128, 256);
  unsigned short *Tenc = wt(256, 64), *Trp = wt(64, 64);
  unsigned short *Td1 = wt(64, 128), *Td2 = wt(128, 64), *Td3 = wt(64, 64);
  if ((size_t)(cur - (char*)d_ws) > ws_size) return;

  float* z = (float*)d_out;           // z_nodes (N x 64)
  float* xhat = z + (size_t)N * 64;   // x_hat   (N x 64)
  float* zg = xhat + (size_t)N * 64;  // z_graph (64)

  zero_k<<<(N + 255) / 256, 256, 0, stream>>>(deg, N, stats, zg);

  // ---- weight conversion: one fused launch ----
  {
    WPack p;
    const float* Ws[13] = {Wl1, Wr1, Wl2, Wr2, Wres2, Wl3, Wr3, Wres3,
                           encW, rpW, d1W, d2W, d3W};
    unsigned short* Ts[13] = {Tl1, Tr1, Tl2, Tr2, Tres2, Tl3, Tr3, Tres3,
                              Tenc, Trp, Td1, Td2, Td3};
    const int Ks[13] = {64, 64, 64, 64, 64, 128, 128, 128, 256, 64, 64, 128, 64};
    const int Fs[13] = {64, 64, 128, 128, 128, 256, 256, 256, 64, 64, 128, 64, 64};
    int base = 0;
    for (int i = 0; i < 13; ++i) {
      p.s[i] = {Ws[i], Ts[i], Ks[i], Fs[i], base};
      base += Ks[i] * Fs[i];
    }
    p.total = base;
    wconv_all_k<<<(base + 255) / 256, 256, 0, stream>>>(p);
  }
  cvt_k<<<1024, 256, 0, stream>>>(x, xb, (size_t)N * 16);

  // ---- CSR by target ----
  const int nb = (N + 255) / 256;
  hist_k<<<512, 256, 0, stream>>>(etgt_in, deg, E);
  scan1_k<<<nb, 256, 0, stream>>>(deg, bsum, N);
  scan2_k<<<1, 256, 0, stream>>>(bsum, nb);
  scan3_k<<<nb, 256, 0, stream>>>(deg, bsum, starts, cursor, N);
  scatter_k<<<512, 256, 0, stream>>>(esrc_in, etgt_in, cursor, esrc, E);

  const int gblk = (N + 63) / 64;
  const int ablk = (N + 3) / 4;
  const float* nullf = nullptr;
  _Float16* nullh = nullptr;
  unsigned short* nullb = nullptr;
  float* nully = nullptr;

  // ---- conv1 ----
  mg_k<64, 64, 2, 0, 0, 0><<<gblk, 256, 0, stream>>>(
      xb, nullf, nullf, nullf, 0.f, Tl1, bl1, Tr1, br1, nullb, Ab, Bb, nullb, nully, N);
  agg1_k<<<(N + 7) / 8, 256, 0, stream>>>(Ab, Bb, att1, bo1, starts, deg, esrc, bufCb,
                                          stats + 0, N);
  // ---- conv2 (LN1 inline) ----
  mg_k<64, 128, 3, 1, 0, 0><<<gblk, 256, 0, stream>>>(
      bufCb, stats + 0, ln1g, ln1b, 1.f / ((float)N * 64.f), Tl2, bl2, Tr2, br2, Tres2,
      Ab, Bb, bufDb, nully, N);
  agg_k<128, 4, 2, 1><<<ablk, 256, 0, stream>>>(Ab, Bb, att2, bo2, starts, deg, esrc,
                                                bufDb, stats + 256, N);
  // ---- conv3 (LN2 inline) ----
  mg_k<128, 256, 3, 1, 0, 0><<<gblk, 256, 0, stream>>>(
      bufDb, stats + 256, ln2g, ln2b, 1.f / ((float)N * 128.f), Tl3, bl3, Tr3, br3,
      Tres3, Ab, Bb, bufCb, nully, N);
  agg_k<256, 4, 4, 1><<<ablk, 256, 0, stream>>>(Ab, Bb, att3, bo3, starts, deg, esrc,
                                                bufCb, stats + 512, N);
  // ---- encoder (LN3 inline) ----
  enc_k<<<gblk, 256, 0, stream>>>(bufCb, stats + 512, ln3g, ln3b,
                                  1.f / ((float)N * 256.f), Tenc, encb, xb, Trp, rpb, z,
                                  xb, N);
  // ---- z_graph ----
  colmean_k<<<256, 256, 0, stream>>>(z, zg, N, 1.f / (float)N);

  // ---- decoder ----
  mg_k<64, 128, 1, 0, 1, 1><<<gblk, 256, 0, stream>>>(
      xb, nullf, nullf, nullf, 0.f, Td1, d1b, nullb, nullf, nullb, nullh, nullh, Db,
      nully, N);
  mg_k<128, 64, 1, 0, 1, 1><<<gblk, 256, 0, stream>>>(
      Db, nullf, nullf, nullf, 0.f, Td2, d2b, nullb, nullf, nullb, nullh, nullh, Cb,
      nully, N);
  mg_k<64, 64, 1, 0, 2, 0><<<gblk, 256, 0, stream>>>(
      Cb, nullf, nullf, nullf, 0.f, Td3, d3b, nullb, nullf, nullb, nullh, nullh, nullb,
      xhat, N);
}

// Round 7
// 448.723 us; speedup vs baseline: 3.0345x; 1.1296x over previous
//
#include <hip/hip_runtime.h>
#include <math.h>

typedef __attribute__((ext_vector_type(8))) short short8;
typedef __attribute__((ext_vector_type(4))) float f32x4;
typedef _Float16 h2 __attribute__((ext_vector_type(2)));

__device__ __forceinline__ unsigned short f2bf(float f) {
  union { float f; unsigned u; } c; c.f = f;
  unsigned r = c.u + 0x7fffu + ((c.u >> 16) & 1u);
  return (unsigned short)(r >> 16);
}
__device__ __forceinline__ float bf2f(unsigned short u) {
  union { unsigned u; float f; } c; c.u = ((unsigned)u) << 16;
  return c.f;
}
__device__ __forceinline__ void dot2(float& e, h2 a, h2 b) {
  asm("v_dot2_f32_f16 %0, %1, %2, %0" : "+v"(e) : "v"(a), "v"(b));
}

// ---------------- CSR build ----------------
__global__ void hist_k(const int* __restrict__ tgt, int* __restrict__ deg, int E) {
  int stride = gridDim.x * blockDim.x;
  for (int e = blockIdx.x * blockDim.x + threadIdx.x; e < E; e += stride)
    atomicAdd(&deg[tgt[e]], 1);
}

__global__ void scan1_k(const int* __restrict__ deg, int* __restrict__ bsum, int n) {
  __shared__ int sh[256];
  int idx = blockIdx.x * 256 + threadIdx.x;
  sh[threadIdx.x] = (idx < n) ? deg[idx] : 0;
  __syncthreads();
  for (int off = 128; off > 0; off >>= 1) {
    if (threadIdx.x < off) sh[threadIdx.x] += sh[threadIdx.x + off];
    __syncthreads();
  }
  if (threadIdx.x == 0) bsum[blockIdx.x] = sh[0];
}

__global__ void scan2_k(int* __restrict__ bsum, int nb) {
  __shared__ int sh[256];
  int t = threadIdx.x;
  int v = (t < nb) ? bsum[t] : 0;
  sh[t] = v; __syncthreads();
  for (int off = 1; off < 256; off <<= 1) {
    int add = (t >= off) ? sh[t - off] : 0;
    __syncthreads();
    sh[t] += add;
    __syncthreads();
  }
  if (t < nb) bsum[t] = sh[t] - v;  // exclusive
}

__global__ void scan3_k(const int* __restrict__ deg, const int* __restrict__ bsum,
                        int* __restrict__ starts, int* __restrict__ cursor, int n) {
  __shared__ int sh[256];
  int t = threadIdx.x;
  int idx = blockIdx.x * 256 + t;
  int v = (idx < n) ? deg[idx] : 0;
  sh[t] = v; __syncthreads();
  for (int off = 1; off < 256; off <<= 1) {
    int add = (t >= off) ? sh[t - off] : 0;
    __syncthreads();
    sh[t] += add;
    __syncthreads();
  }
  if (idx < n) {
    int ex = bsum[blockIdx.x] + sh[t] - v;
    starts[idx] = ex;
    cursor[idx] = ex;
  }
}

__global__ void scatter_k(const int* __restrict__ src, const int* __restrict__ tgt,
                          int* __restrict__ cursor, int* __restrict__ esrc, int E) {
  int stride = gridDim.x * blockDim.x;
  for (int e = blockIdx.x * blockDim.x + threadIdx.x; e < E; e += stride) {
    int p = atomicAdd(&cursor[tgt[e]], 1);
    esrc[p] = src[e];
  }
}

// ---------------- fused prep: weight transpose+cvt, x cvt, zero -------------
struct WSeg { const float* W; unsigned short* T; int K; int F; int base; };
struct WPack { WSeg s[13]; int total; };
__global__ __launch_bounds__(256) void prep_k(WPack p, int WB, const float* __restrict__ x,
                                              unsigned short* __restrict__ xb, size_t n4,
                                              int CB, int* __restrict__ deg, int n,
                                              float* __restrict__ stats,
                                              float* __restrict__ zgb) {
  const int bid = blockIdx.x;
  const int tid = threadIdx.x;
  if (bid < WB) {
    int idx = bid * 256 + tid;
    if (idx >= p.total) return;
    int si = 0;
#pragma unroll
    for (int i = 1; i < 13; ++i) si = (idx >= p.s[i].base) ? i : si;
    const WSeg sg = p.s[si];
    const int loc = idx - sg.base;
    const int k = loc / sg.F, f = loc - k * sg.F;
    sg.T[(size_t)f * sg.K + k] = f2bf(sg.W[loc]);
  } else if (bid < WB + CB) {
    size_t stride = (size_t)CB * 256;
    for (size_t i = (size_t)(bid - WB) * 256 + tid; i < n4; i += stride) {
      float4 v = reinterpret_cast<const float4*>(x)[i];
      ushort4 o;
      o.x = f2bf(v.x); o.y = f2bf(v.y); o.z = f2bf(v.z); o.w = f2bf(v.w);
      reinterpret_cast<ushort4*>(xb)[i] = o;
    }
  } else {
    int zi = (bid - WB - CB) * 256 + tid;
    if (zi < n) deg[zi] = 0;
    if (zi < 768) stats[zi] = 0.f;
    if (zi < 1024) zgb[zi] = 0.f;
  }
}

// ---------------- universal MFMA GEMM, 64-row block tile ---------------------
// X bf16 (optional inline graph-LN+relu), staged in LDS (XOR-swizzled).
// set0/set1 -> fp16 Y0/Y1 (biases); set2 -> bf16 Y2b (residual, no bias).
template <int K, int F, int SETS, int LNF>
__global__ __launch_bounds__(256) void mg_k(
    const unsigned short* __restrict__ X, const float* __restrict__ bins,
    const float* __restrict__ lng, const float* __restrict__ lnb, float invNF,
    const unsigned short* __restrict__ WT0, const float* __restrict__ B0,
    const unsigned short* __restrict__ WT1, const float* __restrict__ B1,
    const unsigned short* __restrict__ WT2,
    _Float16* __restrict__ Y0, _Float16* __restrict__ Y1,
    unsigned short* __restrict__ Y2b, int n) {
  constexpr int NK = K / 32;
  constexpr int TL = F / 64;
  constexpr int CPR = K / 8;
  __shared__ unsigned short As[64 * K];
  __shared__ float lnp[2];
  char* asb = (char*)As;
  const int tid = threadIdx.x;
  const int lane = tid & 63;
  const int wv = tid >> 6;
  const int r0 = blockIdx.x * 64;

  if (LNF) {
    if (tid < 64) {
      float s1 = bins[tid] + bins[tid + 64];
      float s2 = bins[tid + 128] + bins[tid + 192];
#pragma unroll
      for (int mm = 1; mm < 64; mm <<= 1) {
        s1 += __shfl_xor(s1, mm, 64);
        s2 += __shfl_xor(s2, mm, 64);
      }
      if (tid == 0) {
        const float mu = s1 * invNF;
        lnp[0] = mu;
        lnp[1] = rsqrtf(s2 * invNF - mu * mu + 1e-5f);
      }
    }
    __syncthreads();
  }
  const float mu = LNF ? lnp[0] : 0.f;
  const float rs = LNF ? lnp[1] : 0.f;

  for (int c = tid; c < 64 * CPR; c += 256) {
    const int row = c / CPR;
    const int k0 = (c - row * CPR) * 8;
    const int gr = r0 + row;
    short8 a = {0, 0, 0, 0, 0, 0, 0, 0};
    if (gr < n) {
      a = *reinterpret_cast<const short8*>(&X[(size_t)gr * K + k0]);
      if (LNF) {
        float g[8], bb[8];
        *(float4*)&g[0] = *(const float4*)&lng[k0];
        *(float4*)&g[4] = *(const float4*)&lng[k0 + 4];
        *(float4*)&bb[0] = *(const float4*)&lnb[k0];
        *(float4*)&bb[4] = *(const float4*)&lnb[k0 + 4];
#pragma unroll
        for (int q = 0; q < 8; ++q) {
          float f = bf2f((unsigned short)a[q]);
          f = fmaxf(fmaf(f - mu, rs * g[q], bb[q]), 0.f);
          a[q] = (short)f2bf(f);
        }
      }
    }
    const int boff = ((row * K + k0) * 2) ^ ((row & 7) << 4);
    *(short8*)(asb + boff) = a;
  }
  __syncthreads();

  const int rl = lane & 15;
  const int ks = lane >> 4;
#pragma unroll
  for (int set = 0; set < SETS; ++set) {
    const unsigned short* WT = (set == 0) ? WT0 : (set == 1) ? WT1 : WT2;
    f32x4 acc[4][TL];
#pragma unroll
    for (int rt = 0; rt < 4; ++rt)
#pragma unroll
      for (int t = 0; t < TL; ++t) acc[rt][t] = (f32x4){0.f, 0.f, 0.f, 0.f};
#pragma unroll
    for (int kk = 0; kk < NK; ++kk) {
      short8 bf[TL];
#pragma unroll
      for (int t = 0; t < TL; ++t)
        bf[t] = *reinterpret_cast<const short8*>(
            &WT[(size_t)((wv * TL + t) * 16 + rl) * K + kk * 32 + ks * 8]);
      short8 af[4];
#pragma unroll
      for (int rt = 0; rt < 4; ++rt) {
        const int row = rt * 16 + rl;
        const int boff = ((row * K + kk * 32 + ks * 8) * 2) ^ ((row & 7) << 4);
        af[rt] = *(const short8*)(asb + boff);
      }
#pragma unroll
      for (int rt = 0; rt < 4; ++rt)
#pragma unroll
        for (int t = 0; t < TL; ++t)
          acc[rt][t] =
              __builtin_amdgcn_mfma_f32_16x16x32_bf16(af[rt], bf[t], acc[rt][t], 0, 0, 0);
    }
#pragma unroll
    for (int rt = 0; rt < 4; ++rt) {
      const int rowd = r0 + rt * 16 + ks * 4;
#pragma unroll
      for (int t = 0; t < TL; ++t) {
        const int col = (wv * TL + t) * 16 + rl;
        const float bias = (set == 0) ? B0[col] : (set == 1) ? B1[col] : 0.f;
#pragma unroll
        for (int r = 0; r < 4; ++r) {
          const int gr = rowd + r;
          if (gr >= n) continue;
          float o = acc[rt][t][r] + bias;
          const size_t idx = (size_t)gr * F + col;
          if (set == 0) Y0[idx] = (_Float16)o;
          else if (set == 1) Y1[idx] = (_Float16)o;
          else Y2b[idx] = f2bf(o);
        }
      }
    }
  }
}

// ---------------- GATv2 edge aggregation: split-wave, fp16 packed ------------
// NPW nodes/wave; per node, lanes split into 2 edge-halves of LPE lanes; each
// half processes one edge/iter (all F channels, VEC per lane). Shared online
// max via cross-half exchange; fp16 packed accumulate (defer THR=4 keeps p<=e^4).
template <int F, int H, int NPW, int HAS_RES>
__global__ __launch_bounds__(256) void agg_t(
    const _Float16* __restrict__ xl, const _Float16* __restrict__ xr,
    const float* __restrict__ att, const float* __restrict__ bo,
    const int* __restrict__ starts, const int* __restrict__ deg,
    const int* __restrict__ esrc, unsigned short* __restrict__ out,
    float* __restrict__ bins, int n) {
  constexpr int LPN = 64 / NPW;   // lanes per node
  constexpr int LPE = LPN / 2;    // lanes per edge-half
  constexpr int VEC = F / LPE;    // fp16 channels per lane
  constexpr int NP = VEC / 2;     // h2 regs per lane
  constexpr int RED = LPE / H;    // lanes per head group
  union PU { unsigned u[NP]; h2 h[NP]; _Float16 e[VEC]; };
  const h2 HC = {(_Float16)0.2f, (_Float16)0.2f};
  const h2 HZ = {(_Float16)0.f, (_Float16)0.f};
  const int lane = threadIdx.x & 63;
  const int wv = threadIdx.x >> 6;
  const int le = lane & (LPN - 1);
  const int sub = le / LPE;
  const int l_e = le & (LPE - 1);
  const int node = blockIdx.x * 4 * NPW + wv * NPW + ((NPW == 2) ? (lane >> 5) : 0);
  const bool active = node < n;
  const int nl = active ? node : 0;
  const int ch0 = l_e * VEC;

  auto loadrow = [&](int j, PU& r) {
    const char* p = (const char*)xl + ((size_t)j * F + ch0) * 2;
    if constexpr (VEC == 8) {
      uint4 v = *(const uint4*)p;
      r.u[0] = v.x; r.u[1] = v.y; r.u[2] = v.z; r.u[3] = v.w;
    } else {
      uint2 v = *(const uint2*)p;
      r.u[0] = v.x; r.u[1] = v.y;
    }
  };

  PU xru;
  loadrow(0, xru);  // placeholder; real load below (xr not xl)
  {
    const char* p = (const char*)xr + ((size_t)nl * F + ch0) * 2;
    if constexpr (VEC == 8) {
      uint4 v = *(const uint4*)p;
      xru.u[0] = v.x; xru.u[1] = v.y; xru.u[2] = v.z; xru.u[3] = v.w;
    } else {
      uint2 v = *(const uint2*)p;
      xru.u[0] = v.x; xru.u[1] = v.y;
    }
  }
  h2 attp[NP];
  float bov[VEC];
  unsigned short resb[VEC];
#pragma unroll
  for (int pp = 0; pp < NP; ++pp) {
    attp[pp][0] = (_Float16)att[ch0 + pp * 2];
    attp[pp][1] = (_Float16)att[ch0 + pp * 2 + 1];
  }
#pragma unroll
  for (int q = 0; q < VEC; ++q) {
    bov[q] = bo[ch0 + q];
    if (HAS_RES) resb[q] = out[(size_t)nl * F + ch0 + q];
  }
  int st = 0, cnt = 0;
  if (active) { st = starts[node]; cnt = deg[node]; }
  const int total = active ? cnt + 1 : 0;
  int mt = total;
  if constexpr (NPW == 2) {
    int ot = __shfl_xor(total, 32, 64);
    mt = max(total, ot);
  }
  auto getj = [&](int idx) -> int {
    int j = nl;
    if (idx < cnt) j = esrc[st + idx];
    return j;
  };

  float m = -1e30f, s = 0.f;
  PU acc;
#pragma unroll
  for (int pp = 0; pp < NP; ++pp) acc.h[pp] = HZ;

  PU r0, r1;
  loadrow(getj(0 + sub), r0);
  loadrow(getj(2 + sub), r1);
  for (int it = 0; it < mt; it += 2) {
    PU rn;
    loadrow(getj(it + 4 + sub), rn);
    float e = 0.f;
#pragma unroll
    for (int pp = 0; pp < NP; ++pp) {
      h2 t = xru.h[pp] + r0.h[pp];
      h2 lk = __builtin_elementwise_fma(__builtin_elementwise_min(t, HZ), HC,
                                        __builtin_elementwise_max(t, HZ));
      dot2(e, lk, attp[pp]);
    }
#pragma unroll
    for (int mask = 1; mask < RED; mask <<= 1) e += __shfl_xor(e, mask, 64);
    if (it + sub >= total) e = -1e30f;
    const float eo = __shfl_xor(e, LPE, 64);
    const float eM = fmaxf(e, eo);
    if (eM - m > 4.f) {
      const float sc = __expf(m - eM);
      s *= sc;
      const _Float16 sch = (_Float16)sc;
      const h2 sv = {sch, sch};
#pragma unroll
      for (int pp = 0; pp < NP; ++pp) acc.h[pp] *= sv;
      m = eM;
    }
    const float p = __expf(e - m);
    s += p;
    const _Float16 ph = (_Float16)p;
    const h2 pv = {ph, ph};
#pragma unroll
    for (int pp = 0; pp < NP; ++pp)
      acc.h[pp] = __builtin_elementwise_fma(pv, r0.h[pp], acc.h[pp]);
    r0 = r1;
    r1 = rn;
  }
  // combine halves
  const float stot = s + __shfl_xor(s, LPE, 64);
  PU at;
#pragma unroll
  for (int pp = 0; pp < NP; ++pp) {
    PU tmp;
    tmp.u[0] = __shfl_xor(acc.u[pp], LPE, 64);
    at.h[pp] = acc.h[pp] + tmp.h[0];
  }
  float s1w = 0.f, s2w = 0.f;
  if (active && sub == 0) {
    const float inv = 1.f / stot;
    unsigned short ov[VEC];
#pragma unroll
    for (int q = 0; q < VEC; ++q) {
      float o = (float)at.e[q] * inv + bov[q];
      if (HAS_RES) o += bf2f(resb[q]);
      ov[q] = f2bf(o);
      s1w += o;
      s2w += o * o;
    }
    char* op = (char*)out + ((size_t)node * F + ch0) * 2;
    if constexpr (VEC == 8) {
      uint4 v;
      v.x = (unsigned)ov[0] | ((unsigned)ov[1] << 16);
      v.y = (unsigned)ov[2] | ((unsigned)ov[3] << 16);
      v.z = (unsigned)ov[4] | ((unsigned)ov[5] << 16);
      v.w = (unsigned)ov[6] | ((unsigned)ov[7] << 16);
      *(uint4*)op = v;
    } else {
      uint2 v;
      v.x = (unsigned)ov[0] | ((unsigned)ov[1] << 16);
      v.y = (unsigned)ov[2] | ((unsigned)ov[3] << 16);
      *(uint2*)op = v;
    }
  }
#pragma unroll
  for (int mask = 1; mask < 64; mask <<= 1) {
    s1w += __shfl_xor(s1w, mask, 64);
    s2w += __shfl_xor(s2w, mask, 64);
  }
  __shared__ float sh[8];
  if (lane == 0) { sh[wv] = s1w; sh[4 + wv] = s2w; }
  __syncthreads();
  if (threadIdx.x == 0) {
    const int bin = blockIdx.x & 127;
    atomicAdd(&bins[bin], sh[0] + sh[1] + sh[2] + sh[3]);
    atomicAdd(&bins[128 + bin], sh[4] + sh[5] + sh[6] + sh[7]);
  }
}

// ---------------- fused encoder + z_graph bins + decoder ---------------------
// z = relu(LN3(h3)@We+be) + xb@Wrp+brp; dh1=relu(z@d1); dh2=relu(dh1@d2);
// xhat=dh2@d3. All intermediates in LDS per 64-row block.
__global__ __launch_bounds__(256) void encdec_k(
    const unsigned short* __restrict__ h3, const float* __restrict__ bins,
    const float* __restrict__ lng, const float* __restrict__ lnb, float invNF,
    const unsigned short* __restrict__ WTe, const float* __restrict__ Be,
    const unsigned short* __restrict__ xb, const unsigned short* __restrict__ WTrp,
    const float* __restrict__ Brp, const unsigned short* __restrict__ Td1,
    const float* __restrict__ d1b, const unsigned short* __restrict__ Td2,
    const float* __restrict__ d2b, const unsigned short* __restrict__ Td3,
    const float* __restrict__ d3b, float* __restrict__ z, float* __restrict__ xhat,
    float* __restrict__ zgb, int n) {
  __shared__ char smem[49152];
  char* a1b = smem;            // h3 staged 64x256 (32KB) -> dh1 64x128
  char* a2b = smem + 32768;    // xb staged 64x64 (8KB) -> dh2 64x64
  char* zsb = smem + 40960;    // z bf16 64x64 (8KB)
  __shared__ float lnp[2];
  const int tid = threadIdx.x;
  const int lane = tid & 63;
  const int wv = tid >> 6;
  const int rl = lane & 15;
  const int ks = lane >> 4;
  const int r0 = blockIdx.x * 64;

  if (tid < 64) {
    float s1 = bins[tid] + bins[tid + 64];
    float s2 = bins[tid + 128] + bins[tid + 192];
#pragma unroll
    for (int mm = 1; mm < 64; mm <<= 1) {
      s1 += __shfl_xor(s1, mm, 64);
      s2 += __shfl_xor(s2, mm, 64);
    }
    if (tid == 0) {
      const float mu = s1 * invNF;
      lnp[0] = mu;
      lnp[1] = rsqrtf(s2 * invNF - mu * mu + 1e-5f);
    }
  }
  __syncthreads();
  const float mu = lnp[0], rs = lnp[1];

  for (int c = tid; c < 64 * 32; c += 256) {  // stage h3 with LN+relu (K=256)
    const int row = c / 32;
    const int k0 = (c - row * 32) * 8;
    const int gr = r0 + row;
    short8 a = {0, 0, 0, 0, 0, 0, 0, 0};
    if (gr < n) {
      a = *reinterpret_cast<const short8*>(&h3[(size_t)gr * 256 + k0]);
      float g[8], bb[8];
      *(float4*)&g[0] = *(const float4*)&lng[k0];
      *(float4*)&g[4] = *(const float4*)&lng[k0 + 4];
      *(float4*)&bb[0] = *(const float4*)&lnb[k0];
      *(float4*)&bb[4] = *(const float4*)&lnb[k0 + 4];
#pragma unroll
      for (int q = 0; q < 8; ++q) {
        float f = bf2f((unsigned short)a[q]);
        f = fmaxf(fmaf(f - mu, rs * g[q], bb[q]), 0.f);
        a[q] = (short)f2bf(f);
      }
    }
    const int boff = ((row * 256 + k0) * 2) ^ ((row & 7) << 4);
    *(short8*)(a1b + boff) = a;
  }
  for (int c = tid; c < 64 * 8; c += 256) {  // stage xb (K=64)
    const int row = c / 8;
    const int k0 = (c - row * 8) * 8;
    const int gr = r0 + row;
    short8 a = {0, 0, 0, 0, 0, 0, 0, 0};
    if (gr < n) a = *reinterpret_cast<const short8*>(&xb[(size_t)gr * 64 + k0]);
    const int boff = ((row * 64 + k0) * 2) ^ ((row & 7) << 4);
    *(short8*)(a2b + boff) = a;
  }
  __syncthreads();

  // ---- z stage ----
  {
    f32x4 a1[4], a2[4];
#pragma unroll
    for (int rt = 0; rt < 4; ++rt) {
      a1[rt] = (f32x4){0.f, 0.f, 0.f, 0.f};
      a2[rt] = (f32x4){0.f, 0.f, 0.f, 0.f};
    }
#pragma unroll
    for (int kk = 0; kk < 8; ++kk) {
      short8 bfr = *reinterpret_cast<const short8*>(
          &WTe[(size_t)(wv * 16 + rl) * 256 + kk * 32 + ks * 8]);
#pragma unroll
      for (int rt = 0; rt < 4; ++rt) {
        const int row = rt * 16 + rl;
        const int boff = ((row * 256 + kk * 32 + ks * 8) * 2) ^ ((row & 7) << 4);
        short8 af = *(const short8*)(a1b + boff);
        a1[rt] = __builtin_amdgcn_mfma_f32_16x16x32_bf16(af, bfr, a1[rt], 0, 0, 0);
      }
    }
#pragma unroll
    for (int kk = 0; kk < 2; ++kk) {
      short8 bfr = *reinterpret_cast<const short8*>(
          &WTrp[(size_t)(wv * 16 + rl) * 64 + kk * 32 + ks * 8]);
#pragma unroll
      for (int rt = 0; rt < 4; ++rt) {
        const int row = rt * 16 + rl;
        const int boff = ((row * 64 + kk * 32 + ks * 8) * 2) ^ ((row & 7) << 4);
        short8 af = *(const short8*)(a2b + boff);
        a2[rt] = __builtin_amdgcn_mfma_f32_16x16x32_bf16(af, bfr, a2[rt], 0, 0, 0);
      }
    }
    const int col = wv * 16 + rl;
    const float be = Be[col];
    const float brp = Brp[col];
    float colpart = 0.f;
#pragma unroll
    for (int rt = 0; rt < 4; ++rt) {
#pragma unroll
      for (int r = 0; r < 4; ++r) {
        const int lrow = rt * 16 + ks * 4 + r;
        const int gr = r0 + lrow;
        float o = fmaxf(a1[rt][r] + be, 0.f) + a2[rt][r] + brp;
        if (gr < n) {
          z[(size_t)gr * 64 + col] = o;
          colpart += o;
        } else {
          o = 0.f;
        }
        const int boff = ((lrow * 64 + col) * 2) ^ ((lrow & 7) << 4);
        *(unsigned short*)(zsb + boff) = f2bf(o);
      }
    }
    colpart += __shfl_xor(colpart, 16, 64);
    colpart += __shfl_xor(colpart, 32, 64);
    if (lane < 16) atomicAdd(&zgb[(blockIdx.x & 15) * 64 + col], colpart);
  }
  __syncthreads();

  // ---- dh1 = relu(z@d1W + d1b): K=64, F=128 -> a1b ----
  {
    f32x4 acc[4][2];
#pragma unroll
    for (int rt = 0; rt < 4; ++rt) {
      acc[rt][0] = (f32x4){0.f, 0.f, 0.f, 0.f};
      acc[rt][1] = (f32x4){0.f, 0.f, 0.f, 0.f};
    }
#pragma unroll
    for (int kk = 0; kk < 2; ++kk) {
      short8 bfr[2];
#pragma unroll
      for (int t = 0; t < 2; ++t)
        bfr[t] = *reinterpret_cast<const short8*>(
            &Td1[(size_t)((wv * 2 + t) * 16 + rl) * 64 + kk * 32 + ks * 8]);
#pragma unroll
      for (int rt = 0; rt < 4; ++rt) {
        const int row = rt * 16 + rl;
        const int boff = ((row * 64 + kk * 32 + ks * 8) * 2) ^ ((row & 7) << 4);
        short8 af = *(const short8*)(zsb + boff);
#pragma unroll
        for (int t = 0; t < 2; ++t)
          acc[rt][t] = __builtin_amdgcn_mfma_f32_16x16x32_bf16(af, bfr[t], acc[rt][t], 0, 0, 0);
      }
    }
#pragma unroll
    for (int rt = 0; rt < 4; ++rt) {
#pragma unroll
      for (int t = 0; t < 2; ++t) {
        const int col = (wv * 2 + t) * 16 + rl;
        const float bias = d1b[col];
#pragma unroll
        for (int r = 0; r < 4; ++r) {
          const int row = rt * 16 + ks * 4 + r;
          const float o = fmaxf(acc[rt][t][r] + bias, 0.f);
          const int boff = ((row * 128 + col) * 2) ^ ((row & 7) << 4);
          *(unsigned short*)(a1b + boff) = f2bf(o);
        }
      }
    }
  }
  __syncthreads();

  // ---- dh2 = relu(dh1@d2W + d2b): K=128, F=64 -> a2b ----
  {
    f32x4 acc[4];
#pragma unroll
    for (int rt = 0; rt < 4; ++rt) acc[rt] = (f32x4){0.f, 0.f, 0.f, 0.f};
#pragma unroll
    for (int kk = 0; kk < 4; ++kk) {
      short8 bfr = *reinterpret_cast<const short8*>(
          &Td2[(size_t)(wv * 16 + rl) * 128 + kk * 32 + ks * 8]);
#pragma unroll
      for (int rt = 0; rt < 4; ++rt) {
        const int row = rt * 16 + rl;
        const int boff = ((row * 128 + kk * 32 + ks * 8) * 2) ^ ((row & 7) << 4);
        short8 af = *(const short8*)(a1b + boff);
        acc[rt] = __builtin_amdgcn_mfma_f32_16x16x32_bf16(af, bfr, acc[rt], 0, 0, 0);
      }
    }
    const int col = wv * 16 + rl;
    const float bias = d2b[col];
#pragma unroll
    for (int rt = 0; rt < 4; ++rt) {
#pragma unroll
      for (int r = 0; r < 4; ++r) {
        const int row = rt * 16 + ks * 4 + r;
        const float o = fmaxf(acc[rt][r] + bias, 0.f);
        const int boff = ((row * 64 + col) * 2) ^ ((row & 7) << 4);
        *(unsigned short*)(a2b + boff) = f2bf(o);
      }
    }
  }
  __syncthreads();

  // ---- xhat = dh2@d3W + d3b: K=64, F=64 -> global ----
  {
    f32x4 acc[4];
#pragma unroll
    for (int rt = 0; rt < 4; ++rt) acc[rt] = (f32x4){0.f, 0.f, 0.f, 0.f};
#pragma unroll
    for (int kk = 0; kk < 2; ++kk) {
      short8 bfr = *reinterpret_cast<const short8*>(
          &Td3[(size_t)(wv * 16 + rl) * 64 + kk * 32 + ks * 8]);
#pragma unroll
      for (int rt = 0; rt < 4; ++rt) {
        const int row = rt * 16 + rl;
        const int boff = ((row * 64 + kk * 32 + ks * 8) * 2) ^ ((row & 7) << 4);
        short8 af = *(const short8*)(a2b + boff);
        acc[rt] = __builtin_amdgcn_mfma_f32_16x16x32_bf16(af, bfr, acc[rt], 0, 0, 0);
      }
    }
    const int col = wv * 16 + rl;
    const float bias = d3b[col];
#pragma unroll
    for (int rt = 0; rt < 4; ++rt) {
#pragma unroll
      for (int r = 0; r < 4; ++r) {
        const int gr = r0 + rt * 16 + ks * 4 + r;
        if (gr < n) xhat[(size_t)gr * 64 + col] = acc[rt][r] + bias;
      }
    }
  }
}

__global__ void colfin_k(const float* __restrict__ zgb, float* __restrict__ zg,
                         float invN) {
  const int c = threadIdx.x;  // 64 threads
  float s = 0.f;
#pragma unroll
  for (int b = 0; b < 16; ++b) s += zgb[b * 64 + c];
  zg[c] = s * invN;
}

// ---------------------------------------------------------------------------
extern "C" void kernel_launch(void* const* d_in, const int* in_sizes, int n_in,
                              void* d_out, int out_size, void* d_ws, size_t ws_size,
                              hipStream_t stream) {
  const float* x = (const float*)d_in[0];
  const int* ei = (const int*)d_in[1];
  const float *Wl1 = (const float*)d_in[3], *bl1 = (const float*)d_in[4];
  const float *Wr1 = (const float*)d_in[5], *br1 = (const float*)d_in[6];
  const float *att1 = (const float*)d_in[7], *bo1 = (const float*)d_in[8];
  const float *Wl2 = (const float*)d_in[9], *bl2 = (const float*)d_in[10];
  const float *Wr2 = (const float*)d_in[11], *br2 = (const float*)d_in[12];
  const float *att2 = (const float*)d_in[13], *bo2 = (const float*)d_in[14];
  const float *Wres2 = (const float*)d_in[15];
  const float *Wl3 = (const float*)d_in[16], *bl3 = (const float*)d_in[17];
  const float *Wr3 = (const float*)d_in[18], *br3 = (const float*)d_in[19];
  const float *att3 = (const float*)d_in[20], *bo3 = (const float*)d_in[21];
  const float *Wres3 = (const float*)d_in[22];
  const float *ln1g = (const float*)d_in[23], *ln1b = (const float*)d_in[24];
  const float *ln2g = (const float*)d_in[25], *ln2b = (const float*)d_in[26];
  const float *ln3g = (const float*)d_in[27], *ln3b = (const float*)d_in[28];
  const float *encW = (const float*)d_in[29], *encb = (const float*)d_in[30];
  const float *rpW = (const float*)d_in[31], *rpb = (const float*)d_in[32];
  const float *d1W = (const float*)d_in[33], *d1b = (const float*)d_in[34];
  const float *d2W = (const float*)d_in[35], *d2b = (const float*)d_in[36];
  const float *d3W = (const float*)d_in[37], *d3b = (const float*)d_in[38];

  const int N = in_sizes[0] / 64;
  const int E = in_sizes[1] / 2;
  const int* esrc_in = ei;      // row 0: src
  const int* etgt_in = ei + E;  // row 1: tgt

  // ---- workspace layout ----
  char* cur = (char*)d_ws;
  auto take = [&](size_t bytes) {
    char* p = cur;
    cur += (bytes + 15) & ~(size_t)15;
    return p;
  };
  unsigned short* bufCb = (unsigned short*)take((size_t)N * 256 * 2);  // h1/h3 bf16
  unsigned short* bufDb = (unsigned short*)take((size_t)N * 128 * 2);  // h2 bf16
  _Float16* Ab = (_Float16*)take((size_t)N * 256 * 2);                 // xl fp16
  _Float16* Bb = (_Float16*)take((size_t)N * 256 * 2);                 // xr fp16
  unsigned short* xb = (unsigned short*)take((size_t)N * 64 * 2);      // x bf16
  float* stats = (float*)take(768 * 4);                                // 3 x (128+128)
  float* zgb = (float*)take(1024 * 4);                                 // 16 x 64 z bins
  int* deg = (int*)take((size_t)N * 4);
  int* starts = (int*)take((size_t)N * 4);
  int* cursor = (int*)take((size_t)N * 4);
  int* bsum = (int*)take(1024);
  int* esrc = (int*)take((size_t)E * 4);
  auto wt = [&](int K, int F) { return (unsigned short*)take((size_t)K * F * 2); };
  unsigned short *Tl1 = wt(64, 64), *Tr1 = wt(64, 64);
  unsigned short *Tl2 = wt(64, 128), *Tr2 = wt(64, 128), *Tres2 = wt(64, 128);
  unsigned short *Tl3 = wt(128, 256), *Tr3 = wt(128, 256), *Tres3 = wt(128, 256);
  unsigned short *Tenc = wt(256, 64), *Trp = wt(64, 64);
  unsigned short *Td1 = wt(64, 128), *Td2 = wt(128, 64), *Td3 = wt(64, 64);
  if ((size_t)(cur - (char*)d_ws) > ws_size) return;

  float* z = (float*)d_out;           // z_nodes (N x 64)
  float* xhat = z + (size_t)N * 64;   // x_hat   (N x 64)
  float* zg = xhat + (size_t)N * 64;  // z_graph (64)

  // ---- fused prep: wconv + cvt + zero ----
  {
    WPack p;
    const float* Ws[13] = {Wl1, Wr1, Wl2, Wr2, Wres2, Wl3, Wr3, Wres3,
                           encW, rpW, d1W, d2W, d3W};
    unsigned short* Ts[13] = {Tl1, Tr1, Tl2, Tr2, Tres2, Tl3, Tr3, Tres3,
                              Tenc, Trp, Td1, Td2, Td3};
    const int Ks[13] = {64, 64, 64, 64, 64, 128, 128, 128, 256, 64, 64, 128, 64};
    const int Fs[13] = {64, 64, 128, 128, 128, 256, 256, 256, 64, 64, 128, 64, 64};
    int base = 0;
    for (int i = 0; i < 13; ++i) {
      p.s[i] = {Ws[i], Ts[i], Ks[i], Fs[i], base};
      base += Ks[i] * Fs[i];
    }
    p.total = base;
    const int WB = (base + 255) / 256;
    const int CB = 512;
    const int ZB = (N + 255) / 256;
    prep_k<<<WB + CB + ZB, 256, 0, stream>>>(p, WB, x, xb, (size_t)N * 16, CB, deg, N,
                                             stats, zgb);
  }

  // ---- CSR by target ----
  const int nb = (N + 255) / 256;
  hist_k<<<512, 256, 0, stream>>>(etgt_in, deg, E);
  scan1_k<<<nb, 256, 0, stream>>>(deg, bsum, N);
  scan2_k<<<1, 256, 0, stream>>>(bsum, nb);
  scan3_k<<<nb, 256, 0, stream>>>(deg, bsum, starts, cursor, N);
  scatter_k<<<512, 256, 0, stream>>>(esrc_in, etgt_in, cursor, esrc, E);

  const int gblk = (N + 63) / 64;
  const float* nullf = nullptr;
  unsigned short* nullb = nullptr;

  // ---- conv1 ----
  mg_k<64, 64, 2, 0><<<gblk, 256, 0, stream>>>(xb, nullf, nullf, nullf, 0.f, Tl1, bl1,
                                               Tr1, br1, nullb, Ab, Bb, nullb, N);
  agg_t<64, 1, 2, 0><<<(N + 7) / 8, 256, 0, stream>>>(Ab, Bb, att1, bo1, starts, deg,
                                                      esrc, bufCb, stats + 0, N);
  // ---- conv2 (LN1 inline) ----
  mg_k<64, 128, 3, 1><<<gblk, 256, 0, stream>>>(
      bufCb, stats + 0, ln1g, ln1b, 1.f / ((float)N * 64.f), Tl2, bl2, Tr2, br2, Tres2,
      Ab, Bb, bufDb, N);
  agg_t<128, 4, 1, 1><<<(N + 3) / 4, 256, 0, stream>>>(Ab, Bb, att2, bo2, starts, deg,
                                                       esrc, bufDb, stats + 256, N);
  // ---- conv3 (LN2 inline) ----
  mg_k<128, 256, 3, 1><<<gblk, 256, 0, stream>>>(
      bufDb, stats + 256, ln2g, ln2b, 1.f / ((float)N * 128.f), Tl3, bl3, Tr3, br3,
      Tres3, Ab, Bb, bufCb, N);
  agg_t<256, 4, 1, 1><<<(N + 3) / 4, 256, 0, stream>>>(Ab, Bb, att3, bo3, starts, deg,
                                                       esrc, bufCb, stats + 512, N);
  // ---- fused encoder + decoder (LN3 inline) ----
  encdec_k<<<gblk, 256, 0, stream>>>(bufCb, stats + 512, ln3g, ln3b,
                                     1.f / ((float)N * 256.f), Tenc, encb, xb, Trp, rpb,
                                     Td1, d1b, Td2, d2b, Td3, d3b, z, xhat, zgb, N);
  colfin_k<<<1, 64, 0, stream>>>(zgb, zg, 1.f / (float)N);
}